// Round 4
// baseline (998.388 us; speedup 1.0000x reference)
//
#include <hip/hip_runtime.h>
#include <hip/hip_fp16.h>

#define BB 1024
#define SS 128
#define FF 64
#define HH 100

typedef _Float16 h8 __attribute__((ext_vector_type(8)));
typedef _Float16 h4 __attribute__((ext_vector_type(4)));
typedef float f4v __attribute__((ext_vector_type(4)));

__device__ __forceinline__ float sigmf(float x){ return 1.0f/(1.0f+__expf(-x)); }
__device__ __forceinline__ float ftanh(float x){ float e=__expf(2.f*x); return 1.f - 2.f/(e+1.f); }

// LDS-only barrier: waits own LDS ops, does NOT drain vmcnt (global stores
// stay in flight across steps).
#define LDS_BARRIER() __asm__ __volatile__("s_waitcnt lgkmcnt(0)\ns_barrier" ::: "memory")

__device__ __forceinline__ float wsum(float v){
#pragma unroll
  for (int m = 32; m >= 1; m >>= 1) v += __shfl_xor(v, m, 64);
  return v;
}
__device__ __forceinline__ float wmax(float v){
#pragma unroll
  for (int m = 32; m >= 1; m >>= 1) v = fmaxf(v, __shfl_xor(v, m, 64));
  return v;
}

// ---------------- gram: gram[b,i,j] = sum_s x[b,s,i]*x[b,s,j] ----------------
__global__ __launch_bounds__(256) void k_gram(const float* __restrict__ x, float* __restrict__ gram){
  __shared__ __align__(16) float xs[SS*FF];
  int b = blockIdx.x, tid = threadIdx.x;
  const float* xb = x + (size_t)b*SS*FF;
  for (int i = tid; i < SS*FF/4; i += 256)
    ((float4*)xs)[i] = ((const float4*)xb)[i];
  __syncthreads();
  int ti = (tid & 15) * 4, tj = (tid >> 4) * 4;
  float acc[4][4];
#pragma unroll
  for (int a=0;a<4;++a)
#pragma unroll
    for (int c=0;c<4;++c) acc[a][c]=0.f;
  for (int s = 0; s < SS; ++s) {
    const float* row = xs + s*FF;
    float4 av = *(const float4*)(row + ti);
    float4 bv = *(const float4*)(row + tj);
    float aa[4] = {av.x,av.y,av.z,av.w};
    float bb2[4] = {bv.x,bv.y,bv.z,bv.w};
#pragma unroll
    for (int a=0;a<4;++a)
#pragma unroll
      for (int c=0;c<4;++c) acc[a][c] += aa[a]*bb2[c];
  }
  float* g = gram + (size_t)b*4096;
#pragma unroll
  for (int a=0;a<4;++a)
#pragma unroll
    for (int c=0;c<4;++c) g[(ti+a)*64 + tj + c] = acc[a][c];
}

// ------- conv1(3x3,1->16,SAME)+bias+relu+maxpool2 -> half CHANNEL-LAST [B][p][ic] -------
__global__ __launch_bounds__(256) void k_conv1pool(const float* __restrict__ gram,
    const float* __restrict__ c1w, const float* __restrict__ c1b, __half* __restrict__ pool1){
  __shared__ float img2[66*66];
  __shared__ float ws1[144];
  __shared__ float bs1[16];
  int tid=threadIdx.x, b=blockIdx.x;
  for (int i=tid;i<66*66;i+=256) img2[i]=0.f;
  if (tid<144) ws1[tid]=c1w[tid];
  if (tid<16) bs1[tid]=c1b[tid];
  __syncthreads();
  const float* gb = gram + (size_t)b*4096;
  for (int i=tid;i<4096;i+=256){ int y=i>>6, xx=i&63; img2[(y+1)*66 + xx+1] = gb[i]; }
  __syncthreads();
  int oc = tid>>4, slot = tid&15;
  float wr[9];
#pragma unroll
  for (int t=0;t<9;++t) wr[t]=ws1[oc*9+t];
  float bo = bs1[oc];
  for (int p=slot;p<1024;p+=16){
    int py=p>>5, px=p&31;
    int y0=py*2, x0=px*2;
    float v[4][4];
#pragma unroll
    for (int wy=0;wy<4;++wy)
#pragma unroll
      for (int wxx=0;wxx<4;++wxx) v[wy][wxx]=img2[(y0+wy)*66 + x0+wxx];
    float s00=bo,s01=bo,s10=bo,s11=bo;
#pragma unroll
    for (int ky=0;ky<3;++ky)
#pragma unroll
      for (int kx=0;kx<3;++kx){
        float w=wr[ky*3+kx];
        s00 += v[ky][kx]*w;   s01 += v[ky][kx+1]*w;
        s10 += v[ky+1][kx]*w; s11 += v[ky+1][kx+1]*w;
      }
    float mx = fmaxf(fmaxf(s00,s01),fmaxf(s10,s11));
    pool1[(size_t)b*16384 + p*16 + oc] = __float2half(fmaxf(mx,0.f));
  }
}

// ================= conv2 as implicit-im2col MFMA GEMM =================
__global__ __launch_bounds__(512, 4) void k_conv2mfma(const __half* __restrict__ pool1,
    const float* __restrict__ c2w, const float* __restrict__ c2b, float* __restrict__ proc){
  __shared__ __align__(16) _Float16 img[(34*34+1)*24];   // +1 zero slot
  __shared__ float red[8][32];
  int b = blockIdx.x, tid = threadIdx.x;
  int wv = tid>>6, l = tid&63, lm = l&15, lq = l>>4;
  h8 bfr[2][5];
  float biasv[2];
#pragma unroll
  for (int nt=0; nt<2; ++nt){
    int oc = nt*16 + lm;
    biasv[nt] = c2b[oc];
#pragma unroll
    for (int c=0;c<5;++c){
      h8 f;
#pragma unroll
      for (int j=0;j<8;++j){
        int k = c*32 + lq*8 + j;
        int tap = k>>4, ic = k&15;
        f[j] = (_Float16)((tap<9) ? c2w[oc*144 + ic*9 + tap] : 0.f);
      }
      bfr[nt][c]=f;
    }
  }
  {
    h8 z = {0,0,0,0,0,0,0,0};
    for (int i=tid; i<(34*34+1)*3; i+=512) ((h8*)img)[i] = z;
  }
  __syncthreads();
  const __half* src = pool1 + (size_t)b*16384;
  for (int pp=tid; pp<1024; pp+=512){
    int y=pp>>5, x=pp&31;
    const h8* s = (const h8*)(src + pp*16);
    h8* d = (h8*)&img[((y+1)*34 + (x+1))*24];
    d[0]=s[0]; d[1]=s[1];
  }
  __syncthreads();
  f4v ssum0 = {0,0,0,0}, ssum1 = {0,0,0,0};
#pragma unroll 2
  for (int i=0;i<8;++i){
    int mt = wv + i*8;
    int y = mt>>1, x0 = (mt&1)*16;
    h8 afr[5];
#pragma unroll
    for (int c=0;c<5;++c){
      int tap = 2*c + (lq>>1);
      int addr;
      if (c==4 && lq>=2) addr = 34*34*24;
      else {
        int dy = tap/3 - 1, dx = tap - (tap/3)*3 - 1;
        addr = ((y+dy+1)*34 + (x0+lm+dx+1))*24 + (lq&1)*8;
      }
      afr[c] = *(const h8*)&img[addr];
    }
    f4v a0 = {biasv[0],biasv[0],biasv[0],biasv[0]};
    f4v a1 = {biasv[1],biasv[1],biasv[1],biasv[1]};
#pragma unroll
    for (int c=0;c<5;++c){
      a0 = __builtin_amdgcn_mfma_f32_16x16x32_f16(afr[c], bfr[0][c], a0, 0,0,0);
      a1 = __builtin_amdgcn_mfma_f32_16x16x32_f16(afr[c], bfr[1][c], a1, 0,0,0);
    }
#pragma unroll
    for (int r=0;r<4;++r){
      ssum0[r] += fmaxf(a0[r],0.f);
      ssum1[r] += fmaxf(a1[r],0.f);
    }
  }
  float s0 = ssum0[0]+ssum0[1]+ssum0[2]+ssum0[3];
  float s1 = ssum1[0]+ssum1[1]+ssum1[2]+ssum1[3];
  s0 += __shfl_xor(s0,16,64); s0 += __shfl_xor(s0,32,64);
  s1 += __shfl_xor(s1,16,64); s1 += __shfl_xor(s1,32,64);
  if (lq==0){ red[wv][lm]=s0; red[wv][16+lm]=s1; }
  __syncthreads();
  if (tid<32){
    float t=0.f;
#pragma unroll
    for (int w2=0;w2<8;++w2) t += red[w2][tid];
    proc[b*32+tid] = t*(1.f/1024.f);
  }
}

// ------------- fs = tanh(x@fW1^T+fb1)@fW2^T+fb2, per (b,s) row -------------
__global__ __launch_bounds__(256) void k_fs(const float* __restrict__ x,
    const float* __restrict__ fW1, const float* __restrict__ fb1,
    const float* __restrict__ fW2, const float* __restrict__ fb2,
    float* __restrict__ fs){
  __shared__ float w1t[64*32];
  __shared__ float w2t[32*64];
  __shared__ float b1s[32], b2s[64];
  __shared__ __align__(16) float xbuf[4][8][64];
  __shared__ float t1buf[4][8][32];
  int tid=threadIdx.x, wv=tid>>6, lane=tid&63;
  for (int i=tid;i<2048;i+=256){ int j=i>>6,k=i&63; w1t[k*32+j]=fW1[i]; }
  for (int i=tid;i<2048;i+=256){ int j=i>>5,k=i&31; w2t[k*64+j]=fW2[i]; }
  if (tid<32) b1s[tid]=fb1[tid];
  if (tid<64) b2s[tid]=fb2[tid];
  __syncthreads();
  size_t Rw = (size_t)blockIdx.x*64 + wv*16;
  int j = lane & 31, half = lane >> 5;
  for (int pass=0; pass<2; ++pass){
    size_t R0 = Rw + pass*8;
    const float4* src = (const float4*)(x + R0*64);
    float4* dst = (float4*)&xbuf[wv][0][0];
    for (int i=lane;i<128;i+=64) dst[i]=src[i];
    __syncthreads();
    {
      float a0=b1s[j],a1=b1s[j],a2=b1s[j],a3=b1s[j];
      const float* xr = &xbuf[wv][half*4][0];
      for (int k=0;k<64;++k){
        float w = w1t[k*32+j];
        a0 += w*xr[k]; a1 += w*xr[64+k]; a2 += w*xr[128+k]; a3 += w*xr[192+k];
      }
      float* t1r = &t1buf[wv][half*4][0];
      t1r[j]=ftanh(a0); t1r[32+j]=ftanh(a1); t1r[64+j]=ftanh(a2); t1r[96+j]=ftanh(a3);
    }
    __syncthreads();
    {
      float f[8];
#pragma unroll
      for (int r=0;r<8;++r) f[r]=b2s[lane];
      for (int k=0;k<32;++k){
        float w = w2t[k*64+lane];
#pragma unroll
        for (int r=0;r<8;++r) f[r] += w*t1buf[wv][r][k];
      }
#pragma unroll
      for (int r=0;r<8;++r) fs[(R0+r)*64 + lane] = f[r];
    }
    __syncthreads();
  }
}

// ------- aw = tanh([fs,proc]@cW1^T+cb1)@cW2^T+cb2; feature_w=softmax(aw); wx=x*fw -------
__global__ __launch_bounds__(256) void k_attnmlp(const float* __restrict__ x,
    const float* __restrict__ fs, const float* __restrict__ proc,
    const float* __restrict__ cW1, const float* __restrict__ cb1,
    const float* __restrict__ cW2, const float* __restrict__ cb2,
    float* __restrict__ fw_out, float* __restrict__ wx){
  __shared__ float c1t[96*64];
  __shared__ float c2t[64*64];
  __shared__ float cb1s[64], cb2s[64];
  __shared__ float cmb[4][4][96];
  __shared__ float h2b[4][4][64];
  int tid = threadIdx.x, wv = tid>>6, lane = tid&63;
  for (int i = tid; i < 6144; i += 256){ int j = i/96, k = i%96; c1t[k*64+j] = cW1[i]; }
  for (int i = tid; i < 4096; i += 256){ int j = i>>6, k = i&63; c2t[k*64+j] = cW2[i]; }
  if (tid < 64) { cb1s[tid] = cb1[tid]; cb2s[tid] = cb2[tid]; }
  __syncthreads();
  size_t Rw = (size_t)blockIdx.x*64 + wv*16;
  for (int pass = 0; pass < 4; ++pass) {
    size_t R0 = Rw + pass*4;
    for (int i = lane; i < 384; i += 64) {
      int r = i/96, k = i%96;
      size_t R = R0 + r;
      cmb[wv][r][k] = (k < 64) ? fs[R*64 + k] : proc[(R>>7)*32 + (k-64)];
    }
    __syncthreads();
    float h0a=cb1s[lane],h1a=cb1s[lane],h2a=cb1s[lane],h3a=cb1s[lane];
    for (int k = 0; k < 96; ++k) {
      float w = c1t[k*64+lane];
      h0a += w*cmb[wv][0][k]; h1a += w*cmb[wv][1][k];
      h2a += w*cmb[wv][2][k]; h3a += w*cmb[wv][3][k];
    }
    h2b[wv][0][lane]=ftanh(h0a); h2b[wv][1][lane]=ftanh(h1a);
    h2b[wv][2][lane]=ftanh(h2a); h2b[wv][3][lane]=ftanh(h3a);
    __syncthreads();
    float a0=cb2s[lane],a1=cb2s[lane],a2=cb2s[lane],a3=cb2s[lane];
    for (int k = 0; k < 64; ++k) {
      float w = c2t[k*64+lane];
      a0 += w*h2b[wv][0][k]; a1 += w*h2b[wv][1][k];
      a2 += w*h2b[wv][2][k]; a3 += w*h2b[wv][3][k];
    }
    float m0=wmax(a0), m1=wmax(a1), m2=wmax(a2), m3=wmax(a3);
    float e0=__expf(a0-m0), e1=__expf(a1-m1), e2=__expf(a2-m2), e3=__expf(a3-m3);
    float s0=wsum(e0), s1=wsum(e1), s2=wsum(e2), s3=wsum(e3);
    float f0v=e0/s0, f1v=e1/s1, f2v=e2/s2, f3v=e3/s3;
    size_t R;
    R=R0+0; fw_out[R*64+lane]=f0v; wx[R*64+lane]=x[R*64+lane]*f0v;
    R=R0+1; fw_out[R*64+lane]=f1v; wx[R*64+lane]=x[R*64+lane]*f1v;
    R=R0+2; fw_out[R*64+lane]=f2v; wx[R*64+lane]=x[R*64+lane]*f2v;
    R=R0+3; fw_out[R*64+lane]=f3v; wx[R*64+lane]=x[R*64+lane]*f3v;
    __syncthreads();
  }
}

// ================= MFMA encoder LSTM (swapped operands) =================
// Round-0 structure (7 waves, 16 batches/block, 64 blocks), three chain cuts:
// 1) x-prefetch issued TWO steps early (manual unroll-2, ping-pong regs rA/rB:
//    load x(t+2) at step t, consume at step t+1 -> full-step vmcnt slack; the
//    old 1-step prefetch left the only in-recurrence HBM load with ~600cyc
//    slack vs ~900cyc latency).
// 2) f32 enc store dropped; k_attn2 consumes ench (f16). WRITE 80->29MB.
// 3) s_setprio around the MFMA cluster (waves role-diverse post-barrier).
// Note: VGPR 108 + ~96 AGPR (unified file) => max 2 waves/SIMD; colocation
// beyond that is impossible without moving weights out of registers (R1/R2).
// ench: f16 copy of enc, row-padded to 112 (units 100..111 zeroed).
__global__ __launch_bounds__(448) void k_enc_mfma(const float* __restrict__ wx,
    const float* __restrict__ Wih, const float* __restrict__ Whh,
    const float* __restrict__ bih, const float* __restrict__ bhh,
    _Float16* __restrict__ ench){
  __shared__ __align__(16) _Float16 hbuf[2][16*128];
  __shared__ __align__(16) _Float16 xst[2][16*64];
  int tid = threadIdx.x;
  int w = tid >> 6, l = tid & 63;
  int lm = l & 15, lq = l >> 4;
  int b0 = blockIdx.x * 16;
  int au = w*16 + lm;
  bool avalid = au < 100;
  int u0 = w*16 + lq*4;
  bool uvalid = (u0 + 3) < 100;
  h8 wfr[4][6];
#pragma unroll
  for (int tt=0; tt<4; ++tt){
    int row = tt*100 + au;
#pragma unroll
    for (int cc=0; cc<6; ++cc){
      h8 f;
#pragma unroll
      for (int j=0;j<8;++j){
        int kg = cc*32 + lq*8 + j;
        float v = 0.f;
        if (avalid){
          if (kg < 64) v = Wih[(size_t)row*64 + kg];
          else { int kh = kg - 64; if (kh < 100) v = Whh[(size_t)row*100 + kh]; }
        }
        f[j] = (_Float16)v;
      }
      wfr[tt][cc] = f;
    }
  }
  f4v biasv[4];
#pragma unroll
  for (int tt=0; tt<4; ++tt){
    if (uvalid){
      float4 bi = *(const float4*)&bih[tt*100 + u0];
      float4 bh = *(const float4*)&bhh[tt*100 + u0];
      f4v bv2 = {bi.x+bh.x, bi.y+bh.y, bi.z+bh.z, bi.w+bh.w};
      biasv[tt] = bv2;
    } else { f4v z = {0,0,0,0}; biasv[tt] = z; }
  }
  for (int i = tid; i < 2*16*128; i += 448) hbuf[0][i] = (_Float16)0.f;
  int sm = tid >> 4, skq = tid & 15;
  bool doPref = (tid < 256);
  float4 rA, rB;
  if (doPref){
    float4 xv0 = *(const float4*)(wx + ((size_t)(b0+sm)*SS + 0)*FF + skq*4);
    h4 p = {(_Float16)xv0.x,(_Float16)xv0.y,(_Float16)xv0.z,(_Float16)xv0.w};
    *(h4*)&xst[0][sm*64 + (((skq>>1) ^ (sm&7))<<3) + (skq&1)*4] = p;
    rA = *(const float4*)(wx + ((size_t)(b0+sm)*SS + 1)*FF + skq*4);   // x(1)
  }
  float cst[4] = {0.f,0.f,0.f,0.f};
  int hwaddr = lm*128 + (((2*w + (lq>>1)) ^ (lm&7))<<3) + (lq&1)*4;
  int xwaddr = sm*64 + (((skq>>1) ^ (sm&7))<<3) + (skq&1)*4;
  __syncthreads();

#define ENC_STEP(T, CUR, RCONS, RISSUE)                                          \
  {                                                                              \
    const int cur = (CUR), nxt = (CUR)^1;                                        \
    if (doPref && (T) < SS-2)                                                    \
      RISSUE = *(const float4*)(wx + ((size_t)(b0+sm)*SS + ((T)+2))*FF + skq*4); \
    h8 bact[6];                                                                  \
    _Pragma("unroll")                                                            \
    for (int cc=0; cc<2; ++cc)                                                   \
      bact[cc] = *(const h8*)&xst[cur][lm*64 + (((cc*4+lq) ^ (lm&7))<<3)];       \
    _Pragma("unroll")                                                            \
    for (int cc=0; cc<4; ++cc)                                                   \
      bact[2+cc] = *(const h8*)&hbuf[cur][lm*128 + (((cc*4+lq) ^ (lm&7))<<3)];   \
    f4v acc[4];                                                                  \
    __builtin_amdgcn_s_setprio(1);                                               \
    _Pragma("unroll")                                                            \
    for (int tt=0; tt<4; ++tt){                                                  \
      f4v a = biasv[tt];                                                         \
      _Pragma("unroll")                                                          \
      for (int cc=0; cc<6; ++cc)                                                 \
        a = __builtin_amdgcn_mfma_f32_16x16x32_f16(wfr[tt][cc], bact[cc], a, 0,0,0); \
      acc[tt] = a;                                                               \
    }                                                                            \
    __builtin_amdgcn_s_setprio(0);                                               \
    float hn[4];                                                                 \
    _Pragma("unroll")                                                            \
    for (int r=0;r<4;++r){                                                       \
      float cn = sigmf(acc[1][r])*cst[r] + sigmf(acc[0][r])*ftanh(acc[2][r]);    \
      hn[r] = sigmf(acc[3][r])*ftanh(cn);                                        \
      cst[r] = cn;                                                               \
    }                                                                            \
    if (uvalid){                                                                 \
      h4 hp = {(_Float16)hn[0],(_Float16)hn[1],(_Float16)hn[2],(_Float16)hn[3]}; \
      *(h4*)&hbuf[nxt][hwaddr] = hp;                                             \
      *(h4*)&ench[((size_t)(b0+lm)*SS + (T))*112 + u0] = hp;                     \
    } else {                                                                     \
      h4 z = {(_Float16)0.f,(_Float16)0.f,(_Float16)0.f,(_Float16)0.f};          \
      *(h4*)&ench[((size_t)(b0+lm)*SS + (T))*112 + u0] = z;                      \
    }                                                                            \
    if (doPref && (T) < SS-1){                                                   \
      h4 p = {(_Float16)RCONS.x,(_Float16)RCONS.y,(_Float16)RCONS.z,(_Float16)RCONS.w}; \
      *(h4*)&xst[nxt][xwaddr] = p;                                               \
    }                                                                            \
    LDS_BARRIER();                                                               \
  }

  for (int t = 0; t < SS; t += 2){
    ENC_STEP(t,   0, rA, rB)   // consumes x(t+1) from rA, issues x(t+2) into rB
    ENC_STEP(t+1, 1, rB, rA)   // consumes x(t+2) from rB, issues x(t+3) into rA
  }
#undef ENC_STEP
}

// ================= ts GEMM: ts[b,s] = aW2 @ tanh(aW1 @ enc_row + ab1) + ab2 ========
// M = B*S rows (ench f16, 112-padded), N = 64, K = 100->128 (chunk 3 half-zero).
// A-frags: direct 16B global loads (no LDS). B (aW1) + ab1/aW2 in registers.
__global__ __launch_bounds__(256) void k_ts(const _Float16* __restrict__ ench,
    const float* __restrict__ aW1, const float* __restrict__ ab1,
    const float* __restrict__ aW2, const float* __restrict__ ab2,
    float* __restrict__ ts){
  int tid = threadIdx.x, wv = tid>>6, l = tid&63, lm = l&15, lq = l>>4;
  h8 bfr[4][4];
#pragma unroll
  for (int nt=0; nt<4; ++nt){
    int n = nt*16 + lm;
#pragma unroll
    for (int cc=0; cc<4; ++cc){
      h8 f;
#pragma unroll
      for (int j=0;j<8;++j){
        int k = cc*32 + lq*8 + j;
        f[j] = (_Float16)((k<100) ? aW1[n*100+k] : 0.f);
      }
      bfr[nt][cc]=f;
    }
  }
  float ab1v[4], aw2v[4];
#pragma unroll
  for (int nt=0; nt<4; ++nt){ ab1v[nt] = ab1[nt*16+lm]; aw2v[nt] = aW2[nt*16+lm]; }
  float ab2v = ab2[0];
  int tile0 = (blockIdx.x*4 + wv)*4;
#pragma unroll
  for (int i=0;i<4;++i){
    int M0 = (tile0+i)*16;
    const _Float16* rowp = ench + (size_t)(M0+lm)*112;
    h8 afr[4];
#pragma unroll
    for (int cc=0; cc<3; ++cc)
      afr[cc] = *(const h8*)(rowp + cc*32 + lq*8);
    if (lq < 2) afr[3] = *(const h8*)(rowp + 96 + lq*8);
    else { h8 z={0,0,0,0,0,0,0,0}; afr[3]=z; }
    f4v acc[4];
#pragma unroll
    for (int nt=0; nt<4; ++nt){
      f4v a = {ab1v[nt],ab1v[nt],ab1v[nt],ab1v[nt]};
#pragma unroll
      for (int cc=0; cc<4; ++cc)
        a = __builtin_amdgcn_mfma_f32_16x16x32_f16(afr[cc], bfr[nt][cc], a, 0,0,0);
      acc[nt]=a;
    }
    float p[4];
#pragma unroll
    for (int r=0;r<4;++r){
      p[r] = aw2v[0]*ftanh(acc[0][r]) + aw2v[1]*ftanh(acc[1][r])
           + aw2v[2]*ftanh(acc[2][r]) + aw2v[3]*ftanh(acc[3][r]);
#pragma unroll
      for (int m=1;m<16;m<<=1) p[r] += __shfl_xor(p[r], m, 64);
    }
    if (lm==0){
      float4 st; st.x=p[0]+ab2v; st.y=p[1]+ab2v; st.z=p[2]+ab2v; st.w=p[3]+ab2v;
      *(float4*)&ts[M0 + lq*4] = st;
    }
  }
}

// ------- per-b: softmax(ts) over S, ctx, bott, dh0, dc0, decpre -------
// ctx now accumulated from ench (f16): h already round-trips f16 in the
// recurrence, added error ~5e-5.
__global__ __launch_bounds__(256) void k_attn2(const _Float16* __restrict__ ench,
    const float* __restrict__ ts,
    const float* __restrict__ bW, const float* __restrict__ bb_,
    const float* __restrict__ h0W, const float* __restrict__ h0b,
    const float* __restrict__ c0W, const float* __restrict__ c0b,
    const float* __restrict__ dWih, const float* __restrict__ dbih, const float* __restrict__ dbhh,
    float* __restrict__ tw_out, float* __restrict__ dh0, float* __restrict__ dc0,
    float* __restrict__ decpre){
  __shared__ float tsb[SS];
  __shared__ float ctxb[HH];
  __shared__ float bottb[32];
  __shared__ float red[8];
  int tid = threadIdx.x, wv = tid>>6, lane = tid&63;
  int b = blockIdx.x;
  const _Float16* encb = ench + (size_t)b*SS*112;
  float tv = (tid < SS) ? ts[(size_t)b*SS + tid] : -1e30f;
  float m = wmax(tv);
  if (lane==0) red[wv]=m;
  __syncthreads();
  m = fmaxf(fmaxf(red[0],red[1]), fmaxf(red[2],red[3]));
  float e = (tid < SS) ? __expf(tv - m) : 0.f;
  float sm = wsum(e);
  if (lane==0) red[4+wv]=sm;
  __syncthreads();
  float denom = red[4]+red[5]+red[6]+red[7];
  if (tid < SS){
    float twv = e/denom;
    tw_out[(size_t)b*SS + tid] = twv;
    tsb[tid] = twv;
  }
  __syncthreads();
  if (tid < HH){
    float a = 0.f;
#pragma unroll 4
    for (int s=0;s<SS;++s) a += tsb[s]*(float)encb[s*112 + tid];
    ctxb[tid]=a;
  }
  __syncthreads();
  if (tid < 32){
    float a = bb_[tid];
    const float* wr = bW + tid*HH;
    for (int k=0;k<HH;++k) a += wr[k]*ctxb[k];
    bottb[tid]=a;
  }
  __syncthreads();
  if (tid < HH){
    float a = h0b[tid];
    const float* wr = h0W + tid*32;
#pragma unroll
    for (int k=0;k<32;++k) a += wr[k]*bottb[k];
    dh0[(size_t)b*HH + tid] = a;
  } else if (tid < 200){
    int jj = tid-100;
    float a = c0b[jj];
    const float* wr = c0W + jj*32;
#pragma unroll
    for (int k=0;k<32;++k) a += wr[k]*bottb[k];
    dc0[(size_t)b*HH + jj] = a;
  }
  {
    int jj = tid;
    float a = dbih[jj]+dbhh[jj];
    const float* wr = dWih + jj*32;
#pragma unroll
    for (int k=0;k<32;++k) a += wr[k]*bottb[k];
    decpre[(size_t)b*400 + jj] = a;
    jj = tid + 256;
    if (jj < 400){
      float a2v = dbih[jj]+dbhh[jj];
      const float* wr2 = dWih + jj*32;
#pragma unroll
      for (int k=0;k<32;++k) a2v += wr2[k]*bottb[k];
      decpre[(size_t)b*400 + jj] = a2v;
    }
  }
}

// ================= MFMA decoder LSTM (swapped operands) =================
// Round-0 structure; f32 dec store replaced by f16 dech [row][112]
// (k_out converts at stage; pad units 100..111 never read). Unroll-2 for
// compile-time cur/nxt + setprio around MFMA.
__global__ __launch_bounds__(448) void k_dec_mfma(const float* __restrict__ decpre,
    const float* __restrict__ Whh,
    const float* __restrict__ dh0, const float* __restrict__ dc0,
    _Float16* __restrict__ dech){
  __shared__ __align__(16) _Float16 hbuf[2][16*128];
  int tid = threadIdx.x;
  int w = tid >> 6, l = tid & 63;
  int lm = l & 15, lq = l >> 4;
  int b0 = blockIdx.x * 16;
  int au = w*16 + lm;
  bool avalid = au < 100;
  int u0 = w*16 + lq*4;
  bool uvalid = (u0 + 3) < 100;
  h8 wfr[4][4];
#pragma unroll
  for (int tt = 0; tt < 4; ++tt){
    int row = tt*100 + au;
#pragma unroll
    for (int cc = 0; cc < 4; ++cc){
      h8 f;
#pragma unroll
      for (int j = 0; j < 8; ++j){
        int kh = cc*32 + lq*8 + j;
        float v = (avalid && kh < 100) ? Whh[(size_t)row*100 + kh] : 0.f;
        f[j] = (_Float16)v;
      }
      wfr[tt][cc] = f;
    }
  }
  f4v pre[4];
  float cst[4] = {0.f,0.f,0.f,0.f};
  if (uvalid){
#pragma unroll
    for (int tt = 0; tt < 4; ++tt){
      float4 p = *(const float4*)&decpre[(size_t)(b0+lm)*400 + tt*100 + u0];
      f4v pv = {p.x, p.y, p.z, p.w};
      pre[tt] = pv;
    }
    float4 c4 = *(const float4*)&dc0[(size_t)(b0+lm)*100 + u0];
    cst[0]=c4.x; cst[1]=c4.y; cst[2]=c4.z; cst[3]=c4.w;
  } else {
    f4v z = {0,0,0,0};
#pragma unroll
    for (int tt = 0; tt < 4; ++tt) pre[tt] = z;
  }
  for (int i = tid; i < 16*128; i += 448) hbuf[1][i] = (_Float16)0.f;
  for (int idx = tid; idx < 16*128; idx += 448){
    int m = idx >> 7, u2 = idx & 127;
    float v = (u2 < 100) ? dh0[(size_t)(b0+m)*HH + u2] : 0.f;
    hbuf[0][m*128 + (((u2>>3) ^ (m&7))<<3) + (u2&7)] = (_Float16)v;
  }
  int hwaddr = lm*128 + (((2*w + (lq>>1)) ^ (lm&7))<<3) + (lq&1)*4;
  __syncthreads();

#define DEC_STEP(T, CUR)                                                         \
  {                                                                              \
    const int cur = (CUR), nxt = (CUR)^1;                                        \
    h8 bact[4];                                                                  \
    _Pragma("unroll")                                                            \
    for (int cc = 0; cc < 4; ++cc)                                               \
      bact[cc] = *(const h8*)&hbuf[cur][lm*128 + (((cc*4+lq) ^ (lm&7))<<3)];     \
    f4v acc[4];                                                                  \
    __builtin_amdgcn_s_setprio(1);                                               \
    _Pragma("unroll")                                                            \
    for (int tt = 0; tt < 4; ++tt){                                              \
      f4v a = pre[tt];                                                           \
      _Pragma("unroll")                                                          \
      for (int cc = 0; cc < 4; ++cc)                                             \
        a = __builtin_amdgcn_mfma_f32_16x16x32_f16(wfr[tt][cc], bact[cc], a, 0,0,0); \
      acc[tt] = a;                                                               \
    }                                                                            \
    __builtin_amdgcn_s_setprio(0);                                               \
    float hn[4];                                                                 \
    _Pragma("unroll")                                                            \
    for (int r=0;r<4;++r){                                                       \
      float cn = sigmf(acc[1][r])*cst[r] + sigmf(acc[0][r])*ftanh(acc[2][r]);    \
      hn[r] = sigmf(acc[3][r])*ftanh(cn);                                        \
      cst[r] = cn;                                                               \
    }                                                                            \
    if (uvalid){                                                                 \
      h4 hp = {(_Float16)hn[0],(_Float16)hn[1],(_Float16)hn[2],(_Float16)hn[3]}; \
      *(h4*)&hbuf[nxt][hwaddr] = hp;                                             \
      *(h4*)&dech[((size_t)(b0+lm)*SS + (T))*112 + u0] = hp;                     \
    }                                                                            \
    LDS_BARRIER();                                                               \
  }

  for (int t = 0; t < SS; t += 2){
    DEC_STEP(t,   0)
    DEC_STEP(t+1, 1)
  }
#undef DEC_STEP
}

// ------------- out = dec @ oW^T + ob (dec consumed as f16 dech) -------------
__global__ __launch_bounds__(256) void k_out(const _Float16* __restrict__ dech,
    const float* __restrict__ oW, const float* __restrict__ ob, float* __restrict__ out0){
  __shared__ float oWt[100*64];
  __shared__ float dsr[64*112];
  int tid=threadIdx.x;
  size_t R0 = (size_t)blockIdx.x*64;
  for (int i=tid;i<6400;i+=256){ int j=i/100,k=i%100; oWt[k*64+j]=oW[i]; }
  {
    const h8* db = (const h8*)(dech + R0*112);
    for (int i=tid;i<896;i+=256){
      h8 v = db[i];
      float* d = dsr + i*8;
#pragma unroll
      for (int j=0;j<8;++j) d[j] = (float)v[j];
    }
  }
  __syncthreads();
  int j = tid&63, rb = tid>>6;
  float acc[16];
#pragma unroll
  for (int i=0;i<16;++i) acc[i]=0.f;
  for (int k=0;k<100;++k){
    float w = oWt[k*64+j];
#pragma unroll
    for (int i=0;i<16;++i) acc[i] += w*dsr[(rb + i*4)*112 + k];
  }
  float obv = ob[j];
#pragma unroll
  for (int i=0;i<16;++i) out0[(R0 + rb + i*4)*64 + j] = acc[i] + obv;
}

extern "C" void kernel_launch(void* const* d_in, const int* in_sizes, int n_in,
                              void* d_out, int out_size, void* d_ws, size_t ws_size,
                              hipStream_t stream) {
  const float* x    = (const float*)d_in[0];
  const float* c1w  = (const float*)d_in[1];
  const float* c1b  = (const float*)d_in[2];
  const float* c2w  = (const float*)d_in[3];
  const float* c2b  = (const float*)d_in[4];
  const float* fW1  = (const float*)d_in[5];
  const float* fb1  = (const float*)d_in[6];
  const float* fW2  = (const float*)d_in[7];
  const float* fb2  = (const float*)d_in[8];
  const float* cW1  = (const float*)d_in[9];
  const float* cb1  = (const float*)d_in[10];
  const float* cW2  = (const float*)d_in[11];
  const float* cb2  = (const float*)d_in[12];
  const float* eWih = (const float*)d_in[13];
  const float* eWhh = (const float*)d_in[14];
  const float* ebih = (const float*)d_in[15];
  const float* ebhh = (const float*)d_in[16];
  const float* aW1  = (const float*)d_in[17];
  const float* ab1  = (const float*)d_in[18];
  const float* aW2  = (const float*)d_in[19];
  const float* ab2  = (const float*)d_in[20];
  const float* bW   = (const float*)d_in[21];
  const float* bb   = (const float*)d_in[22];
  const float* h0W  = (const float*)d_in[23];
  const float* h0b  = (const float*)d_in[24];
  const float* c0W  = (const float*)d_in[25];
  const float* c0b  = (const float*)d_in[26];
  const float* dWih = (const float*)d_in[27];
  const float* dWhh = (const float*)d_in[28];
  const float* dbih = (const float*)d_in[29];
  const float* dbhh = (const float*)d_in[30];
  const float* oW   = (const float*)d_in[31];
  const float* ob   = (const float*)d_in[32];

  float* out0   = (float*)d_out;
  float* out_tw = out0 + (size_t)BB*SS*FF;
  float* out_fw = out_tw + (size_t)BB*SS;

  char* ws = (char*)d_ws;
  float*  gram   = (float*) (ws + 0);           // 16.78 MB (reused as ts after conv1)
  __half* pool1  = (__half*)(ws + 16777216);    // 33.55 MB (channel-last [b][p][ic])
  float*  proc   = (float*) (ws + 50331648);    // 0.13 MB
  float*  fsbuf  = (float*) (ws + 50462720);    // 33.55 MB (reused as ench after attnmlp)
  float*  wx     = (float*) (ws + 84017152);    // 33.55 MB
  // ws+117571584 (old f32 enc region, 52.43 MB) now unused
  float*  dh0    = (float*) (ws + 170000384);   // 0.41 MB
  float*  dc0    = (float*) (ws + 170409984);   // 0.41 MB
  float*  decpre = (float*) (ws + 170819584);   // 1.64 MB
  _Float16* dech = (_Float16*)(ws + 172457984); // 29.36 MB (f16, [row][112])
  float*     tsbuf = (float*)gram;              // 0.52 MB (gram dead after conv1)
  _Float16*  ench  = (_Float16*)fsbuf;          // 29.36 MB (fsbuf dead after attnmlp)

  k_gram<<<BB, 256, 0, stream>>>(x, gram);
  k_conv1pool<<<BB, 256, 0, stream>>>(gram, c1w, c1b, pool1);
  k_conv2mfma<<<BB, 512, 0, stream>>>(pool1, c2w, c2b, proc);
  k_fs<<<2048, 256, 0, stream>>>(x, fW1, fb1, fW2, fb2, fsbuf);
  k_attnmlp<<<2048, 256, 0, stream>>>(x, fsbuf, proc, cW1, cb1, cW2, cb2, out_fw, wx);
  k_enc_mfma<<<64, 448, 0, stream>>>(wx, eWih, eWhh, ebih, ebhh, ench);
  k_ts<<<512, 256, 0, stream>>>(ench, aW1, ab1, aW2, ab2, tsbuf);
  k_attn2<<<BB, 256, 0, stream>>>(ench, tsbuf, bW, bb, h0W, h0b, c0W, c0b,
                                  dWih, dbih, dbhh, out_tw, dh0, dc0, decpre);
  k_dec_mfma<<<64, 448, 0, stream>>>(decpre, dWhh, dh0, dc0, dech);
  k_out<<<2048, 256, 0, stream>>>(dech, oW, ob, out0);
}

// Round 5
// 825.202 us; speedup vs baseline: 1.2099x; 1.2099x over previous
//
#include <hip/hip_runtime.h>
#include <hip/hip_fp16.h>

#define BB 1024
#define SS 128
#define FF 64
#define HH 100

typedef _Float16 h8 __attribute__((ext_vector_type(8)));
typedef _Float16 h4 __attribute__((ext_vector_type(4)));
typedef float f4v __attribute__((ext_vector_type(4)));

// v_rcp_f32 (~1 ulp). Without -ffast-math, fp32 '/' expands to the full IEEE
// div sequence (~11 VALU ops, ~40cyc serial). The LSTM gate math ran 20
// divisions per wave per STEP inside the recurrence chain (R4 counters:
// active-CU VALUBusy ~55%, ~630 VALU instr/wave/step vs ~160 visible).
__device__ __forceinline__ float frcp(float x){ return __builtin_amdgcn_rcpf(x); }
__device__ __forceinline__ float sigmf(float x){ return frcp(1.0f+__expf(-x)); }
__device__ __forceinline__ float ftanh(float x){ float e=__expf(2.f*x); return 1.f - 2.f*frcp(e+1.f); }

// LDS-only barrier: waits own LDS ops, does NOT drain vmcnt (global stores
// stay in flight across steps).
#define LDS_BARRIER() __asm__ __volatile__("s_waitcnt lgkmcnt(0)\ns_barrier" ::: "memory")

__device__ __forceinline__ float wsum(float v){
#pragma unroll
  for (int m = 32; m >= 1; m >>= 1) v += __shfl_xor(v, m, 64);
  return v;
}
__device__ __forceinline__ float wmax(float v){
#pragma unroll
  for (int m = 32; m >= 1; m >>= 1) v = fmaxf(v, __shfl_xor(v, m, 64));
  return v;
}

// ---------------- gram: gram[b,i,j] = sum_s x[b,s,i]*x[b,s,j] ----------------
__global__ __launch_bounds__(256) void k_gram(const float* __restrict__ x, float* __restrict__ gram){
  __shared__ __align__(16) float xs[SS*FF];
  int b = blockIdx.x, tid = threadIdx.x;
  const float* xb = x + (size_t)b*SS*FF;
  for (int i = tid; i < SS*FF/4; i += 256)
    ((float4*)xs)[i] = ((const float4*)xb)[i];
  __syncthreads();
  int ti = (tid & 15) * 4, tj = (tid >> 4) * 4;
  float acc[4][4];
#pragma unroll
  for (int a=0;a<4;++a)
#pragma unroll
    for (int c=0;c<4;++c) acc[a][c]=0.f;
  for (int s = 0; s < SS; ++s) {
    const float* row = xs + s*FF;
    float4 av = *(const float4*)(row + ti);
    float4 bv = *(const float4*)(row + tj);
    float aa[4] = {av.x,av.y,av.z,av.w};
    float bb2[4] = {bv.x,bv.y,bv.z,bv.w};
#pragma unroll
    for (int a=0;a<4;++a)
#pragma unroll
      for (int c=0;c<4;++c) acc[a][c] += aa[a]*bb2[c];
  }
  float* g = gram + (size_t)b*4096;
#pragma unroll
  for (int a=0;a<4;++a)
#pragma unroll
    for (int c=0;c<4;++c) g[(ti+a)*64 + tj + c] = acc[a][c];
}

// ------- conv1(3x3,1->16,SAME)+bias+relu+maxpool2 -> half CHANNEL-LAST [B][p][ic] -------
__global__ __launch_bounds__(256) void k_conv1pool(const float* __restrict__ gram,
    const float* __restrict__ c1w, const float* __restrict__ c1b, __half* __restrict__ pool1){
  __shared__ float img2[66*66];
  __shared__ float ws1[144];
  __shared__ float bs1[16];
  int tid=threadIdx.x, b=blockIdx.x;
  for (int i=tid;i<66*66;i+=256) img2[i]=0.f;
  if (tid<144) ws1[tid]=c1w[tid];
  if (tid<16) bs1[tid]=c1b[tid];
  __syncthreads();
  const float* gb = gram + (size_t)b*4096;
  for (int i=tid;i<4096;i+=256){ int y=i>>6, xx=i&63; img2[(y+1)*66 + xx+1] = gb[i]; }
  __syncthreads();
  int oc = tid>>4, slot = tid&15;
  float wr[9];
#pragma unroll
  for (int t=0;t<9;++t) wr[t]=ws1[oc*9+t];
  float bo = bs1[oc];
  for (int p=slot;p<1024;p+=16){
    int py=p>>5, px=p&31;
    int y0=py*2, x0=px*2;
    float v[4][4];
#pragma unroll
    for (int wy=0;wy<4;++wy)
#pragma unroll
      for (int wxx=0;wxx<4;++wxx) v[wy][wxx]=img2[(y0+wy)*66 + x0+wxx];
    float s00=bo,s01=bo,s10=bo,s11=bo;
#pragma unroll
    for (int ky=0;ky<3;++ky)
#pragma unroll
      for (int kx=0;kx<3;++kx){
        float w=wr[ky*3+kx];
        s00 += v[ky][kx]*w;   s01 += v[ky][kx+1]*w;
        s10 += v[ky+1][kx]*w; s11 += v[ky+1][kx+1]*w;
      }
    float mx = fmaxf(fmaxf(s00,s01),fmaxf(s10,s11));
    pool1[(size_t)b*16384 + p*16 + oc] = __float2half(fmaxf(mx,0.f));
  }
}

// ================= conv2 as implicit-im2col MFMA GEMM =================
__global__ __launch_bounds__(512, 4) void k_conv2mfma(const __half* __restrict__ pool1,
    const float* __restrict__ c2w, const float* __restrict__ c2b, float* __restrict__ proc){
  __shared__ __align__(16) _Float16 img[(34*34+1)*24];   // +1 zero slot
  __shared__ float red[8][32];
  int b = blockIdx.x, tid = threadIdx.x;
  int wv = tid>>6, l = tid&63, lm = l&15, lq = l>>4;
  h8 bfr[2][5];
  float biasv[2];
#pragma unroll
  for (int nt=0; nt<2; ++nt){
    int oc = nt*16 + lm;
    biasv[nt] = c2b[oc];
#pragma unroll
    for (int c=0;c<5;++c){
      h8 f;
#pragma unroll
      for (int j=0;j<8;++j){
        int k = c*32 + lq*8 + j;
        int tap = k>>4, ic = k&15;
        f[j] = (_Float16)((tap<9) ? c2w[oc*144 + ic*9 + tap] : 0.f);
      }
      bfr[nt][c]=f;
    }
  }
  {
    h8 z = {0,0,0,0,0,0,0,0};
    for (int i=tid; i<(34*34+1)*3; i+=512) ((h8*)img)[i] = z;
  }
  __syncthreads();
  const __half* src = pool1 + (size_t)b*16384;
  for (int pp=tid; pp<1024; pp+=512){
    int y=pp>>5, x=pp&31;
    const h8* s = (const h8*)(src + pp*16);
    h8* d = (h8*)&img[((y+1)*34 + (x+1))*24];
    d[0]=s[0]; d[1]=s[1];
  }
  __syncthreads();
  f4v ssum0 = {0,0,0,0}, ssum1 = {0,0,0,0};
#pragma unroll 2
  for (int i=0;i<8;++i){
    int mt = wv + i*8;
    int y = mt>>1, x0 = (mt&1)*16;
    h8 afr[5];
#pragma unroll
    for (int c=0;c<5;++c){
      int tap = 2*c + (lq>>1);
      int addr;
      if (c==4 && lq>=2) addr = 34*34*24;
      else {
        int dy = tap/3 - 1, dx = tap - (tap/3)*3 - 1;
        addr = ((y+dy+1)*34 + (x0+lm+dx+1))*24 + (lq&1)*8;
      }
      afr[c] = *(const h8*)&img[addr];
    }
    f4v a0 = {biasv[0],biasv[0],biasv[0],biasv[0]};
    f4v a1 = {biasv[1],biasv[1],biasv[1],biasv[1]};
#pragma unroll
    for (int c=0;c<5;++c){
      a0 = __builtin_amdgcn_mfma_f32_16x16x32_f16(afr[c], bfr[0][c], a0, 0,0,0);
      a1 = __builtin_amdgcn_mfma_f32_16x16x32_f16(afr[c], bfr[1][c], a1, 0,0,0);
    }
#pragma unroll
    for (int r=0;r<4;++r){
      ssum0[r] += fmaxf(a0[r],0.f);
      ssum1[r] += fmaxf(a1[r],0.f);
    }
  }
  float s0 = ssum0[0]+ssum0[1]+ssum0[2]+ssum0[3];
  float s1 = ssum1[0]+ssum1[1]+ssum1[2]+ssum1[3];
  s0 += __shfl_xor(s0,16,64); s0 += __shfl_xor(s0,32,64);
  s1 += __shfl_xor(s1,16,64); s1 += __shfl_xor(s1,32,64);
  if (lq==0){ red[wv][lm]=s0; red[wv][16+lm]=s1; }
  __syncthreads();
  if (tid<32){
    float t=0.f;
#pragma unroll
    for (int w2=0;w2<8;++w2) t += red[w2][tid];
    proc[b*32+tid] = t*(1.f/1024.f);
  }
}

// ------------- fs = tanh(x@fW1^T+fb1)@fW2^T+fb2, per (b,s) row -------------
__global__ __launch_bounds__(256) void k_fs(const float* __restrict__ x,
    const float* __restrict__ fW1, const float* __restrict__ fb1,
    const float* __restrict__ fW2, const float* __restrict__ fb2,
    float* __restrict__ fs){
  __shared__ float w1t[64*32];
  __shared__ float w2t[32*64];
  __shared__ float b1s[32], b2s[64];
  __shared__ __align__(16) float xbuf[4][8][64];
  __shared__ float t1buf[4][8][32];
  int tid=threadIdx.x, wv=tid>>6, lane=tid&63;
  for (int i=tid;i<2048;i+=256){ int j=i>>6,k=i&63; w1t[k*32+j]=fW1[i]; }
  for (int i=tid;i<2048;i+=256){ int j=i>>5,k=i&31; w2t[k*64+j]=fW2[i]; }
  if (tid<32) b1s[tid]=fb1[tid];
  if (tid<64) b2s[tid]=fb2[tid];
  __syncthreads();
  size_t Rw = (size_t)blockIdx.x*64 + wv*16;
  int j = lane & 31, half = lane >> 5;
  for (int pass=0; pass<2; ++pass){
    size_t R0 = Rw + pass*8;
    const float4* src = (const float4*)(x + R0*64);
    float4* dst = (float4*)&xbuf[wv][0][0];
    for (int i=lane;i<128;i+=64) dst[i]=src[i];
    __syncthreads();
    {
      float a0=b1s[j],a1=b1s[j],a2=b1s[j],a3=b1s[j];
      const float* xr = &xbuf[wv][half*4][0];
      for (int k=0;k<64;++k){
        float w = w1t[k*32+j];
        a0 += w*xr[k]; a1 += w*xr[64+k]; a2 += w*xr[128+k]; a3 += w*xr[192+k];
      }
      float* t1r = &t1buf[wv][half*4][0];
      t1r[j]=ftanh(a0); t1r[32+j]=ftanh(a1); t1r[64+j]=ftanh(a2); t1r[96+j]=ftanh(a3);
    }
    __syncthreads();
    {
      float f[8];
#pragma unroll
      for (int r=0;r<8;++r) f[r]=b2s[lane];
      for (int k=0;k<32;++k){
        float w = w2t[k*64+lane];
#pragma unroll
        for (int r=0;r<8;++r) f[r] += w*t1buf[wv][r][k];
      }
#pragma unroll
      for (int r=0;r<8;++r) fs[(R0+r)*64 + lane] = f[r];
    }
    __syncthreads();
  }
}

// ------- aw = tanh([fs,proc]@cW1^T+cb1)@cW2^T+cb2; feature_w=softmax(aw); wx=x*fw -------
__global__ __launch_bounds__(256) void k_attnmlp(const float* __restrict__ x,
    const float* __restrict__ fs, const float* __restrict__ proc,
    const float* __restrict__ cW1, const float* __restrict__ cb1,
    const float* __restrict__ cW2, const float* __restrict__ cb2,
    float* __restrict__ fw_out, float* __restrict__ wx){
  __shared__ float c1t[96*64];
  __shared__ float c2t[64*64];
  __shared__ float cb1s[64], cb2s[64];
  __shared__ float cmb[4][4][96];
  __shared__ float h2b[4][4][64];
  int tid = threadIdx.x, wv = tid>>6, lane = tid&63;
  for (int i = tid; i < 6144; i += 256){ int j = i/96, k = i%96; c1t[k*64+j] = cW1[i]; }
  for (int i = tid; i < 4096; i += 256){ int j = i>>6, k = i&63; c2t[k*64+j] = cW2[i]; }
  if (tid < 64) { cb1s[tid] = cb1[tid]; cb2s[tid] = cb2[tid]; }
  __syncthreads();
  size_t Rw = (size_t)blockIdx.x*64 + wv*16;
  for (int pass = 0; pass < 4; ++pass) {
    size_t R0 = Rw + pass*4;
    for (int i = lane; i < 384; i += 64) {
      int r = i/96, k = i%96;
      size_t R = R0 + r;
      cmb[wv][r][k] = (k < 64) ? fs[R*64 + k] : proc[(R>>7)*32 + (k-64)];
    }
    __syncthreads();
    float h0a=cb1s[lane],h1a=cb1s[lane],h2a=cb1s[lane],h3a=cb1s[lane];
    for (int k = 0; k < 96; ++k) {
      float w = c1t[k*64+lane];
      h0a += w*cmb[wv][0][k]; h1a += w*cmb[wv][1][k];
      h2a += w*cmb[wv][2][k]; h3a += w*cmb[wv][3][k];
    }
    h2b[wv][0][lane]=ftanh(h0a); h2b[wv][1][lane]=ftanh(h1a);
    h2b[wv][2][lane]=ftanh(h2a); h2b[wv][3][lane]=ftanh(h3a);
    __syncthreads();
    float a0=cb2s[lane],a1=cb2s[lane],a2=cb2s[lane],a3=cb2s[lane];
    for (int k = 0; k < 64; ++k) {
      float w = c2t[k*64+lane];
      a0 += w*h2b[wv][0][k]; a1 += w*h2b[wv][1][k];
      a2 += w*h2b[wv][2][k]; a3 += w*h2b[wv][3][k];
    }
    float m0=wmax(a0), m1=wmax(a1), m2=wmax(a2), m3=wmax(a3);
    float e0=__expf(a0-m0), e1=__expf(a1-m1), e2=__expf(a2-m2), e3=__expf(a3-m3);
    float s0=wsum(e0), s1=wsum(e1), s2=wsum(e2), s3=wsum(e3);
    float f0v=e0*frcp(s0), f1v=e1*frcp(s1), f2v=e2*frcp(s2), f3v=e3*frcp(s3);
    size_t R;
    R=R0+0; fw_out[R*64+lane]=f0v; wx[R*64+lane]=x[R*64+lane]*f0v;
    R=R0+1; fw_out[R*64+lane]=f1v; wx[R*64+lane]=x[R*64+lane]*f1v;
    R=R0+2; fw_out[R*64+lane]=f2v; wx[R*64+lane]=x[R*64+lane]*f2v;
    R=R0+3; fw_out[R*64+lane]=f3v; wx[R*64+lane]=x[R*64+lane]*f3v;
    __syncthreads();
  }
}

// ================= MFMA encoder LSTM (swapped operands) =================
// Round-0 structure (7 waves, 16 batches/block, 64 blocks). R4 cuts kept
// (2-step-early x prefetch, f16-only output, setprio). R5 cut: all fp32
// divisions in the gate math replaced by v_rcp_f32 (sigmf/ftanh helpers) --
// each IEEE div was ~11 VALU ops + ~40cyc serial latency, 20 of them per
// wave per step inside the recurrence chain.
// ench: f16 copy of enc, row-padded to 112 (units 100..111 zeroed).
__global__ __launch_bounds__(448) void k_enc_mfma(const float* __restrict__ wx,
    const float* __restrict__ Wih, const float* __restrict__ Whh,
    const float* __restrict__ bih, const float* __restrict__ bhh,
    _Float16* __restrict__ ench){
  __shared__ __align__(16) _Float16 hbuf[2][16*128];
  __shared__ __align__(16) _Float16 xst[2][16*64];
  int tid = threadIdx.x;
  int w = tid >> 6, l = tid & 63;
  int lm = l & 15, lq = l >> 4;
  int b0 = blockIdx.x * 16;
  int au = w*16 + lm;
  bool avalid = au < 100;
  int u0 = w*16 + lq*4;
  bool uvalid = (u0 + 3) < 100;
  h8 wfr[4][6];
#pragma unroll
  for (int tt=0; tt<4; ++tt){
    int row = tt*100 + au;
#pragma unroll
    for (int cc=0; cc<6; ++cc){
      h8 f;
#pragma unroll
      for (int j=0;j<8;++j){
        int kg = cc*32 + lq*8 + j;
        float v = 0.f;
        if (avalid){
          if (kg < 64) v = Wih[(size_t)row*64 + kg];
          else { int kh = kg - 64; if (kh < 100) v = Whh[(size_t)row*100 + kh]; }
        }
        f[j] = (_Float16)v;
      }
      wfr[tt][cc] = f;
    }
  }
  f4v biasv[4];
#pragma unroll
  for (int tt=0; tt<4; ++tt){
    if (uvalid){
      float4 bi = *(const float4*)&bih[tt*100 + u0];
      float4 bh = *(const float4*)&bhh[tt*100 + u0];
      f4v bv2 = {bi.x+bh.x, bi.y+bh.y, bi.z+bh.z, bi.w+bh.w};
      biasv[tt] = bv2;
    } else { f4v z = {0,0,0,0}; biasv[tt] = z; }
  }
  for (int i = tid; i < 2*16*128; i += 448) hbuf[0][i] = (_Float16)0.f;
  int sm = tid >> 4, skq = tid & 15;
  bool doPref = (tid < 256);
  float4 rA, rB;
  if (doPref){
    float4 xv0 = *(const float4*)(wx + ((size_t)(b0+sm)*SS + 0)*FF + skq*4);
    h4 p = {(_Float16)xv0.x,(_Float16)xv0.y,(_Float16)xv0.z,(_Float16)xv0.w};
    *(h4*)&xst[0][sm*64 + (((skq>>1) ^ (sm&7))<<3) + (skq&1)*4] = p;
    rA = *(const float4*)(wx + ((size_t)(b0+sm)*SS + 1)*FF + skq*4);   // x(1)
  }
  float cst[4] = {0.f,0.f,0.f,0.f};
  int hwaddr = lm*128 + (((2*w + (lq>>1)) ^ (lm&7))<<3) + (lq&1)*4;
  int xwaddr = sm*64 + (((skq>>1) ^ (sm&7))<<3) + (skq&1)*4;
  __syncthreads();

#define ENC_STEP(T, CUR, RCONS, RISSUE)                                          \
  {                                                                              \
    const int cur = (CUR), nxt = (CUR)^1;                                        \
    if (doPref && (T) < SS-2)                                                    \
      RISSUE = *(const float4*)(wx + ((size_t)(b0+sm)*SS + ((T)+2))*FF + skq*4); \
    h8 bact[6];                                                                  \
    _Pragma("unroll")                                                            \
    for (int cc=0; cc<2; ++cc)                                                   \
      bact[cc] = *(const h8*)&xst[cur][lm*64 + (((cc*4+lq) ^ (lm&7))<<3)];       \
    _Pragma("unroll")                                                            \
    for (int cc=0; cc<4; ++cc)                                                   \
      bact[2+cc] = *(const h8*)&hbuf[cur][lm*128 + (((cc*4+lq) ^ (lm&7))<<3)];   \
    f4v acc[4];                                                                  \
    __builtin_amdgcn_s_setprio(1);                                               \
    _Pragma("unroll")                                                            \
    for (int tt=0; tt<4; ++tt){                                                  \
      f4v a = biasv[tt];                                                         \
      _Pragma("unroll")                                                          \
      for (int cc=0; cc<6; ++cc)                                                 \
        a = __builtin_amdgcn_mfma_f32_16x16x32_f16(wfr[tt][cc], bact[cc], a, 0,0,0); \
      acc[tt] = a;                                                               \
    }                                                                            \
    __builtin_amdgcn_s_setprio(0);                                               \
    float hn[4];                                                                 \
    _Pragma("unroll")                                                            \
    for (int r=0;r<4;++r){                                                       \
      float cn = sigmf(acc[1][r])*cst[r] + sigmf(acc[0][r])*ftanh(acc[2][r]);    \
      hn[r] = sigmf(acc[3][r])*ftanh(cn);                                        \
      cst[r] = cn;                                                               \
    }                                                                            \
    if (uvalid){                                                                 \
      h4 hp = {(_Float16)hn[0],(_Float16)hn[1],(_Float16)hn[2],(_Float16)hn[3]}; \
      *(h4*)&hbuf[nxt][hwaddr] = hp;                                             \
      *(h4*)&ench[((size_t)(b0+lm)*SS + (T))*112 + u0] = hp;                     \
    } else {                                                                     \
      h4 z = {(_Float16)0.f,(_Float16)0.f,(_Float16)0.f,(_Float16)0.f};          \
      *(h4*)&ench[((size_t)(b0+lm)*SS + (T))*112 + u0] = z;                      \
    }                                                                            \
    if (doPref && (T) < SS-1){                                                   \
      h4 p = {(_Float16)RCONS.x,(_Float16)RCONS.y,(_Float16)RCONS.z,(_Float16)RCONS.w}; \
      *(h4*)&xst[nxt][xwaddr] = p;                                               \
    }                                                                            \
    LDS_BARRIER();                                                               \
  }

  for (int t = 0; t < SS; t += 2){
    ENC_STEP(t,   0, rA, rB)   // consumes x(t+1) from rA, issues x(t+2) into rB
    ENC_STEP(t+1, 1, rB, rA)   // consumes x(t+2) from rB, issues x(t+3) into rA
  }
#undef ENC_STEP
}

// ================= ts GEMM: ts[b,s] = aW2 @ tanh(aW1 @ enc_row + ab1) + ab2 ========
// M = B*S rows (ench f16, 112-padded), N = 64, K = 100->128 (chunk 3 half-zero).
// A-frags: direct 16B global loads (no LDS). B (aW1) + ab1/aW2 in registers.
__global__ __launch_bounds__(256) void k_ts(const _Float16* __restrict__ ench,
    const float* __restrict__ aW1, const float* __restrict__ ab1,
    const float* __restrict__ aW2, const float* __restrict__ ab2,
    float* __restrict__ ts){
  int tid = threadIdx.x, wv = tid>>6, l = tid&63, lm = l&15, lq = l>>4;
  h8 bfr[4][4];
#pragma unroll
  for (int nt=0; nt<4; ++nt){
    int n = nt*16 + lm;
#pragma unroll
    for (int cc=0; cc<4; ++cc){
      h8 f;
#pragma unroll
      for (int j=0;j<8;++j){
        int k = cc*32 + lq*8 + j;
        f[j] = (_Float16)((k<100) ? aW1[n*100+k] : 0.f);
      }
      bfr[nt][cc]=f;
    }
  }
  float ab1v[4], aw2v[4];
#pragma unroll
  for (int nt=0; nt<4; ++nt){ ab1v[nt] = ab1[nt*16+lm]; aw2v[nt] = aW2[nt*16+lm]; }
  float ab2v = ab2[0];
  int tile0 = (blockIdx.x*4 + wv)*4;
#pragma unroll
  for (int i=0;i<4;++i){
    int M0 = (tile0+i)*16;
    const _Float16* rowp = ench + (size_t)(M0+lm)*112;
    h8 afr[4];
#pragma unroll
    for (int cc=0; cc<3; ++cc)
      afr[cc] = *(const h8*)(rowp + cc*32 + lq*8);
    if (lq < 2) afr[3] = *(const h8*)(rowp + 96 + lq*8);
    else { h8 z={0,0,0,0,0,0,0,0}; afr[3]=z; }
    f4v acc[4];
#pragma unroll
    for (int nt=0; nt<4; ++nt){
      f4v a = {ab1v[nt],ab1v[nt],ab1v[nt],ab1v[nt]};
#pragma unroll
      for (int cc=0; cc<4; ++cc)
        a = __builtin_amdgcn_mfma_f32_16x16x32_f16(afr[cc], bfr[nt][cc], a, 0,0,0);
      acc[nt]=a;
    }
    float p[4];
#pragma unroll
    for (int r=0;r<4;++r){
      p[r] = aw2v[0]*ftanh(acc[0][r]) + aw2v[1]*ftanh(acc[1][r])
           + aw2v[2]*ftanh(acc[2][r]) + aw2v[3]*ftanh(acc[3][r]);
#pragma unroll
      for (int m=1;m<16;m<<=1) p[r] += __shfl_xor(p[r], m, 64);
    }
    if (lm==0){
      float4 st; st.x=p[0]+ab2v; st.y=p[1]+ab2v; st.z=p[2]+ab2v; st.w=p[3]+ab2v;
      *(float4*)&ts[M0 + lq*4] = st;
    }
  }
}

// ------- per-b: softmax(ts) over S, ctx, bott, dh0, dc0, decpre -------
// ctx accumulated from ench (f16): h already round-trips f16 in the
// recurrence, added error ~5e-5.
__global__ __launch_bounds__(256) void k_attn2(const _Float16* __restrict__ ench,
    const float* __restrict__ ts,
    const float* __restrict__ bW, const float* __restrict__ bb_,
    const float* __restrict__ h0W, const float* __restrict__ h0b,
    const float* __restrict__ c0W, const float* __restrict__ c0b,
    const float* __restrict__ dWih, const float* __restrict__ dbih, const float* __restrict__ dbhh,
    float* __restrict__ tw_out, float* __restrict__ dh0, float* __restrict__ dc0,
    float* __restrict__ decpre){
  __shared__ float tsb[SS];
  __shared__ float ctxb[HH];
  __shared__ float bottb[32];
  __shared__ float red[8];
  int tid = threadIdx.x, wv = tid>>6, lane = tid&63;
  int b = blockIdx.x;
  const _Float16* encb = ench + (size_t)b*SS*112;
  float tv = (tid < SS) ? ts[(size_t)b*SS + tid] : -1e30f;
  float m = wmax(tv);
  if (lane==0) red[wv]=m;
  __syncthreads();
  m = fmaxf(fmaxf(red[0],red[1]), fmaxf(red[2],red[3]));
  float e = (tid < SS) ? __expf(tv - m) : 0.f;
  float sm = wsum(e);
  if (lane==0) red[4+wv]=sm;
  __syncthreads();
  float denom = red[4]+red[5]+red[6]+red[7];
  float rden = frcp(denom);
  if (tid < SS){
    float twv = e*rden;
    tw_out[(size_t)b*SS + tid] = twv;
    tsb[tid] = twv;
  }
  __syncthreads();
  if (tid < HH){
    float a = 0.f;
#pragma unroll 4
    for (int s=0;s<SS;++s) a += tsb[s]*(float)encb[s*112 + tid];
    ctxb[tid]=a;
  }
  __syncthreads();
  if (tid < 32){
    float a = bb_[tid];
    const float* wr = bW + tid*HH;
    for (int k=0;k<HH;++k) a += wr[k]*ctxb[k];
    bottb[tid]=a;
  }
  __syncthreads();
  if (tid < HH){
    float a = h0b[tid];
    const float* wr = h0W + tid*32;
#pragma unroll
    for (int k=0;k<32;++k) a += wr[k]*bottb[k];
    dh0[(size_t)b*HH + tid] = a;
  } else if (tid < 200){
    int jj = tid-100;
    float a = c0b[jj];
    const float* wr = c0W + jj*32;
#pragma unroll
    for (int k=0;k<32;++k) a += wr[k]*bottb[k];
    dc0[(size_t)b*HH + jj] = a;
  }
  {
    int jj = tid;
    float a = dbih[jj]+dbhh[jj];
    const float* wr = dWih + jj*32;
#pragma unroll
    for (int k=0;k<32;++k) a += wr[k]*bottb[k];
    decpre[(size_t)b*400 + jj] = a;
    jj = tid + 256;
    if (jj < 400){
      float a2v = dbih[jj]+dbhh[jj];
      const float* wr2 = dWih + jj*32;
#pragma unroll
      for (int k=0;k<32;++k) a2v += wr2[k]*bottb[k];
      decpre[(size_t)b*400 + jj] = a2v;
    }
  }
}

// ================= MFMA decoder LSTM (swapped operands) =================
// Round-0 structure; f16 dech output; rcp-based gate math (see k_enc_mfma).
__global__ __launch_bounds__(448) void k_dec_mfma(const float* __restrict__ decpre,
    const float* __restrict__ Whh,
    const float* __restrict__ dh0, const float* __restrict__ dc0,
    _Float16* __restrict__ dech){
  __shared__ __align__(16) _Float16 hbuf[2][16*128];
  int tid = threadIdx.x;
  int w = tid >> 6, l = tid & 63;
  int lm = l & 15, lq = l >> 4;
  int b0 = blockIdx.x * 16;
  int au = w*16 + lm;
  bool avalid = au < 100;
  int u0 = w*16 + lq*4;
  bool uvalid = (u0 + 3) < 100;
  h8 wfr[4][4];
#pragma unroll
  for (int tt = 0; tt < 4; ++tt){
    int row = tt*100 + au;
#pragma unroll
    for (int cc = 0; cc < 4; ++cc){
      h8 f;
#pragma unroll
      for (int j = 0; j < 8; ++j){
        int kh = cc*32 + lq*8 + j;
        float v = (avalid && kh < 100) ? Whh[(size_t)row*100 + kh] : 0.f;
        f[j] = (_Float16)v;
      }
      wfr[tt][cc] = f;
    }
  }
  f4v pre[4];
  float cst[4] = {0.f,0.f,0.f,0.f};
  if (uvalid){
#pragma unroll
    for (int tt = 0; tt < 4; ++tt){
      float4 p = *(const float4*)&decpre[(size_t)(b0+lm)*400 + tt*100 + u0];
      f4v pv = {p.x, p.y, p.z, p.w};
      pre[tt] = pv;
    }
    float4 c4 = *(const float4*)&dc0[(size_t)(b0+lm)*100 + u0];
    cst[0]=c4.x; cst[1]=c4.y; cst[2]=c4.z; cst[3]=c4.w;
  } else {
    f4v z = {0,0,0,0};
#pragma unroll
    for (int tt = 0; tt < 4; ++tt) pre[tt] = z;
  }
  for (int i = tid; i < 16*128; i += 448) hbuf[1][i] = (_Float16)0.f;
  for (int idx = tid; idx < 16*128; idx += 448){
    int m = idx >> 7, u2 = idx & 127;
    float v = (u2 < 100) ? dh0[(size_t)(b0+m)*HH + u2] : 0.f;
    hbuf[0][m*128 + (((u2>>3) ^ (m&7))<<3) + (u2&7)] = (_Float16)v;
  }
  int hwaddr = lm*128 + (((2*w + (lq>>1)) ^ (lm&7))<<3) + (lq&1)*4;
  __syncthreads();

#define DEC_STEP(T, CUR)                                                         \
  {                                                                              \
    const int cur = (CUR), nxt = (CUR)^1;                                        \
    h8 bact[4];                                                                  \
    _Pragma("unroll")                                                            \
    for (int cc = 0; cc < 4; ++cc)                                               \
      bact[cc] = *(const h8*)&hbuf[cur][lm*128 + (((cc*4+lq) ^ (lm&7))<<3)];     \
    f4v acc[4];                                                                  \
    __builtin_amdgcn_s_setprio(1);                                               \
    _Pragma("unroll")                                                            \
    for (int tt = 0; tt < 4; ++tt){                                              \
      f4v a = pre[tt];                                                           \
      _Pragma("unroll")                                                          \
      for (int cc = 0; cc < 4; ++cc)                                             \
        a = __builtin_amdgcn_mfma_f32_16x16x32_f16(wfr[tt][cc], bact[cc], a, 0,0,0); \
      acc[tt] = a;                                                               \
    }                                                                            \
    __builtin_amdgcn_s_setprio(0);                                               \
    float hn[4];                                                                 \
    _Pragma("unroll")                                                            \
    for (int r=0;r<4;++r){                                                       \
      float cn = sigmf(acc[1][r])*cst[r] + sigmf(acc[0][r])*ftanh(acc[2][r]);    \
      hn[r] = sigmf(acc[3][r])*ftanh(cn);                                        \
      cst[r] = cn;                                                               \
    }                                                                            \
    if (uvalid){                                                                 \
      h4 hp = {(_Float16)hn[0],(_Float16)hn[1],(_Float16)hn[2],(_Float16)hn[3]}; \
      *(h4*)&hbuf[nxt][hwaddr] = hp;                                             \
      *(h4*)&dech[((size_t)(b0+lm)*SS + (T))*112 + u0] = hp;                     \
    }                                                                            \
    LDS_BARRIER();                                                               \
  }

  for (int t = 0; t < SS; t += 2){
    DEC_STEP(t,   0)
    DEC_STEP(t+1, 1)
  }
#undef DEC_STEP
}

// ------------- out = dec @ oW^T + ob (dec consumed as f16 dech) -------------
__global__ __launch_bounds__(256) void k_out(const _Float16* __restrict__ dech,
    const float* __restrict__ oW, const float* __restrict__ ob, float* __restrict__ out0){
  __shared__ float oWt[100*64];
  __shared__ float dsr[64*112];
  int tid=threadIdx.x;
  size_t R0 = (size_t)blockIdx.x*64;
  for (int i=tid;i<6400;i+=256){ int j=i/100,k=i%100; oWt[k*64+j]=oW[i]; }
  {
    const h8* db = (const h8*)(dech + R0*112);
    for (int i=tid;i<896;i+=256){
      h8 v = db[i];
      float* d = dsr + i*8;
#pragma unroll
      for (int j=0;j<8;++j) d[j] = (float)v[j];
    }
  }
  __syncthreads();
  int j = tid&63, rb = tid>>6;
  float acc[16];
#pragma unroll
  for (int i=0;i<16;++i) acc[i]=0.f;
  for (int k=0;k<100;++k){
    float w = oWt[k*64+j];
#pragma unroll
    for (int i=0;i<16;++i) acc[i] += w*dsr[(rb + i*4)*112 + k];
  }
  float obv = ob[j];
#pragma unroll
  for (int i=0;i<16;++i) out0[(R0 + rb + i*4)*64 + j] = acc[i] + obv;
}

extern "C" void kernel_launch(void* const* d_in, const int* in_sizes, int n_in,
                              void* d_out, int out_size, void* d_ws, size_t ws_size,
                              hipStream_t stream) {
  const float* x    = (const float*)d_in[0];
  const float* c1w  = (const float*)d_in[1];
  const float* c1b  = (const float*)d_in[2];
  const float* c2w  = (const float*)d_in[3];
  const float* c2b  = (const float*)d_in[4];
  const float* fW1  = (const float*)d_in[5];
  const float* fb1  = (const float*)d_in[6];
  const float* fW2  = (const float*)d_in[7];
  const float* fb2  = (const float*)d_in[8];
  const float* cW1  = (const float*)d_in[9];
  const float* cb1  = (const float*)d_in[10];
  const float* cW2  = (const float*)d_in[11];
  const float* cb2  = (const float*)d_in[12];
  const float* eWih = (const float*)d_in[13];
  const float* eWhh = (const float*)d_in[14];
  const float* ebih = (const float*)d_in[15];
  const float* ebhh = (const float*)d_in[16];
  const float* aW1  = (const float*)d_in[17];
  const float* ab1  = (const float*)d_in[18];
  const float* aW2  = (const float*)d_in[19];
  const float* ab2  = (const float*)d_in[20];
  const float* bW   = (const float*)d_in[21];
  const float* bb   = (const float*)d_in[22];
  const float* h0W  = (const float*)d_in[23];
  const float* h0b  = (const float*)d_in[24];
  const float* c0W  = (const float*)d_in[25];
  const float* c0b  = (const float*)d_in[26];
  const float* dWih = (const float*)d_in[27];
  const float* dWhh = (const float*)d_in[28];
  const float* dbih = (const float*)d_in[29];
  const float* dbhh = (const float*)d_in[30];
  const float* oW   = (const float*)d_in[31];
  const float* ob   = (const float*)d_in[32];

  float* out0   = (float*)d_out;
  float* out_tw = out0 + (size_t)BB*SS*FF;
  float* out_fw = out_tw + (size_t)BB*SS;

  char* ws = (char*)d_ws;
  float*  gram   = (float*) (ws + 0);           // 16.78 MB (reused as ts after conv1)
  __half* pool1  = (__half*)(ws + 16777216);    // 33.55 MB (channel-last [b][p][ic])
  float*  proc   = (float*) (ws + 50331648);    // 0.13 MB
  float*  fsbuf  = (float*) (ws + 50462720);    // 33.55 MB (reused as ench after attnmlp)
  float*  wx     = (float*) (ws + 84017152);    // 33.55 MB
  // ws+117571584 (old f32 enc region, 52.43 MB) now unused
  float*  dh0    = (float*) (ws + 170000384);   // 0.41 MB
  float*  dc0    = (float*) (ws + 170409984);   // 0.41 MB
  float*  decpre = (float*) (ws + 170819584);   // 1.64 MB
  _Float16* dech = (_Float16*)(ws + 172457984); // 29.36 MB (f16, [row][112])
  float*     tsbuf = (float*)gram;              // 0.52 MB (gram dead after conv1)
  _Float16*  ench  = (_Float16*)fsbuf;          // 29.36 MB (fsbuf dead after attnmlp)

  k_gram<<<BB, 256, 0, stream>>>(x, gram);
  k_conv1pool<<<BB, 256, 0, stream>>>(gram, c1w, c1b, pool1);
  k_conv2mfma<<<BB, 512, 0, stream>>>(pool1, c2w, c2b, proc);
  k_fs<<<2048, 256, 0, stream>>>(x, fW1, fb1, fW2, fb2, fsbuf);
  k_attnmlp<<<2048, 256, 0, stream>>>(x, fsbuf, proc, cW1, cb1, cW2, cb2, out_fw, wx);
  k_enc_mfma<<<64, 448, 0, stream>>>(wx, eWih, eWhh, ebih, ebhh, ench);
  k_ts<<<512, 256, 0, stream>>>(ench, aW1, ab1, aW2, ab2, tsbuf);
  k_attn2<<<BB, 256, 0, stream>>>(ench, tsbuf, bW, bb, h0W, h0b, c0W, c0b,
                                  dWih, dbih, dbhh, out_tw, dh0, dc0, decpre);
  k_dec_mfma<<<64, 448, 0, stream>>>(decpre, dWhh, dh0, dc0, dech);
  k_out<<<2048, 256, 0, stream>>>(dech, oW, ob, out0);
}

// Round 6
// 823.568 us; speedup vs baseline: 1.2123x; 1.0020x over previous
//
#include <hip/hip_runtime.h>
#include <hip/hip_fp16.h>

#define BB 1024
#define SS 128
#define FF 64
#define HH 100

typedef _Float16 h8 __attribute__((ext_vector_type(8)));
typedef _Float16 h4 __attribute__((ext_vector_type(4)));
typedef float f4v __attribute__((ext_vector_type(4)));

// --- fast transcendentals ---------------------------------------------------
// v_rcp_f32 (~1 ulp); fp32 '/' without fast-math is ~11 VALU ops (R5: -32%).
// exp2-domain gates (R6): __expf = v_mul(1/ln2)+v_exp (v_exp IS 2^x). Folding
// the 1/ln2 (and sign / tanh's 2x) into the f16 weight fragments + biases at
// build time makes sigma/tanh start directly at v_exp_f32: saves 4 VALU
// ops/cell and shortens the serial trans chain in the LSTM recurrence.
#define S_SIG  (-1.4426950408889634f)   // i,f,o rows: acc = -z/ln2
#define S_TANH ( 2.8853900817779268f)   // g rows:     acc = 2z/ln2
__device__ __forceinline__ float frcp(float x){ return __builtin_amdgcn_rcpf(x); }
__device__ __forceinline__ float fexp2(float x){ return __builtin_amdgcn_exp2f(x); }
__device__ __forceinline__ float sigm2(float a){ return frcp(1.f + fexp2(a)); }        // a = -z/ln2
__device__ __forceinline__ float tanh2(float a){ return 1.f - 2.f*frcp(fexp2(a)+1.f);} // a = 2z/ln2
__device__ __forceinline__ float ftanh(float x){ return tanh2(x*S_TANH); }             // unscaled arg

// LDS-only barrier: waits own LDS ops, does NOT drain vmcnt (global stores
// stay in flight across steps).
#define LDS_BARRIER() __asm__ __volatile__("s_waitcnt lgkmcnt(0)\ns_barrier" ::: "memory")

__device__ __forceinline__ float wsum(float v){
#pragma unroll
  for (int m = 32; m >= 1; m >>= 1) v += __shfl_xor(v, m, 64);
  return v;
}
__device__ __forceinline__ float wmax(float v){
#pragma unroll
  for (int m = 32; m >= 1; m >>= 1) v = fmaxf(v, __shfl_xor(v, m, 64));
  return v;
}

// ---------------- gram: gram[b,i,j] = sum_s x[b,s,i]*x[b,s,j] ----------------
__global__ __launch_bounds__(256) void k_gram(const float* __restrict__ x, float* __restrict__ gram){
  __shared__ __align__(16) float xs[SS*FF];
  int b = blockIdx.x, tid = threadIdx.x;
  const float* xb = x + (size_t)b*SS*FF;
  for (int i = tid; i < SS*FF/4; i += 256)
    ((float4*)xs)[i] = ((const float4*)xb)[i];
  __syncthreads();
  int ti = (tid & 15) * 4, tj = (tid >> 4) * 4;
  float acc[4][4];
#pragma unroll
  for (int a=0;a<4;++a)
#pragma unroll
    for (int c=0;c<4;++c) acc[a][c]=0.f;
  for (int s = 0; s < SS; ++s) {
    const float* row = xs + s*FF;
    float4 av = *(const float4*)(row + ti);
    float4 bv = *(const float4*)(row + tj);
    float aa[4] = {av.x,av.y,av.z,av.w};
    float bb2[4] = {bv.x,bv.y,bv.z,bv.w};
#pragma unroll
    for (int a=0;a<4;++a)
#pragma unroll
      for (int c=0;c<4;++c) acc[a][c] += aa[a]*bb2[c];
  }
  float* g = gram + (size_t)b*4096;
#pragma unroll
  for (int a=0;a<4;++a)
#pragma unroll
    for (int c=0;c<4;++c) g[(ti+a)*64 + tj + c] = acc[a][c];
}

// ------- conv1(3x3,1->16,SAME)+bias+relu+maxpool2 -> half CHANNEL-LAST [B][p][ic] -------
__global__ __launch_bounds__(256) void k_conv1pool(const float* __restrict__ gram,
    const float* __restrict__ c1w, const float* __restrict__ c1b, __half* __restrict__ pool1){
  __shared__ float img2[66*66];
  __shared__ float ws1[144];
  __shared__ float bs1[16];
  int tid=threadIdx.x, b=blockIdx.x;
  for (int i=tid;i<66*66;i+=256) img2[i]=0.f;
  if (tid<144) ws1[tid]=c1w[tid];
  if (tid<16) bs1[tid]=c1b[tid];
  __syncthreads();
  const float* gb = gram + (size_t)b*4096;
  for (int i=tid;i<4096;i+=256){ int y=i>>6, xx=i&63; img2[(y+1)*66 + xx+1] = gb[i]; }
  __syncthreads();
  int oc = tid>>4, slot = tid&15;
  float wr[9];
#pragma unroll
  for (int t=0;t<9;++t) wr[t]=ws1[oc*9+t];
  float bo = bs1[oc];
  for (int p=slot;p<1024;p+=16){
    int py=p>>5, px=p&31;
    int y0=py*2, x0=px*2;
    float v[4][4];
#pragma unroll
    for (int wy=0;wy<4;++wy)
#pragma unroll
      for (int wxx=0;wxx<4;++wxx) v[wy][wxx]=img2[(y0+wy)*66 + x0+wxx];
    float s00=bo,s01=bo,s10=bo,s11=bo;
#pragma unroll
    for (int ky=0;ky<3;++ky)
#pragma unroll
      for (int kx=0;kx<3;++kx){
        float w=wr[ky*3+kx];
        s00 += v[ky][kx]*w;   s01 += v[ky][kx+1]*w;
        s10 += v[ky+1][kx]*w; s11 += v[ky+1][kx+1]*w;
      }
    float mx = fmaxf(fmaxf(s00,s01),fmaxf(s10,s11));
    pool1[(size_t)b*16384 + p*16 + oc] = __float2half(fmaxf(mx,0.f));
  }
}

// ================= conv2 as implicit-im2col MFMA GEMM =================
__global__ __launch_bounds__(512, 4) void k_conv2mfma(const __half* __restrict__ pool1,
    const float* __restrict__ c2w, const float* __restrict__ c2b, float* __restrict__ proc){
  __shared__ __align__(16) _Float16 img[(34*34+1)*24];   // +1 zero slot
  __shared__ float red[8][32];
  int b = blockIdx.x, tid = threadIdx.x;
  int wv = tid>>6, l = tid&63, lm = l&15, lq = l>>4;
  h8 bfr[2][5];
  float biasv[2];
#pragma unroll
  for (int nt=0; nt<2; ++nt){
    int oc = nt*16 + lm;
    biasv[nt] = c2b[oc];
#pragma unroll
    for (int c=0;c<5;++c){
      h8 f;
#pragma unroll
      for (int j=0;j<8;++j){
        int k = c*32 + lq*8 + j;
        int tap = k>>4, ic = k&15;
        f[j] = (_Float16)((tap<9) ? c2w[oc*144 + ic*9 + tap] : 0.f);
      }
      bfr[nt][c]=f;
    }
  }
  {
    h8 z = {0,0,0,0,0,0,0,0};
    for (int i=tid; i<(34*34+1)*3; i+=512) ((h8*)img)[i] = z;
  }
  __syncthreads();
  const __half* src = pool1 + (size_t)b*16384;
  for (int pp=tid; pp<1024; pp+=512){
    int y=pp>>5, x=pp&31;
    const h8* s = (const h8*)(src + pp*16);
    h8* d = (h8*)&img[((y+1)*34 + (x+1))*24];
    d[0]=s[0]; d[1]=s[1];
  }
  __syncthreads();
  f4v ssum0 = {0,0,0,0}, ssum1 = {0,0,0,0};
#pragma unroll 2
  for (int i=0;i<8;++i){
    int mt = wv + i*8;
    int y = mt>>1, x0 = (mt&1)*16;
    h8 afr[5];
#pragma unroll
    for (int c=0;c<5;++c){
      int tap = 2*c + (lq>>1);
      int addr;
      if (c==4 && lq>=2) addr = 34*34*24;
      else {
        int dy = tap/3 - 1, dx = tap - (tap/3)*3 - 1;
        addr = ((y+dy+1)*34 + (x0+lm+dx+1))*24 + (lq&1)*8;
      }
      afr[c] = *(const h8*)&img[addr];
    }
    f4v a0 = {biasv[0],biasv[0],biasv[0],biasv[0]};
    f4v a1 = {biasv[1],biasv[1],biasv[1],biasv[1]};
#pragma unroll
    for (int c=0;c<5;++c){
      a0 = __builtin_amdgcn_mfma_f32_16x16x32_f16(afr[c], bfr[0][c], a0, 0,0,0);
      a1 = __builtin_amdgcn_mfma_f32_16x16x32_f16(afr[c], bfr[1][c], a1, 0,0,0);
    }
#pragma unroll
    for (int r=0;r<4;++r){
      ssum0[r] += fmaxf(a0[r],0.f);
      ssum1[r] += fmaxf(a1[r],0.f);
    }
  }
  float s0 = ssum0[0]+ssum0[1]+ssum0[2]+ssum0[3];
  float s1 = ssum1[0]+ssum1[1]+ssum1[2]+ssum1[3];
  s0 += __shfl_xor(s0,16,64); s0 += __shfl_xor(s0,32,64);
  s1 += __shfl_xor(s1,16,64); s1 += __shfl_xor(s1,32,64);
  if (lq==0){ red[wv][lm]=s0; red[wv][16+lm]=s1; }
  __syncthreads();
  if (tid<32){
    float t=0.f;
#pragma unroll
    for (int w2=0;w2<8;++w2) t += red[w2][tid];
    proc[b*32+tid] = t*(1.f/1024.f);
  }
}

// ------------- fs = tanh(x@fW1^T+fb1)@fW2^T+fb2, per (b,s) row -------------
// Layer-1 weights/bias staged pre-scaled by 2/ln2 -> tanh2 (no mul).
__global__ __launch_bounds__(256) void k_fs(const float* __restrict__ x,
    const float* __restrict__ fW1, const float* __restrict__ fb1,
    const float* __restrict__ fW2, const float* __restrict__ fb2,
    float* __restrict__ fs){
  __shared__ float w1t[64*32];
  __shared__ float w2t[32*64];
  __shared__ float b1s[32], b2s[64];
  __shared__ __align__(16) float xbuf[4][8][64];
  __shared__ float t1buf[4][8][32];
  int tid=threadIdx.x, wv=tid>>6, lane=tid&63;
  for (int i=tid;i<2048;i+=256){ int j=i>>6,k=i&63; w1t[k*32+j]=fW1[i]*S_TANH; }
  for (int i=tid;i<2048;i+=256){ int j=i>>5,k=i&31; w2t[k*64+j]=fW2[i]; }
  if (tid<32) b1s[tid]=fb1[tid]*S_TANH;
  if (tid<64) b2s[tid]=fb2[tid];
  __syncthreads();
  size_t Rw = (size_t)blockIdx.x*64 + wv*16;
  int j = lane & 31, half = lane >> 5;
  for (int pass=0; pass<2; ++pass){
    size_t R0 = Rw + pass*8;
    const float4* src = (const float4*)(x + R0*64);
    float4* dst = (float4*)&xbuf[wv][0][0];
    for (int i=lane;i<128;i+=64) dst[i]=src[i];
    __syncthreads();
    {
      float a0=b1s[j],a1=b1s[j],a2=b1s[j],a3=b1s[j];
      const float* xr = &xbuf[wv][half*4][0];
      for (int k=0;k<64;++k){
        float w = w1t[k*32+j];
        a0 += w*xr[k]; a1 += w*xr[64+k]; a2 += w*xr[128+k]; a3 += w*xr[192+k];
      }
      float* t1r = &t1buf[wv][half*4][0];
      t1r[j]=tanh2(a0); t1r[32+j]=tanh2(a1); t1r[64+j]=tanh2(a2); t1r[96+j]=tanh2(a3);
    }
    __syncthreads();
    {
      float f[8];
#pragma unroll
      for (int r=0;r<8;++r) f[r]=b2s[lane];
      for (int k=0;k<32;++k){
        float w = w2t[k*64+lane];
#pragma unroll
        for (int r=0;r<8;++r) f[r] += w*t1buf[wv][r][k];
      }
#pragma unroll
      for (int r=0;r<8;++r) fs[(R0+r)*64 + lane] = f[r];
    }
    __syncthreads();
  }
}

// ------- aw = tanh([fs,proc]@cW1^T+cb1)@cW2^T+cb2; feature_w=softmax(aw); wx=x*fw -------
// Layer-1 weights/bias staged pre-scaled by 2/ln2 -> tanh2.
__global__ __launch_bounds__(256) void k_attnmlp(const float* __restrict__ x,
    const float* __restrict__ fs, const float* __restrict__ proc,
    const float* __restrict__ cW1, const float* __restrict__ cb1,
    const float* __restrict__ cW2, const float* __restrict__ cb2,
    float* __restrict__ fw_out, float* __restrict__ wx){
  __shared__ float c1t[96*64];
  __shared__ float c2t[64*64];
  __shared__ float cb1s[64], cb2s[64];
  __shared__ float cmb[4][4][96];
  __shared__ float h2b[4][4][64];
  int tid = threadIdx.x, wv = tid>>6, lane = tid&63;
  for (int i = tid; i < 6144; i += 256){ int j = i/96, k = i%96; c1t[k*64+j] = cW1[i]*S_TANH; }
  for (int i = tid; i < 4096; i += 256){ int j = i>>6, k = i&63; c2t[k*64+j] = cW2[i]; }
  if (tid < 64) { cb1s[tid] = cb1[tid]*S_TANH; cb2s[tid] = cb2[tid]; }
  __syncthreads();
  size_t Rw = (size_t)blockIdx.x*64 + wv*16;
  for (int pass = 0; pass < 4; ++pass) {
    size_t R0 = Rw + pass*4;
    for (int i = lane; i < 384; i += 64) {
      int r = i/96, k = i%96;
      size_t R = R0 + r;
      cmb[wv][r][k] = (k < 64) ? fs[R*64 + k] : proc[(R>>7)*32 + (k-64)];
    }
    __syncthreads();
    float h0a=cb1s[lane],h1a=cb1s[lane],h2a=cb1s[lane],h3a=cb1s[lane];
    for (int k = 0; k < 96; ++k) {
      float w = c1t[k*64+lane];
      h0a += w*cmb[wv][0][k]; h1a += w*cmb[wv][1][k];
      h2a += w*cmb[wv][2][k]; h3a += w*cmb[wv][3][k];
    }
    h2b[wv][0][lane]=tanh2(h0a); h2b[wv][1][lane]=tanh2(h1a);
    h2b[wv][2][lane]=tanh2(h2a); h2b[wv][3][lane]=tanh2(h3a);
    __syncthreads();
    float a0=cb2s[lane],a1=cb2s[lane],a2=cb2s[lane],a3=cb2s[lane];
    for (int k = 0; k < 64; ++k) {
      float w = c2t[k*64+lane];
      a0 += w*h2b[wv][0][k]; a1 += w*h2b[wv][1][k];
      a2 += w*h2b[wv][2][k]; a3 += w*h2b[wv][3][k];
    }
    float m0=wmax(a0), m1=wmax(a1), m2=wmax(a2), m3=wmax(a3);
    float e0=__expf(a0-m0), e1=__expf(a1-m1), e2=__expf(a2-m2), e3=__expf(a3-m3);
    float s0=wsum(e0), s1=wsum(e1), s2=wsum(e2), s3=wsum(e3);
    float f0v=e0*frcp(s0), f1v=e1*frcp(s1), f2v=e2*frcp(s2), f3v=e3*frcp(s3);
    size_t R;
    R=R0+0; fw_out[R*64+lane]=f0v; wx[R*64+lane]=x[R*64+lane]*f0v;
    R=R0+1; fw_out[R*64+lane]=f1v; wx[R*64+lane]=x[R*64+lane]*f1v;
    R=R0+2; fw_out[R*64+lane]=f2v; wx[R*64+lane]=x[R*64+lane]*f2v;
    R=R0+3; fw_out[R*64+lane]=f3v; wx[R*64+lane]=x[R*64+lane]*f3v;
    __syncthreads();
  }
}

// ================= MFMA encoder LSTM (swapped operands) =================
// 7 waves, 16 batches/block, 64 blocks (N=16 MFMA batch cols pins grid at 64;
// M/K splits would need per-step cross-block h exchange; 512-reg/SIMD file
// caps 2 waves/SIMD with weights in AGPRs -> per-wave issue + chain length
// are the only levers). R6: (a) gate weights/biases pre-scaled into exp2
// domain (i,f,o rows * -1/ln2; g rows * 2/ln2) so sigma/tanh start at
// v_exp_f32 directly; (b) 6-deep MFMA chain split into two 3-deep chains
// + v_add (cuts ~2-3 MFMA latencies off the step critical path).
// ench: f16 copy of enc, row-padded to 112 (units 100..111 zeroed).
__global__ __launch_bounds__(448) void k_enc_mfma(const float* __restrict__ wx,
    const float* __restrict__ Wih, const float* __restrict__ Whh,
    const float* __restrict__ bih, const float* __restrict__ bhh,
    _Float16* __restrict__ ench){
  __shared__ __align__(16) _Float16 hbuf[2][16*128];
  __shared__ __align__(16) _Float16 xst[2][16*64];
  int tid = threadIdx.x;
  int w = tid >> 6, l = tid & 63;
  int lm = l & 15, lq = l >> 4;
  int b0 = blockIdx.x * 16;
  int au = w*16 + lm;
  bool avalid = au < 100;
  int u0 = w*16 + lq*4;
  bool uvalid = (u0 + 3) < 100;
  const float gsc[4] = {S_SIG, S_SIG, S_TANH, S_SIG};   // gate order i,f,g,o
  h8 wfr[4][6];
#pragma unroll
  for (int tt=0; tt<4; ++tt){
    int row = tt*100 + au;
#pragma unroll
    for (int cc=0; cc<6; ++cc){
      h8 f;
#pragma unroll
      for (int j=0;j<8;++j){
        int kg = cc*32 + lq*8 + j;
        float v = 0.f;
        if (avalid){
          if (kg < 64) v = Wih[(size_t)row*64 + kg];
          else { int kh = kg - 64; if (kh < 100) v = Whh[(size_t)row*100 + kh]; }
        }
        f[j] = (_Float16)(v*gsc[tt]);
      }
      wfr[tt][cc] = f;
    }
  }
  f4v biasv[4];
#pragma unroll
  for (int tt=0; tt<4; ++tt){
    if (uvalid){
      float4 bi = *(const float4*)&bih[tt*100 + u0];
      float4 bh = *(const float4*)&bhh[tt*100 + u0];
      float s = gsc[tt];
      f4v bv2 = {(bi.x+bh.x)*s, (bi.y+bh.y)*s, (bi.z+bh.z)*s, (bi.w+bh.w)*s};
      biasv[tt] = bv2;
    } else { f4v z = {0,0,0,0}; biasv[tt] = z; }
  }
  for (int i = tid; i < 2*16*128; i += 448) hbuf[0][i] = (_Float16)0.f;
  int sm = tid >> 4, skq = tid & 15;
  bool doPref = (tid < 256);
  float4 rA, rB;
  if (doPref){
    float4 xv0 = *(const float4*)(wx + ((size_t)(b0+sm)*SS + 0)*FF + skq*4);
    h4 p = {(_Float16)xv0.x,(_Float16)xv0.y,(_Float16)xv0.z,(_Float16)xv0.w};
    *(h4*)&xst[0][sm*64 + (((skq>>1) ^ (sm&7))<<3) + (skq&1)*4] = p;
    rA = *(const float4*)(wx + ((size_t)(b0+sm)*SS + 1)*FF + skq*4);   // x(1)
  }
  float cst[4] = {0.f,0.f,0.f,0.f};
  int hwaddr = lm*128 + (((2*w + (lq>>1)) ^ (lm&7))<<3) + (lq&1)*4;
  int xwaddr = sm*64 + (((skq>>1) ^ (sm&7))<<3) + (skq&1)*4;
  __syncthreads();

#define ENC_STEP(T, CUR, RCONS, RISSUE)                                          \
  {                                                                              \
    const int cur = (CUR), nxt = (CUR)^1;                                        \
    if (doPref && (T) < SS-2)                                                    \
      RISSUE = *(const float4*)(wx + ((size_t)(b0+sm)*SS + ((T)+2))*FF + skq*4); \
    h8 bact[6];                                                                  \
    _Pragma("unroll")                                                            \
    for (int cc=0; cc<2; ++cc)                                                   \
      bact[cc] = *(const h8*)&xst[cur][lm*64 + (((cc*4+lq) ^ (lm&7))<<3)];       \
    _Pragma("unroll")                                                            \
    for (int cc=0; cc<4; ++cc)                                                   \
      bact[2+cc] = *(const h8*)&hbuf[cur][lm*128 + (((cc*4+lq) ^ (lm&7))<<3)];   \
    f4v acc[4];                                                                  \
    __builtin_amdgcn_s_setprio(1);                                               \
    _Pragma("unroll")                                                            \
    for (int tt=0; tt<4; ++tt){                                                  \
      f4v a1 = biasv[tt];                                                        \
      f4v a2 = {0.f,0.f,0.f,0.f};                                                \
      a1 = __builtin_amdgcn_mfma_f32_16x16x32_f16(wfr[tt][0], bact[0], a1, 0,0,0); \
      a2 = __builtin_amdgcn_mfma_f32_16x16x32_f16(wfr[tt][1], bact[1], a2, 0,0,0); \
      a1 = __builtin_amdgcn_mfma_f32_16x16x32_f16(wfr[tt][2], bact[2], a1, 0,0,0); \
      a2 = __builtin_amdgcn_mfma_f32_16x16x32_f16(wfr[tt][3], bact[3], a2, 0,0,0); \
      a1 = __builtin_amdgcn_mfma_f32_16x16x32_f16(wfr[tt][4], bact[4], a1, 0,0,0); \
      a2 = __builtin_amdgcn_mfma_f32_16x16x32_f16(wfr[tt][5], bact[5], a2, 0,0,0); \
      acc[tt] = a1 + a2;                                                         \
    }                                                                            \
    __builtin_amdgcn_s_setprio(0);                                               \
    float hn[4];                                                                 \
    _Pragma("unroll")                                                            \
    for (int r=0;r<4;++r){                                                       \
      float cn = sigm2(acc[1][r])*cst[r] + sigm2(acc[0][r])*tanh2(acc[2][r]);    \
      hn[r] = sigm2(acc[3][r])*tanh2(cn*S_TANH);                                 \
      cst[r] = cn;                                                               \
    }                                                                            \
    if (uvalid){                                                                 \
      h4 hp = {(_Float16)hn[0],(_Float16)hn[1],(_Float16)hn[2],(_Float16)hn[3]}; \
      *(h4*)&hbuf[nxt][hwaddr] = hp;                                             \
      *(h4*)&ench[((size_t)(b0+lm)*SS + (T))*112 + u0] = hp;                     \
    } else {                                                                     \
      h4 z = {(_Float16)0.f,(_Float16)0.f,(_Float16)0.f,(_Float16)0.f};          \
      *(h4*)&ench[((size_t)(b0+lm)*SS + (T))*112 + u0] = z;                      \
    }                                                                            \
    if (doPref && (T) < SS-1){                                                   \
      h4 p = {(_Float16)RCONS.x,(_Float16)RCONS.y,(_Float16)RCONS.z,(_Float16)RCONS.w}; \
      *(h4*)&xst[nxt][xwaddr] = p;                                               \
    }                                                                            \
    LDS_BARRIER();                                                               \
  }

  for (int t = 0; t < SS; t += 2){
    ENC_STEP(t,   0, rA, rB)   // consumes x(t+1) from rA, issues x(t+2) into rB
    ENC_STEP(t+1, 1, rB, rA)   // consumes x(t+2) from rB, issues x(t+3) into rA
  }
#undef ENC_STEP
}

// ================= ts GEMM: ts[b,s] = aW2 @ tanh(aW1 @ enc_row + ab1) + ab2 ========
// M = B*S rows (ench f16, 112-padded), N = 64, K = 100->128 (chunk 3 half-zero).
// aW1/ab1 pre-scaled by 2/ln2 -> tanh2 on the MFMA output directly.
__global__ __launch_bounds__(256) void k_ts(const _Float16* __restrict__ ench,
    const float* __restrict__ aW1, const float* __restrict__ ab1,
    const float* __restrict__ aW2, const float* __restrict__ ab2,
    float* __restrict__ ts){
  int tid = threadIdx.x, wv = tid>>6, l = tid&63, lm = l&15, lq = l>>4;
  h8 bfr[4][4];
#pragma unroll
  for (int nt=0; nt<4; ++nt){
    int n = nt*16 + lm;
#pragma unroll
    for (int cc=0; cc<4; ++cc){
      h8 f;
#pragma unroll
      for (int j=0;j<8;++j){
        int k = cc*32 + lq*8 + j;
        f[j] = (_Float16)((k<100) ? aW1[n*100+k]*S_TANH : 0.f);
      }
      bfr[nt][cc]=f;
    }
  }
  float ab1v[4], aw2v[4];
#pragma unroll
  for (int nt=0; nt<4; ++nt){ ab1v[nt] = ab1[nt*16+lm]*S_TANH; aw2v[nt] = aW2[nt*16+lm]; }
  float ab2v = ab2[0];
  int tile0 = (blockIdx.x*4 + wv)*4;
#pragma unroll
  for (int i=0;i<4;++i){
    int M0 = (tile0+i)*16;
    const _Float16* rowp = ench + (size_t)(M0+lm)*112;
    h8 afr[4];
#pragma unroll
    for (int cc=0; cc<3; ++cc)
      afr[cc] = *(const h8*)(rowp + cc*32 + lq*8);
    if (lq < 2) afr[3] = *(const h8*)(rowp + 96 + lq*8);
    else { h8 z={0,0,0,0,0,0,0,0}; afr[3]=z; }
    f4v acc[4];
#pragma unroll
    for (int nt=0; nt<4; ++nt){
      f4v a = {ab1v[nt],ab1v[nt],ab1v[nt],ab1v[nt]};
#pragma unroll
      for (int cc=0; cc<4; ++cc)
        a = __builtin_amdgcn_mfma_f32_16x16x32_f16(afr[cc], bfr[nt][cc], a, 0,0,0);
      acc[nt]=a;
    }
    float p[4];
#pragma unroll
    for (int r=0;r<4;++r){
      p[r] = aw2v[0]*tanh2(acc[0][r]) + aw2v[1]*tanh2(acc[1][r])
           + aw2v[2]*tanh2(acc[2][r]) + aw2v[3]*tanh2(acc[3][r]);
#pragma unroll
      for (int m=1;m<16;m<<=1) p[r] += __shfl_xor(p[r], m, 64);
    }
    if (lm==0){
      float4 st; st.x=p[0]+ab2v; st.y=p[1]+ab2v; st.z=p[2]+ab2v; st.w=p[3]+ab2v;
      *(float4*)&ts[M0 + lq*4] = st;
    }
  }
}

// ------- per-b: softmax(ts) over S, ctx, bott, dh0, dc0, decpre -------
// ctx accumulated from ench (f16): h already round-trips f16 in the
// recurrence, added error ~5e-5.
__global__ __launch_bounds__(256) void k_attn2(const _Float16* __restrict__ ench,
    const float* __restrict__ ts,
    const float* __restrict__ bW, const float* __restrict__ bb_,
    const float* __restrict__ h0W, const float* __restrict__ h0b,
    const float* __restrict__ c0W, const float* __restrict__ c0b,
    const float* __restrict__ dWih, const float* __restrict__ dbih, const float* __restrict__ dbhh,
    float* __restrict__ tw_out, float* __restrict__ dh0, float* __restrict__ dc0,
    float* __restrict__ decpre){
  __shared__ float tsb[SS];
  __shared__ float ctxb[HH];
  __shared__ float bottb[32];
  __shared__ float red[8];
  int tid = threadIdx.x, wv = tid>>6, lane = tid&63;
  int b = blockIdx.x;
  const _Float16* encb = ench + (size_t)b*SS*112;
  float tv = (tid < SS) ? ts[(size_t)b*SS + tid] : -1e30f;
  float m = wmax(tv);
  if (lane==0) red[wv]=m;
  __syncthreads();
  m = fmaxf(fmaxf(red[0],red[1]), fmaxf(red[2],red[3]));
  float e = (tid < SS) ? __expf(tv - m) : 0.f;
  float sm = wsum(e);
  if (lane==0) red[4+wv]=sm;
  __syncthreads();
  float denom = red[4]+red[5]+red[6]+red[7];
  float rden = frcp(denom);
  if (tid < SS){
    float twv = e*rden;
    tw_out[(size_t)b*SS + tid] = twv;
    tsb[tid] = twv;
  }
  __syncthreads();
  if (tid < HH){
    float a = 0.f;
#pragma unroll 4
    for (int s=0;s<SS;++s) a += tsb[s]*(float)encb[s*112 + tid];
    ctxb[tid]=a;
  }
  __syncthreads();
  if (tid < 32){
    float a = bb_[tid];
    const float* wr = bW + tid*HH;
    for (int k=0;k<HH;++k) a += wr[k]*ctxb[k];
    bottb[tid]=a;
  }
  __syncthreads();
  if (tid < HH){
    float a = h0b[tid];
    const float* wr = h0W + tid*32;
#pragma unroll
    for (int k=0;k<32;++k) a += wr[k]*bottb[k];
    dh0[(size_t)b*HH + tid] = a;
  } else if (tid < 200){
    int jj = tid-100;
    float a = c0b[jj];
    const float* wr = c0W + jj*32;
#pragma unroll
    for (int k=0;k<32;++k) a += wr[k]*bottb[k];
    dc0[(size_t)b*HH + jj] = a;
  }
  {
    int jj = tid;
    float a = dbih[jj]+dbhh[jj];
    const float* wr = dWih + jj*32;
#pragma unroll
    for (int k=0;k<32;++k) a += wr[k]*bottb[k];
    decpre[(size_t)b*400 + jj] = a;
    jj = tid + 256;
    if (jj < 400){
      float a2v = dbih[jj]+dbhh[jj];
      const float* wr2 = dWih + jj*32;
#pragma unroll
      for (int k=0;k<32;++k) a2v += wr2[k]*bottb[k];
      decpre[(size_t)b*400 + jj] = a2v;
    }
  }
}

// ================= MFMA decoder LSTM (swapped operands) =================
// f16 dech output; exp2-domain gates (wfr + pre scaled); 4-chunk chain split
// into two 2-deep chains + add.
__global__ __launch_bounds__(448) void k_dec_mfma(const float* __restrict__ decpre,
    const float* __restrict__ Whh,
    const float* __restrict__ dh0, const float* __restrict__ dc0,
    _Float16* __restrict__ dech){
  __shared__ __align__(16) _Float16 hbuf[2][16*128];
  int tid = threadIdx.x;
  int w = tid >> 6, l = tid & 63;
  int lm = l & 15, lq = l >> 4;
  int b0 = blockIdx.x * 16;
  int au = w*16 + lm;
  bool avalid = au < 100;
  int u0 = w*16 + lq*4;
  bool uvalid = (u0 + 3) < 100;
  const float gsc[4] = {S_SIG, S_SIG, S_TANH, S_SIG};
  h8 wfr[4][4];
#pragma unroll
  for (int tt = 0; tt < 4; ++tt){
    int row = tt*100 + au;
#pragma unroll
    for (int cc = 0; cc < 4; ++cc){
      h8 f;
#pragma unroll
      for (int j = 0; j < 8; ++j){
        int kh = cc*32 + lq*8 + j;
        float v = (avalid && kh < 100) ? Whh[(size_t)row*100 + kh] : 0.f;
        f[j] = (_Float16)(v*gsc[tt]);
      }
      wfr[tt][cc] = f;
    }
  }
  f4v pre[4];
  float cst[4] = {0.f,0.f,0.f,0.f};
  if (uvalid){
#pragma unroll
    for (int tt = 0; tt < 4; ++tt){
      float4 p = *(const float4*)&decpre[(size_t)(b0+lm)*400 + tt*100 + u0];
      float s = gsc[tt];
      f4v pv = {p.x*s, p.y*s, p.z*s, p.w*s};
      pre[tt] = pv;
    }
    float4 c4 = *(const float4*)&dc0[(size_t)(b0+lm)*100 + u0];
    cst[0]=c4.x; cst[1]=c4.y; cst[2]=c4.z; cst[3]=c4.w;
  } else {
    f4v z = {0,0,0,0};
#pragma unroll
    for (int tt = 0; tt < 4; ++tt) pre[tt] = z;
  }
  for (int i = tid; i < 16*128; i += 448) hbuf[1][i] = (_Float16)0.f;
  for (int idx = tid; idx < 16*128; idx += 448){
    int m = idx >> 7, u2 = idx & 127;
    float v = (u2 < 100) ? dh0[(size_t)(b0+m)*HH + u2] : 0.f;
    hbuf[0][m*128 + (((u2>>3) ^ (m&7))<<3) + (u2&7)] = (_Float16)v;
  }
  int hwaddr = lm*128 + (((2*w + (lq>>1)) ^ (lm&7))<<3) + (lq&1)*4;
  __syncthreads();

#define DEC_STEP(T, CUR)                                                         \
  {                                                                              \
    const int cur = (CUR), nxt = (CUR)^1;                                        \
    h8 bact[4];                                                                  \
    _Pragma("unroll")                                                            \
    for (int cc = 0; cc < 4; ++cc)                                               \
      bact[cc] = *(const h8*)&hbuf[cur][lm*128 + (((cc*4+lq) ^ (lm&7))<<3)];     \
    f4v acc[4];                                                                  \
    __builtin_amdgcn_s_setprio(1);                                               \
    _Pragma("unroll")                                                            \
    for (int tt = 0; tt < 4; ++tt){                                              \
      f4v a1 = pre[tt];                                                          \
      f4v a2 = {0.f,0.f,0.f,0.f};                                                \
      a1 = __builtin_amdgcn_mfma_f32_16x16x32_f16(wfr[tt][0], bact[0], a1, 0,0,0); \
      a2 = __builtin_amdgcn_mfma_f32_16x16x32_f16(wfr[tt][1], bact[1], a2, 0,0,0); \
      a1 = __builtin_amdgcn_mfma_f32_16x16x32_f16(wfr[tt][2], bact[2], a1, 0,0,0); \
      a2 = __builtin_amdgcn_mfma_f32_16x16x32_f16(wfr[tt][3], bact[3], a2, 0,0,0); \
      acc[tt] = a1 + a2;                                                         \
    }                                                                            \
    __builtin_amdgcn_s_setprio(0);                                               \
    float hn[4];                                                                 \
    _Pragma("unroll")                                                            \
    for (int r=0;r<4;++r){                                                       \
      float cn = sigm2(acc[1][r])*cst[r] + sigm2(acc[0][r])*tanh2(acc[2][r]);    \
      hn[r] = sigm2(acc[3][r])*tanh2(cn*S_TANH);                                 \
      cst[r] = cn;                                                               \
    }                                                                            \
    if (uvalid){                                                                 \
      h4 hp = {(_Float16)hn[0],(_Float16)hn[1],(_Float16)hn[2],(_Float16)hn[3]}; \
      *(h4*)&hbuf[nxt][hwaddr] = hp;                                             \
      *(h4*)&dech[((size_t)(b0+lm)*SS + (T))*112 + u0] = hp;                     \
    }                                                                            \
    LDS_BARRIER();                                                               \
  }

  for (int t = 0; t < SS; t += 2){
    DEC_STEP(t,   0)
    DEC_STEP(t+1, 1)
  }
#undef DEC_STEP
}

// ------------- out = dec @ oW^T + ob (dec consumed as f16 dech) -------------
__global__ __launch_bounds__(256) void k_out(const _Float16* __restrict__ dech,
    const float* __restrict__ oW, const float* __restrict__ ob, float* __restrict__ out0){
  __shared__ float oWt[100*64];
  __shared__ float dsr[64*112];
  int tid=threadIdx.x;
  size_t R0 = (size_t)blockIdx.x*64;
  for (int i=tid;i<6400;i+=256){ int j=i/100,k=i%100; oWt[k*64+j]=oW[i]; }
  {
    const h8* db = (const h8*)(dech + R0*112);
    for (int i=tid;i<896;i+=256){
      h8 v = db[i];
      float* d = dsr + i*8;
#pragma unroll
      for (int j=0;j<8;++j) d[j] = (float)v[j];
    }
  }
  __syncthreads();
  int j = tid&63, rb = tid>>6;
  float acc[16];
#pragma unroll
  for (int i=0;i<16;++i) acc[i]=0.f;
  for (int k=0;k<100;++k){
    float w = oWt[k*64+j];
#pragma unroll
    for (int i=0;i<16;++i) acc[i] += w*dsr[(rb + i*4)*112 + k];
  }
  float obv = ob[j];
#pragma unroll
  for (int i=0;i<16;++i) out0[(R0 + rb + i*4)*64 + j] = acc[i] + obv;
}

extern "C" void kernel_launch(void* const* d_in, const int* in_sizes, int n_in,
                              void* d_out, int out_size, void* d_ws, size_t ws_size,
                              hipStream_t stream) {
  const float* x    = (const float*)d_in[0];
  const float* c1w  = (const float*)d_in[1];
  const float* c1b  = (const float*)d_in[2];
  const float* c2w  = (const float*)d_in[3];
  const float* c2b  = (const float*)d_in[4];
  const float* fW1  = (const float*)d_in[5];
  const float* fb1  = (const float*)d_in[6];
  const float* fW2  = (const float*)d_in[7];
  const float* fb2  = (const float*)d_in[8];
  const float* cW1  = (const float*)d_in[9];
  const float* cb1  = (const float*)d_in[10];
  const float* cW2  = (const float*)d_in[11];
  const float* cb2  = (const float*)d_in[12];
  const float* eWih = (const float*)d_in[13];
  const float* eWhh = (const float*)d_in[14];
  const float* ebih = (const float*)d_in[15];
  const float* ebhh = (const float*)d_in[16];
  const float* aW1  = (const float*)d_in[17];
  const float* ab1  = (const float*)d_in[18];
  const float* aW2  = (const float*)d_in[19];
  const float* ab2  = (const float*)d_in[20];
  const float* bW   = (const float*)d_in[21];
  const float* bb   = (const float*)d_in[22];
  const float* h0W  = (const float*)d_in[23];
  const float* h0b  = (const float*)d_in[24];
  const float* c0W  = (const float*)d_in[25];
  const float* c0b  = (const float*)d_in[26];
  const float* dWih = (const float*)d_in[27];
  const float* dWhh = (const float*)d_in[28];
  const float* dbih = (const float*)d_in[29];
  const float* dbhh = (const float*)d_in[30];
  const float* oW   = (const float*)d_in[31];
  const float* ob   = (const float*)d_in[32];

  float* out0   = (float*)d_out;
  float* out_tw = out0 + (size_t)BB*SS*FF;
  float* out_fw = out_tw + (size_t)BB*SS;

  char* ws = (char*)d_ws;
  float*  gram   = (float*) (ws + 0);           // 16.78 MB (reused as ts after conv1)
  __half* pool1  = (__half*)(ws + 16777216);    // 33.55 MB (channel-last [b][p][ic])
  float*  proc   = (float*) (ws + 50331648);    // 0.13 MB
  float*  fsbuf  = (float*) (ws + 50462720);    // 33.55 MB (reused as ench after attnmlp)
  float*  wx     = (float*) (ws + 84017152);    // 33.55 MB
  // ws+117571584 (old f32 enc region, 52.43 MB) now unused
  float*  dh0    = (float*) (ws + 170000384);   // 0.41 MB
  float*  dc0    = (float*) (ws + 170409984);   // 0.41 MB
  float*  decpre = (float*) (ws + 170819584);   // 1.64 MB
  _Float16* dech = (_Float16*)(ws + 172457984); // 29.36 MB (f16, [row][112])
  float*     tsbuf = (float*)gram;              // 0.52 MB (gram dead after conv1)
  _Float16*  ench  = (_Float16*)fsbuf;          // 29.36 MB (fsbuf dead after attnmlp)

  k_gram<<<BB, 256, 0, stream>>>(x, gram);
  k_conv1pool<<<BB, 256, 0, stream>>>(gram, c1w, c1b, pool1);
  k_conv2mfma<<<BB, 512, 0, stream>>>(pool1, c2w, c2b, proc);
  k_fs<<<2048, 256, 0, stream>>>(x, fW1, fb1, fW2, fb2, fsbuf);
  k_attnmlp<<<2048, 256, 0, stream>>>(x, fsbuf, proc, cW1, cb1, cW2, cb2, out_fw, wx);
  k_enc_mfma<<<64, 448, 0, stream>>>(wx, eWih, eWhh, ebih, ebhh, ench);
  k_ts<<<512, 256, 0, stream>>>(ench, aW1, ab1, aW2, ab2, tsbuf);
  k_attn2<<<BB, 256, 0, stream>>>(ench, tsbuf, bW, bb, h0W, h0b, c0W, c0b,
                                  dWih, dbih, dbhh, out_tw, dh0, dc0, decpre);
  k_dec_mfma<<<64, 448, 0, stream>>>(decpre, dWhh, dh0, dc0, dech);
  k_out<<<2048, 256, 0, stream>>>(dech, oW, ob, out0);
}

// Round 7
// 799.345 us; speedup vs baseline: 1.2490x; 1.0303x over previous
//
#include <hip/hip_runtime.h>
#include <hip/hip_fp16.h>

#define BB 1024
#define SS 128
#define FF 64
#define HH 100

typedef _Float16 h8 __attribute__((ext_vector_type(8)));
typedef _Float16 h4 __attribute__((ext_vector_type(4)));
typedef float f4v __attribute__((ext_vector_type(4)));

// --- fast transcendentals ---------------------------------------------------
// v_rcp_f32 (~1 ulp); fp32 '/' without fast-math is ~11 VALU ops (R5: -32%).
// exp2-domain gates (R6): fold 1/ln2 (and tanh's 2x) into weights/biases so
// sigma/tanh start at v_exp_f32 directly.
// R7: product fusion sigma(zi)*tanh(zt) = (Et-1)*rcp(1+Ei+Et+Ei*Et) with
// Ei=exp2(-zi/ln2), Et=exp2(2zt/ln2): saves one quarter-rate rcp per product,
// used twice per LSTM cell (i*g and o*tanh(c)) -> -48 cyc/wave of ~530.
#define S_SIG  (-1.4426950408889634f)   // i,f,o rows: acc = -z/ln2
#define S_TANH ( 2.8853900817779268f)   // g rows:     acc = 2z/ln2
__device__ __forceinline__ float frcp(float x){ return __builtin_amdgcn_rcpf(x); }
__device__ __forceinline__ float fexp2(float x){ return __builtin_amdgcn_exp2f(x); }
__device__ __forceinline__ float sigm2(float a){ return frcp(1.f + fexp2(a)); }        // a = -z/ln2
__device__ __forceinline__ float tanh2(float a){ return 1.f - 2.f*frcp(fexp2(a)+1.f);} // a = 2z/ln2
__device__ __forceinline__ float ftanh(float x){ return tanh2(x*S_TANH); }             // unscaled arg
// sigma*tanh from pre-exponentiated Ei, Et:
__device__ __forceinline__ float sigtanh(float Ei, float Et){
  float D = __builtin_fmaf(Ei, Et, Ei) + (Et + 1.f);   // (1+Ei)(1+Et)
  return (Et - 1.f) * frcp(D);
}

// LDS-only barrier: waits own LDS ops, does NOT drain vmcnt (global stores
// stay in flight across steps).
#define LDS_BARRIER() __asm__ __volatile__("s_waitcnt lgkmcnt(0)\ns_barrier" ::: "memory")

__device__ __forceinline__ float wsum(float v){
#pragma unroll
  for (int m = 32; m >= 1; m >>= 1) v += __shfl_xor(v, m, 64);
  return v;
}
__device__ __forceinline__ float wmax(float v){
#pragma unroll
  for (int m = 32; m >= 1; m >>= 1) v = fmaxf(v, __shfl_xor(v, m, 64));
  return v;
}

// ---------------- gram: gram[b,i,j] = sum_s x[b,s,i]*x[b,s,j] ----------------
__global__ __launch_bounds__(256) void k_gram(const float* __restrict__ x, float* __restrict__ gram){
  __shared__ __align__(16) float xs[SS*FF];
  int b = blockIdx.x, tid = threadIdx.x;
  const float* xb = x + (size_t)b*SS*FF;
  for (int i = tid; i < SS*FF/4; i += 256)
    ((float4*)xs)[i] = ((const float4*)xb)[i];
  __syncthreads();
  int ti = (tid & 15) * 4, tj = (tid >> 4) * 4;
  float acc[4][4];
#pragma unroll
  for (int a=0;a<4;++a)
#pragma unroll
    for (int c=0;c<4;++c) acc[a][c]=0.f;
  for (int s = 0; s < SS; ++s) {
    const float* row = xs + s*FF;
    float4 av = *(const float4*)(row + ti);
    float4 bv = *(const float4*)(row + tj);
    float aa[4] = {av.x,av.y,av.z,av.w};
    float bb2[4] = {bv.x,bv.y,bv.z,bv.w};
#pragma unroll
    for (int a=0;a<4;++a)
#pragma unroll
      for (int c=0;c<4;++c) acc[a][c] += aa[a]*bb2[c];
  }
  float* g = gram + (size_t)b*4096;
#pragma unroll
  for (int a=0;a<4;++a)
#pragma unroll
    for (int c=0;c<4;++c) g[(ti+a)*64 + tj + c] = acc[a][c];
}

// ------- conv1(3x3,1->16,SAME)+bias+relu+maxpool2 -> half CHANNEL-LAST [B][p][ic] -------
__global__ __launch_bounds__(256) void k_conv1pool(const float* __restrict__ gram,
    const float* __restrict__ c1w, const float* __restrict__ c1b, __half* __restrict__ pool1){
  __shared__ float img2[66*66];
  __shared__ float ws1[144];
  __shared__ float bs1[16];
  int tid=threadIdx.x, b=blockIdx.x;
  for (int i=tid;i<66*66;i+=256) img2[i]=0.f;
  if (tid<144) ws1[tid]=c1w[tid];
  if (tid<16) bs1[tid]=c1b[tid];
  __syncthreads();
  const float* gb = gram + (size_t)b*4096;
  for (int i=tid;i<4096;i+=256){ int y=i>>6, xx=i&63; img2[(y+1)*66 + xx+1] = gb[i]; }
  __syncthreads();
  int oc = tid>>4, slot = tid&15;
  float wr[9];
#pragma unroll
  for (int t=0;t<9;++t) wr[t]=ws1[oc*9+t];
  float bo = bs1[oc];
  for (int p=slot;p<1024;p+=16){
    int py=p>>5, px=p&31;
    int y0=py*2, x0=px*2;
    float v[4][4];
#pragma unroll
    for (int wy=0;wy<4;++wy)
#pragma unroll
      for (int wxx=0;wxx<4;++wxx) v[wy][wxx]=img2[(y0+wy)*66 + x0+wxx];
    float s00=bo,s01=bo,s10=bo,s11=bo;
#pragma unroll
    for (int ky=0;ky<3;++ky)
#pragma unroll
      for (int kx=0;kx<3;++kx){
        float w=wr[ky*3+kx];
        s00 += v[ky][kx]*w;   s01 += v[ky][kx+1]*w;
        s10 += v[ky+1][kx]*w; s11 += v[ky+1][kx+1]*w;
      }
    float mx = fmaxf(fmaxf(s00,s01),fmaxf(s10,s11));
    pool1[(size_t)b*16384 + p*16 + oc] = __float2half(fmaxf(mx,0.f));
  }
}

// ================= conv2 as implicit-im2col MFMA GEMM =================
__global__ __launch_bounds__(512, 4) void k_conv2mfma(const __half* __restrict__ pool1,
    const float* __restrict__ c2w, const float* __restrict__ c2b, float* __restrict__ proc){
  __shared__ __align__(16) _Float16 img[(34*34+1)*24];   // +1 zero slot
  __shared__ float red[8][32];
  int b = blockIdx.x, tid = threadIdx.x;
  int wv = tid>>6, l = tid&63, lm = l&15, lq = l>>4;
  h8 bfr[2][5];
  float biasv[2];
#pragma unroll
  for (int nt=0; nt<2; ++nt){
    int oc = nt*16 + lm;
    biasv[nt] = c2b[oc];
#pragma unroll
    for (int c=0;c<5;++c){
      h8 f;
#pragma unroll
      for (int j=0;j<8;++j){
        int k = c*32 + lq*8 + j;
        int tap = k>>4, ic = k&15;
        f[j] = (_Float16)((tap<9) ? c2w[oc*144 + ic*9 + tap] : 0.f);
      }
      bfr[nt][c]=f;
    }
  }
  {
    h8 z = {0,0,0,0,0,0,0,0};
    for (int i=tid; i<(34*34+1)*3; i+=512) ((h8*)img)[i] = z;
  }
  __syncthreads();
  const __half* src = pool1 + (size_t)b*16384;
  for (int pp=tid; pp<1024; pp+=512){
    int y=pp>>5, x=pp&31;
    const h8* s = (const h8*)(src + pp*16);
    h8* d = (h8*)&img[((y+1)*34 + (x+1))*24];
    d[0]=s[0]; d[1]=s[1];
  }
  __syncthreads();
  f4v ssum0 = {0,0,0,0}, ssum1 = {0,0,0,0};
#pragma unroll 2
  for (int i=0;i<8;++i){
    int mt = wv + i*8;
    int y = mt>>1, x0 = (mt&1)*16;
    h8 afr[5];
#pragma unroll
    for (int c=0;c<5;++c){
      int tap = 2*c + (lq>>1);
      int addr;
      if (c==4 && lq>=2) addr = 34*34*24;
      else {
        int dy = tap/3 - 1, dx = tap - (tap/3)*3 - 1;
        addr = ((y+dy+1)*34 + (x0+lm+dx+1))*24 + (lq&1)*8;
      }
      afr[c] = *(const h8*)&img[addr];
    }
    f4v a0 = {biasv[0],biasv[0],biasv[0],biasv[0]};
    f4v a1 = {biasv[1],biasv[1],biasv[1],biasv[1]};
#pragma unroll
    for (int c=0;c<5;++c){
      a0 = __builtin_amdgcn_mfma_f32_16x16x32_f16(afr[c], bfr[0][c], a0, 0,0,0);
      a1 = __builtin_amdgcn_mfma_f32_16x16x32_f16(afr[c], bfr[1][c], a1, 0,0,0);
    }
#pragma unroll
    for (int r=0;r<4;++r){
      ssum0[r] += fmaxf(a0[r],0.f);
      ssum1[r] += fmaxf(a1[r],0.f);
    }
  }
  float s0 = ssum0[0]+ssum0[1]+ssum0[2]+ssum0[3];
  float s1 = ssum1[0]+ssum1[1]+ssum1[2]+ssum1[3];
  s0 += __shfl_xor(s0,16,64); s0 += __shfl_xor(s0,32,64);
  s1 += __shfl_xor(s1,16,64); s1 += __shfl_xor(s1,32,64);
  if (lq==0){ red[wv][lm]=s0; red[wv][16+lm]=s1; }
  __syncthreads();
  if (tid<32){
    float t=0.f;
#pragma unroll
    for (int w2=0;w2<8;++w2) t += red[w2][tid];
    proc[b*32+tid] = t*(1.f/1024.f);
  }
}

// ------------- fs = tanh(x@fW1^T+fb1)@fW2^T+fb2, per (b,s) row -------------
// Layer-1 weights/bias pre-scaled by 2/ln2 -> tanh2. R7: 512 blocks x 256 rows
// (outer rb loop) amortizes the per-block weight staging 4x.
__global__ __launch_bounds__(256) void k_fs(const float* __restrict__ x,
    const float* __restrict__ fW1, const float* __restrict__ fb1,
    const float* __restrict__ fW2, const float* __restrict__ fb2,
    float* __restrict__ fs){
  __shared__ float w1t[64*32];
  __shared__ float w2t[32*64];
  __shared__ float b1s[32], b2s[64];
  __shared__ __align__(16) float xbuf[4][8][64];
  __shared__ float t1buf[4][8][32];
  int tid=threadIdx.x, wv=tid>>6, lane=tid&63;
  for (int i=tid;i<2048;i+=256){ int j=i>>6,k=i&63; w1t[k*32+j]=fW1[i]*S_TANH; }
  for (int i=tid;i<2048;i+=256){ int j=i>>5,k=i&31; w2t[k*64+j]=fW2[i]; }
  if (tid<32) b1s[tid]=fb1[tid]*S_TANH;
  if (tid<64) b2s[tid]=fb2[tid];
  __syncthreads();
  int j = lane & 31, half = lane >> 5;
  for (int rb = 0; rb < 4; ++rb){
    size_t Rw = (size_t)blockIdx.x*256 + rb*64 + wv*16;
    for (int pass=0; pass<2; ++pass){
      size_t R0 = Rw + pass*8;
      const float4* src = (const float4*)(x + R0*64);
      float4* dst = (float4*)&xbuf[wv][0][0];
      for (int i=lane;i<128;i+=64) dst[i]=src[i];
      __syncthreads();
      {
        float a0=b1s[j],a1=b1s[j],a2=b1s[j],a3=b1s[j];
        const float* xr = &xbuf[wv][half*4][0];
        for (int k=0;k<64;++k){
          float w = w1t[k*32+j];
          a0 += w*xr[k]; a1 += w*xr[64+k]; a2 += w*xr[128+k]; a3 += w*xr[192+k];
        }
        float* t1r = &t1buf[wv][half*4][0];
        t1r[j]=tanh2(a0); t1r[32+j]=tanh2(a1); t1r[64+j]=tanh2(a2); t1r[96+j]=tanh2(a3);
      }
      __syncthreads();
      {
        float f[8];
#pragma unroll
        for (int r=0;r<8;++r) f[r]=b2s[lane];
        for (int k=0;k<32;++k){
          float w = w2t[k*64+lane];
#pragma unroll
          for (int r=0;r<8;++r) f[r] += w*t1buf[wv][r][k];
        }
#pragma unroll
        for (int r=0;r<8;++r) fs[(R0+r)*64 + lane] = f[r];
      }
      __syncthreads();
    }
  }
}

// ------- aw = tanh([fs,proc]@cW1^T+cb1)@cW2^T+cb2; feature_w=softmax(aw); wx=x*fw -------
// Layer-1 pre-scaled by 2/ln2 -> tanh2. R7: 512 blocks x 256 rows amortize staging 4x.
__global__ __launch_bounds__(256) void k_attnmlp(const float* __restrict__ x,
    const float* __restrict__ fs, const float* __restrict__ proc,
    const float* __restrict__ cW1, const float* __restrict__ cb1,
    const float* __restrict__ cW2, const float* __restrict__ cb2,
    float* __restrict__ fw_out, float* __restrict__ wx){
  __shared__ float c1t[96*64];
  __shared__ float c2t[64*64];
  __shared__ float cb1s[64], cb2s[64];
  __shared__ float cmb[4][4][96];
  __shared__ float h2b[4][4][64];
  int tid = threadIdx.x, wv = tid>>6, lane = tid&63;
  for (int i = tid; i < 6144; i += 256){ int j = i/96, k = i%96; c1t[k*64+j] = cW1[i]*S_TANH; }
  for (int i = tid; i < 4096; i += 256){ int j = i>>6, k = i&63; c2t[k*64+j] = cW2[i]; }
  if (tid < 64) { cb1s[tid] = cb1[tid]*S_TANH; cb2s[tid] = cb2[tid]; }
  __syncthreads();
  for (int rb = 0; rb < 4; ++rb){
    size_t Rw = (size_t)blockIdx.x*256 + rb*64 + wv*16;
    for (int pass = 0; pass < 4; ++pass) {
      size_t R0 = Rw + pass*4;
      for (int i = lane; i < 384; i += 64) {
        int r = i/96, k = i%96;
        size_t R = R0 + r;
        cmb[wv][r][k] = (k < 64) ? fs[R*64 + k] : proc[(R>>7)*32 + (k-64)];
      }
      __syncthreads();
      float h0a=cb1s[lane],h1a=cb1s[lane],h2a=cb1s[lane],h3a=cb1s[lane];
      for (int k = 0; k < 96; ++k) {
        float w = c1t[k*64+lane];
        h0a += w*cmb[wv][0][k]; h1a += w*cmb[wv][1][k];
        h2a += w*cmb[wv][2][k]; h3a += w*cmb[wv][3][k];
      }
      h2b[wv][0][lane]=tanh2(h0a); h2b[wv][1][lane]=tanh2(h1a);
      h2b[wv][2][lane]=tanh2(h2a); h2b[wv][3][lane]=tanh2(h3a);
      __syncthreads();
      float a0=cb2s[lane],a1=cb2s[lane],a2=cb2s[lane],a3=cb2s[lane];
      for (int k = 0; k < 64; ++k) {
        float w = c2t[k*64+lane];
        a0 += w*h2b[wv][0][k]; a1 += w*h2b[wv][1][k];
        a2 += w*h2b[wv][2][k]; a3 += w*h2b[wv][3][k];
      }
      float m0=wmax(a0), m1=wmax(a1), m2=wmax(a2), m3=wmax(a3);
      float e0=__expf(a0-m0), e1=__expf(a1-m1), e2=__expf(a2-m2), e3=__expf(a3-m3);
      float s0=wsum(e0), s1=wsum(e1), s2=wsum(e2), s3=wsum(e3);
      float f0v=e0*frcp(s0), f1v=e1*frcp(s1), f2v=e2*frcp(s2), f3v=e3*frcp(s3);
      size_t R;
      R=R0+0; fw_out[R*64+lane]=f0v; wx[R*64+lane]=x[R*64+lane]*f0v;
      R=R0+1; fw_out[R*64+lane]=f1v; wx[R*64+lane]=x[R*64+lane]*f1v;
      R=R0+2; fw_out[R*64+lane]=f2v; wx[R*64+lane]=x[R*64+lane]*f2v;
      R=R0+3; fw_out[R*64+lane]=f3v; wx[R*64+lane]=x[R*64+lane]*f3v;
      __syncthreads();
    }
  }
}

// ================= MFMA encoder LSTM (swapped operands) =================
// 7 waves, 16 batches/block, 64 blocks (N=16 MFMA batch cols pins grid at 64;
// 512-reg/SIMD file caps 2 waves/SIMD with weights in AGPRs). exp2-domain
// gates; split MFMA chains; R7: sigtanh product fusion (-1 rcp per product,
// twice per cell).
// ench: f16 copy of enc, row-padded to 112 (units 100..111 zeroed).
__global__ __launch_bounds__(448) void k_enc_mfma(const float* __restrict__ wx,
    const float* __restrict__ Wih, const float* __restrict__ Whh,
    const float* __restrict__ bih, const float* __restrict__ bhh,
    _Float16* __restrict__ ench){
  __shared__ __align__(16) _Float16 hbuf[2][16*128];
  __shared__ __align__(16) _Float16 xst[2][16*64];
  int tid = threadIdx.x;
  int w = tid >> 6, l = tid & 63;
  int lm = l & 15, lq = l >> 4;
  int b0 = blockIdx.x * 16;
  int au = w*16 + lm;
  bool avalid = au < 100;
  int u0 = w*16 + lq*4;
  bool uvalid = (u0 + 3) < 100;
  const float gsc[4] = {S_SIG, S_SIG, S_TANH, S_SIG};   // gate order i,f,g,o
  h8 wfr[4][6];
#pragma unroll
  for (int tt=0; tt<4; ++tt){
    int row = tt*100 + au;
#pragma unroll
    for (int cc=0; cc<6; ++cc){
      h8 f;
#pragma unroll
      for (int j=0;j<8;++j){
        int kg = cc*32 + lq*8 + j;
        float v = 0.f;
        if (avalid){
          if (kg < 64) v = Wih[(size_t)row*64 + kg];
          else { int kh = kg - 64; if (kh < 100) v = Whh[(size_t)row*100 + kh]; }
        }
        f[j] = (_Float16)(v*gsc[tt]);
      }
      wfr[tt][cc] = f;
    }
  }
  f4v biasv[4];
#pragma unroll
  for (int tt=0; tt<4; ++tt){
    if (uvalid){
      float4 bi = *(const float4*)&bih[tt*100 + u0];
      float4 bh = *(const float4*)&bhh[tt*100 + u0];
      float s = gsc[tt];
      f4v bv2 = {(bi.x+bh.x)*s, (bi.y+bh.y)*s, (bi.z+bh.z)*s, (bi.w+bh.w)*s};
      biasv[tt] = bv2;
    } else { f4v z = {0,0,0,0}; biasv[tt] = z; }
  }
  for (int i = tid; i < 2*16*128; i += 448) hbuf[0][i] = (_Float16)0.f;
  int sm = tid >> 4, skq = tid & 15;
  bool doPref = (tid < 256);
  float4 rA, rB;
  if (doPref){
    float4 xv0 = *(const float4*)(wx + ((size_t)(b0+sm)*SS + 0)*FF + skq*4);
    h4 p = {(_Float16)xv0.x,(_Float16)xv0.y,(_Float16)xv0.z,(_Float16)xv0.w};
    *(h4*)&xst[0][sm*64 + (((skq>>1) ^ (sm&7))<<3) + (skq&1)*4] = p;
    rA = *(const float4*)(wx + ((size_t)(b0+sm)*SS + 1)*FF + skq*4);   // x(1)
  }
  float cst[4] = {0.f,0.f,0.f,0.f};
  int hwaddr = lm*128 + (((2*w + (lq>>1)) ^ (lm&7))<<3) + (lq&1)*4;
  int xwaddr = sm*64 + (((skq>>1) ^ (sm&7))<<3) + (skq&1)*4;
  __syncthreads();

#define ENC_STEP(T, CUR, RCONS, RISSUE)                                          \
  {                                                                              \
    const int cur = (CUR), nxt = (CUR)^1;                                        \
    if (doPref && (T) < SS-2)                                                    \
      RISSUE = *(const float4*)(wx + ((size_t)(b0+sm)*SS + ((T)+2))*FF + skq*4); \
    h8 bact[6];                                                                  \
    _Pragma("unroll")                                                            \
    for (int cc=0; cc<2; ++cc)                                                   \
      bact[cc] = *(const h8*)&xst[cur][lm*64 + (((cc*4+lq) ^ (lm&7))<<3)];       \
    _Pragma("unroll")                                                            \
    for (int cc=0; cc<4; ++cc)                                                   \
      bact[2+cc] = *(const h8*)&hbuf[cur][lm*128 + (((cc*4+lq) ^ (lm&7))<<3)];   \
    f4v acc[4];                                                                  \
    __builtin_amdgcn_s_setprio(1);                                               \
    _Pragma("unroll")                                                            \
    for (int tt=0; tt<4; ++tt){                                                  \
      f4v a1 = biasv[tt];                                                        \
      f4v a2 = {0.f,0.f,0.f,0.f};                                                \
      a1 = __builtin_amdgcn_mfma_f32_16x16x32_f16(wfr[tt][0], bact[0], a1, 0,0,0); \
      a2 = __builtin_amdgcn_mfma_f32_16x16x32_f16(wfr[tt][1], bact[1], a2, 0,0,0); \
      a1 = __builtin_amdgcn_mfma_f32_16x16x32_f16(wfr[tt][2], bact[2], a1, 0,0,0); \
      a2 = __builtin_amdgcn_mfma_f32_16x16x32_f16(wfr[tt][3], bact[3], a2, 0,0,0); \
      a1 = __builtin_amdgcn_mfma_f32_16x16x32_f16(wfr[tt][4], bact[4], a1, 0,0,0); \
      a2 = __builtin_amdgcn_mfma_f32_16x16x32_f16(wfr[tt][5], bact[5], a2, 0,0,0); \
      acc[tt] = a1 + a2;                                                         \
    }                                                                            \
    __builtin_amdgcn_s_setprio(0);                                               \
    float hn[4];                                                                 \
    _Pragma("unroll")                                                            \
    for (int r=0;r<4;++r){                                                       \
      float Ei = fexp2(acc[0][r]), Ef = fexp2(acc[1][r]);                        \
      float Eg = fexp2(acc[2][r]), Eo = fexp2(acc[3][r]);                        \
      float cn = frcp(1.f+Ef)*cst[r] + sigtanh(Ei, Eg);                          \
      float Ec = fexp2(cn*S_TANH);                                               \
      hn[r] = sigtanh(Eo, Ec);                                                   \
      cst[r] = cn;                                                               \
    }                                                                            \
    if (uvalid){                                                                 \
      h4 hp = {(_Float16)hn[0],(_Float16)hn[1],(_Float16)hn[2],(_Float16)hn[3]}; \
      *(h4*)&hbuf[nxt][hwaddr] = hp;                                             \
      *(h4*)&ench[((size_t)(b0+lm)*SS + (T))*112 + u0] = hp;                     \
    } else {                                                                     \
      h4 z = {(_Float16)0.f,(_Float16)0.f,(_Float16)0.f,(_Float16)0.f};          \
      *(h4*)&ench[((size_t)(b0+lm)*SS + (T))*112 + u0] = z;                      \
    }                                                                            \
    if (doPref && (T) < SS-1){                                                   \
      h4 p = {(_Float16)RCONS.x,(_Float16)RCONS.y,(_Float16)RCONS.z,(_Float16)RCONS.w}; \
      *(h4*)&xst[nxt][xwaddr] = p;                                               \
    }                                                                            \
    LDS_BARRIER();                                                               \
  }

  for (int t = 0; t < SS; t += 2){
    ENC_STEP(t,   0, rA, rB)   // consumes x(t+1) from rA, issues x(t+2) into rB
    ENC_STEP(t+1, 1, rB, rA)   // consumes x(t+2) from rB, issues x(t+3) into rA
  }
#undef ENC_STEP
}

// ================= ts GEMM: ts[b,s] = aW2 @ tanh(aW1 @ enc_row + ab1) + ab2 ========
// M = B*S rows (ench f16, 112-padded), N = 64, K = 100->128 (chunk 3 half-zero).
// aW1/ab1 pre-scaled by 2/ln2 -> tanh2 on the MFMA output directly.
__global__ __launch_bounds__(256) void k_ts(const _Float16* __restrict__ ench,
    const float* __restrict__ aW1, const float* __restrict__ ab1,
    const float* __restrict__ aW2, const float* __restrict__ ab2,
    float* __restrict__ ts){
  int tid = threadIdx.x, wv = tid>>6, l = tid&63, lm = l&15, lq = l>>4;
  h8 bfr[4][4];
#pragma unroll
  for (int nt=0; nt<4; ++nt){
    int n = nt*16 + lm;
#pragma unroll
    for (int cc=0; cc<4; ++cc){
      h8 f;
#pragma unroll
      for (int j=0;j<8;++j){
        int k = cc*32 + lq*8 + j;
        f[j] = (_Float16)((k<100) ? aW1[n*100+k]*S_TANH : 0.f);
      }
      bfr[nt][cc]=f;
    }
  }
  float ab1v[4], aw2v[4];
#pragma unroll
  for (int nt=0; nt<4; ++nt){ ab1v[nt] = ab1[nt*16+lm]*S_TANH; aw2v[nt] = aW2[nt*16+lm]; }
  float ab2v = ab2[0];
  int tile0 = (blockIdx.x*4 + wv)*4;
#pragma unroll
  for (int i=0;i<4;++i){
    int M0 = (tile0+i)*16;
    const _Float16* rowp = ench + (size_t)(M0+lm)*112;
    h8 afr[4];
#pragma unroll
    for (int cc=0; cc<3; ++cc)
      afr[cc] = *(const h8*)(rowp + cc*32 + lq*8);
    if (lq < 2) afr[3] = *(const h8*)(rowp + 96 + lq*8);
    else { h8 z={0,0,0,0,0,0,0,0}; afr[3]=z; }
    f4v acc[4];
#pragma unroll
    for (int nt=0; nt<4; ++nt){
      f4v a = {ab1v[nt],ab1v[nt],ab1v[nt],ab1v[nt]};
#pragma unroll
      for (int cc=0; cc<4; ++cc)
        a = __builtin_amdgcn_mfma_f32_16x16x32_f16(afr[cc], bfr[nt][cc], a, 0,0,0);
      acc[nt]=a;
    }
    float p[4];
#pragma unroll
    for (int r=0;r<4;++r){
      p[r] = aw2v[0]*tanh2(acc[0][r]) + aw2v[1]*tanh2(acc[1][r])
           + aw2v[2]*tanh2(acc[2][r]) + aw2v[3]*tanh2(acc[3][r]);
#pragma unroll
      for (int m=1;m<16;m<<=1) p[r] += __shfl_xor(p[r], m, 64);
    }
    if (lm==0){
      float4 st; st.x=p[0]+ab2v; st.y=p[1]+ab2v; st.z=p[2]+ab2v; st.w=p[3]+ab2v;
      *(float4*)&ts[M0 + lq*4] = st;
    }
  }
}

// ------- per-b: softmax(ts) over S, ctx, bott, dh0, dc0, decpre -------
// ctx accumulated from ench (f16). R7: ctx GEMV split over 200 threads
// (2 s-halves) instead of 100.
__global__ __launch_bounds__(256) void k_attn2(const _Float16* __restrict__ ench,
    const float* __restrict__ ts,
    const float* __restrict__ bW, const float* __restrict__ bb_,
    const float* __restrict__ h0W, const float* __restrict__ h0b,
    const float* __restrict__ c0W, const float* __restrict__ c0b,
    const float* __restrict__ dWih, const float* __restrict__ dbih, const float* __restrict__ dbhh,
    float* __restrict__ tw_out, float* __restrict__ dh0, float* __restrict__ dc0,
    float* __restrict__ decpre){
  __shared__ float tsb[SS];
  __shared__ float ctxb[HH];
  __shared__ float ctx2[200];
  __shared__ float bottb[32];
  __shared__ float red[8];
  int tid = threadIdx.x, wv = tid>>6, lane = tid&63;
  int b = blockIdx.x;
  const _Float16* encb = ench + (size_t)b*SS*112;
  float tv = (tid < SS) ? ts[(size_t)b*SS + tid] : -1e30f;
  float m = wmax(tv);
  if (lane==0) red[wv]=m;
  __syncthreads();
  m = fmaxf(fmaxf(red[0],red[1]), fmaxf(red[2],red[3]));
  float e = (tid < SS) ? __expf(tv - m) : 0.f;
  float sm = wsum(e);
  if (lane==0) red[4+wv]=sm;
  __syncthreads();
  float denom = red[4]+red[5]+red[6]+red[7];
  float rden = frcp(denom);
  if (tid < SS){
    float twv = e*rden;
    tw_out[(size_t)b*SS + tid] = twv;
    tsb[tid] = twv;
  }
  __syncthreads();
  if (tid < 200){
    int u = (tid < 100) ? tid : (tid - 100);
    int sb = (tid < 100) ? 0 : 64;
    const _Float16* ep = encb + (size_t)sb*112 + u;
    const float* tp = tsb + sb;
    float a = 0.f;
#pragma unroll 4
    for (int s=0;s<64;++s) a += tp[s]*(float)ep[s*112];
    ctx2[tid] = a;
  }
  __syncthreads();
  if (tid < HH) ctxb[tid] = ctx2[tid] + ctx2[tid+100];
  __syncthreads();
  if (tid < 32){
    float a = bb_[tid];
    const float* wr = bW + tid*HH;
    for (int k=0;k<HH;++k) a += wr[k]*ctxb[k];
    bottb[tid]=a;
  }
  __syncthreads();
  if (tid < HH){
    float a = h0b[tid];
    const float* wr = h0W + tid*32;
#pragma unroll
    for (int k=0;k<32;++k) a += wr[k]*bottb[k];
    dh0[(size_t)b*HH + tid] = a;
  } else if (tid < 200){
    int jj = tid-100;
    float a = c0b[jj];
    const float* wr = c0W + jj*32;
#pragma unroll
    for (int k=0;k<32;++k) a += wr[k]*bottb[k];
    dc0[(size_t)b*HH + jj] = a;
  }
  {
    int jj = tid;
    float a = dbih[jj]+dbhh[jj];
    const float* wr = dWih + jj*32;
#pragma unroll
    for (int k=0;k<32;++k) a += wr[k]*bottb[k];
    decpre[(size_t)b*400 + jj] = a;
    jj = tid + 256;
    if (jj < 400){
      float a2v = dbih[jj]+dbhh[jj];
      const float* wr2 = dWih + jj*32;
#pragma unroll
      for (int k=0;k<32;++k) a2v += wr2[k]*bottb[k];
      decpre[(size_t)b*400 + jj] = a2v;
    }
  }
}

// ================= MFMA decoder LSTM (swapped operands) =================
// f16 dech output; exp2-domain gates; split chains; sigtanh fusion (R7).
__global__ __launch_bounds__(448) void k_dec_mfma(const float* __restrict__ decpre,
    const float* __restrict__ Whh,
    const float* __restrict__ dh0, const float* __restrict__ dc0,
    _Float16* __restrict__ dech){
  __shared__ __align__(16) _Float16 hbuf[2][16*128];
  int tid = threadIdx.x;
  int w = tid >> 6, l = tid & 63;
  int lm = l & 15, lq = l >> 4;
  int b0 = blockIdx.x * 16;
  int au = w*16 + lm;
  bool avalid = au < 100;
  int u0 = w*16 + lq*4;
  bool uvalid = (u0 + 3) < 100;
  const float gsc[4] = {S_SIG, S_SIG, S_TANH, S_SIG};
  h8 wfr[4][4];
#pragma unroll
  for (int tt = 0; tt < 4; ++tt){
    int row = tt*100 + au;
#pragma unroll
    for (int cc = 0; cc < 4; ++cc){
      h8 f;
#pragma unroll
      for (int j = 0; j < 8; ++j){
        int kh = cc*32 + lq*8 + j;
        float v = (avalid && kh < 100) ? Whh[(size_t)row*100 + kh] : 0.f;
        f[j] = (_Float16)(v*gsc[tt]);
      }
      wfr[tt][cc] = f;
    }
  }
  f4v pre[4];
  float cst[4] = {0.f,0.f,0.f,0.f};
  if (uvalid){
#pragma unroll
    for (int tt = 0; tt < 4; ++tt){
      float4 p = *(const float4*)&decpre[(size_t)(b0+lm)*400 + tt*100 + u0];
      float s = gsc[tt];
      f4v pv = {p.x*s, p.y*s, p.z*s, p.w*s};
      pre[tt] = pv;
    }
    float4 c4 = *(const float4*)&dc0[(size_t)(b0+lm)*100 + u0];
    cst[0]=c4.x; cst[1]=c4.y; cst[2]=c4.z; cst[3]=c4.w;
  } else {
    f4v z = {0,0,0,0};
#pragma unroll
    for (int tt = 0; tt < 4; ++tt) pre[tt] = z;
  }
  for (int i = tid; i < 16*128; i += 448) hbuf[1][i] = (_Float16)0.f;
  for (int idx = tid; idx < 16*128; idx += 448){
    int m = idx >> 7, u2 = idx & 127;
    float v = (u2 < 100) ? dh0[(size_t)(b0+m)*HH + u2] : 0.f;
    hbuf[0][m*128 + (((u2>>3) ^ (m&7))<<3) + (u2&7)] = (_Float16)v;
  }
  int hwaddr = lm*128 + (((2*w + (lq>>1)) ^ (lm&7))<<3) + (lq&1)*4;
  __syncthreads();

#define DEC_STEP(T, CUR)                                                         \
  {                                                                              \
    const int cur = (CUR), nxt = (CUR)^1;                                        \
    h8 bact[4];                                                                  \
    _Pragma("unroll")                                                            \
    for (int cc = 0; cc < 4; ++cc)                                               \
      bact[cc] = *(const h8*)&hbuf[cur][lm*128 + (((cc*4+lq) ^ (lm&7))<<3)];     \
    f4v acc[4];                                                                  \
    __builtin_amdgcn_s_setprio(1);                                               \
    _Pragma("unroll")                                                            \
    for (int tt = 0; tt < 4; ++tt){                                              \
      f4v a1 = pre[tt];                                                          \
      f4v a2 = {0.f,0.f,0.f,0.f};                                                \
      a1 = __builtin_amdgcn_mfma_f32_16x16x32_f16(wfr[tt][0], bact[0], a1, 0,0,0); \
      a2 = __builtin_amdgcn_mfma_f32_16x16x32_f16(wfr[tt][1], bact[1], a2, 0,0,0); \
      a1 = __builtin_amdgcn_mfma_f32_16x16x32_f16(wfr[tt][2], bact[2], a1, 0,0,0); \
      a2 = __builtin_amdgcn_mfma_f32_16x16x32_f16(wfr[tt][3], bact[3], a2, 0,0,0); \
      acc[tt] = a1 + a2;                                                         \
    }                                                                            \
    __builtin_amdgcn_s_setprio(0);                                               \
    float hn[4];                                                                 \
    _Pragma("unroll")                                                            \
    for (int r=0;r<4;++r){                                                       \
      float Ei = fexp2(acc[0][r]), Ef = fexp2(acc[1][r]);                        \
      float Eg = fexp2(acc[2][r]), Eo = fexp2(acc[3][r]);                        \
      float cn = frcp(1.f+Ef)*cst[r] + sigtanh(Ei, Eg);                          \
      float Ec = fexp2(cn*S_TANH);                                               \
      hn[r] = sigtanh(Eo, Ec);                                                   \
      cst[r] = cn;                                                               \
    }                                                                            \
    if (uvalid){                                                                 \
      h4 hp = {(_Float16)hn[0],(_Float16)hn[1],(_Float16)hn[2],(_Float16)hn[3]}; \
      *(h4*)&hbuf[nxt][hwaddr] = hp;                                             \
      *(h4*)&dech[((size_t)(b0+lm)*SS + (T))*112 + u0] = hp;                     \
    }                                                                            \
    LDS_BARRIER();                                                               \
  }

  for (int t = 0; t < SS; t += 2){
    DEC_STEP(t,   0)
    DEC_STEP(t+1, 1)
  }
#undef DEC_STEP
}

// ------------- out = dec @ oW^T + ob (dec consumed as f16 dech) -------------
// R7: 512 blocks x 4 row-tiles; oWt staged once per block.
__global__ __launch_bounds__(256) void k_out(const _Float16* __restrict__ dech,
    const float* __restrict__ oW, const float* __restrict__ ob, float* __restrict__ out0){
  __shared__ float oWt[100*64];
  __shared__ float dsr[64*112];
  int tid=threadIdx.x;
  for (int i=tid;i<6400;i+=256){ int j=i/100,k=i%100; oWt[k*64+j]=oW[i]; }
  int j = tid&63, rbt = tid>>6;
  float obv = ob[j];
  for (int rb = 0; rb < 4; ++rb){
    size_t R0 = (size_t)blockIdx.x*256 + rb*64;
    __syncthreads();   // oWt ready (rb=0) / dsr readers done (rb>0)
    {
      const h8* db = (const h8*)(dech + R0*112);
      for (int i=tid;i<896;i+=256){
        h8 v = db[i];
        float* d = dsr + i*8;
#pragma unroll
        for (int jj=0;jj<8;++jj) d[jj] = (float)v[jj];
      }
    }
    __syncthreads();
    float acc[16];
#pragma unroll
    for (int i=0;i<16;++i) acc[i]=0.f;
    for (int k=0;k<100;++k){
      float w = oWt[k*64+j];
#pragma unroll
      for (int i=0;i<16;++i) acc[i] += w*dsr[(rbt + i*4)*112 + k];
    }
#pragma unroll
    for (int i=0;i<16;++i) out0[(R0 + rbt + i*4)*64 + j] = acc[i] + obv;
  }
}

extern "C" void kernel_launch(void* const* d_in, const int* in_sizes, int n_in,
                              void* d_out, int out_size, void* d_ws, size_t ws_size,
                              hipStream_t stream) {
  const float* x    = (const float*)d_in[0];
  const float* c1w  = (const float*)d_in[1];
  const float* c1b  = (const float*)d_in[2];
  const float* c2w  = (const float*)d_in[3];
  const float* c2b  = (const float*)d_in[4];
  const float* fW1  = (const float*)d_in[5];
  const float* fb1  = (const float*)d_in[6];
  const float* fW2  = (const float*)d_in[7];
  const float* fb2  = (const float*)d_in[8];
  const float* cW1  = (const float*)d_in[9];
  const float* cb1  = (const float*)d_in[10];
  const float* cW2  = (const float*)d_in[11];
  const float* cb2  = (const float*)d_in[12];
  const float* eWih = (const float*)d_in[13];
  const float* eWhh = (const float*)d_in[14];
  const float* ebih = (const float*)d_in[15];
  const float* ebhh = (const float*)d_in[16];
  const float* aW1  = (const float*)d_in[17];
  const float* ab1  = (const float*)d_in[18];
  const float* aW2  = (const float*)d_in[19];
  const float* ab2  = (const float*)d_in[20];
  const float* bW   = (const float*)d_in[21];
  const float* bb   = (const float*)d_in[22];
  const float* h0W  = (const float*)d_in[23];
  const float* h0b  = (const float*)d_in[24];
  const float* c0W  = (const float*)d_in[25];
  const float* c0b  = (const float*)d_in[26];
  const float* dWih = (const float*)d_in[27];
  const float* dWhh = (const float*)d_in[28];
  const float* dbih = (const float*)d_in[29];
  const float* dbhh = (const float*)d_in[30];
  const float* oW   = (const float*)d_in[31];
  const float* ob   = (const float*)d_in[32];

  float* out0   = (float*)d_out;
  float* out_tw = out0 + (size_t)BB*SS*FF;
  float* out_fw = out_tw + (size_t)BB*SS;

  char* ws = (char*)d_ws;
  float*  gram   = (float*) (ws + 0);           // 16.78 MB (reused as ts after conv1)
  __half* pool1  = (__half*)(ws + 16777216);    // 33.55 MB (channel-last [b][p][ic])
  float*  proc   = (float*) (ws + 50331648);    // 0.13 MB
  float*  fsbuf  = (float*) (ws + 50462720);    // 33.55 MB (reused as ench after attnmlp)
  float*  wx     = (float*) (ws + 84017152);    // 33.55 MB
  // ws+117571584 (old f32 enc region, 52.43 MB) now unused
  float*  dh0    = (float*) (ws + 170000384);   // 0.41 MB
  float*  dc0    = (float*) (ws + 170409984);   // 0.41 MB
  float*  decpre = (float*) (ws + 170819584);   // 1.64 MB
  _Float16* dech = (_Float16*)(ws + 172457984); // 29.36 MB (f16, [row][112])
  float*     tsbuf = (float*)gram;              // 0.52 MB (gram dead after conv1)
  _Float16*  ench  = (_Float16*)fsbuf;          // 29.36 MB (fsbuf dead after attnmlp)

  k_gram<<<BB, 256, 0, stream>>>(x, gram);
  k_conv1pool<<<BB, 256, 0, stream>>>(gram, c1w, c1b, pool1);
  k_conv2mfma<<<BB, 512, 0, stream>>>(pool1, c2w, c2b, proc);
  k_fs<<<512, 256, 0, stream>>>(x, fW1, fb1, fW2, fb2, fsbuf);
  k_attnmlp<<<512, 256, 0, stream>>>(x, fsbuf, proc, cW1, cb1, cW2, cb2, out_fw, wx);
  k_enc_mfma<<<64, 448, 0, stream>>>(wx, eWih, eWhh, ebih, ebhh, ench);
  k_ts<<<512, 256, 0, stream>>>(ench, aW1, ab1, aW2, ab2, tsbuf);
  k_attn2<<<BB, 256, 0, stream>>>(ench, tsbuf, bW, bb, h0W, h0b, c0W, c0b,
                                  dWih, dbih, dbhh, out_tw, dh0, dc0, decpre);
  k_dec_mfma<<<64, 448, 0, stream>>>(decpre, dWhh, dh0, dc0, dech);
  k_out<<<512, 256, 0, stream>>>(dech, oW, ob, out0);
}

// Round 8
// 677.295 us; speedup vs baseline: 1.4741x; 1.1802x over previous
//
#include <hip/hip_runtime.h>
#include <hip/hip_fp16.h>

#define BB 1024
#define SS 128
#define FF 64
#define HH 100

typedef _Float16 h8 __attribute__((ext_vector_type(8)));
typedef _Float16 h4 __attribute__((ext_vector_type(4)));
typedef float f4v __attribute__((ext_vector_type(4)));

// --- fast transcendentals ---------------------------------------------------
// v_rcp_f32 (~1 ulp); fp32 '/' without fast-math is ~11 VALU ops (R5: -32%).
// exp2-domain gates (R6): fold 1/ln2 (and tanh's 2x) into weights/biases so
// sigma/tanh start at v_exp_f32 directly.
// R7: product fusion sigma(zi)*tanh(zt) = (Et-1)*rcp((1+Ei)(1+Et)).
#define S_SIG  (-1.4426950408889634f)   // i,f,o rows: acc = -z/ln2
#define S_TANH ( 2.8853900817779268f)   // g rows:     acc = 2z/ln2
#define LOG2E  ( 1.4426950408889634f)
__device__ __forceinline__ float frcp(float x){ return __builtin_amdgcn_rcpf(x); }
__device__ __forceinline__ float fexp2(float x){ return __builtin_amdgcn_exp2f(x); }
__device__ __forceinline__ float sigm2(float a){ return frcp(1.f + fexp2(a)); }        // a = -z/ln2
__device__ __forceinline__ float tanh2(float a){ return 1.f - 2.f*frcp(fexp2(a)+1.f);} // a = 2z/ln2
__device__ __forceinline__ float ftanh(float x){ return tanh2(x*S_TANH); }             // unscaled arg
__device__ __forceinline__ float sigtanh(float Ei, float Et){
  float D = __builtin_fmaf(Ei, Et, Ei) + (Et + 1.f);   // (1+Ei)(1+Et)
  return (Et - 1.f) * frcp(D);
}

// LDS-only barrier: waits own LDS ops, does NOT drain vmcnt (global stores
// stay in flight across steps).
#define LDS_BARRIER() __asm__ __volatile__("s_waitcnt lgkmcnt(0)\ns_barrier" ::: "memory")

__device__ __forceinline__ float wsum(float v){
#pragma unroll
  for (int m = 32; m >= 1; m >>= 1) v += __shfl_xor(v, m, 64);
  return v;
}
__device__ __forceinline__ float wmax(float v){
#pragma unroll
  for (int m = 32; m >= 1; m >>= 1) v = fmaxf(v, __shfl_xor(v, m, 64));
  return v;
}

// ====== gram + conv1(3x3,1->16)+relu+maxpool2 FUSED (R8) ======
// gram[b] (64x64) is computed in LDS and consumed in-place by conv1pool --
// the 16.8MB gram buffer never touches HBM (34MB round-trip + 1 launch saved).
__global__ __launch_bounds__(256) void k_gc1(const float* __restrict__ x,
    const float* __restrict__ c1w, const float* __restrict__ c1b, __half* __restrict__ pool1){
  __shared__ __align__(16) float xs[SS*FF];
  __shared__ float img2[66*66];
  __shared__ float ws1[144];
  __shared__ float bs1[16];
  int tid=threadIdx.x, b=blockIdx.x;
  const float* xb = x + (size_t)b*SS*FF;
  for (int i = tid; i < SS*FF/4; i += 256)
    ((float4*)xs)[i] = ((const float4*)xb)[i];
  for (int i=tid;i<66*66;i+=256) img2[i]=0.f;
  if (tid<144) ws1[tid]=c1w[tid];
  if (tid<16) bs1[tid]=c1b[tid];
  __syncthreads();
  // gram tile: thread covers rows ti..ti+3, cols tj..tj+3
  int ti = (tid & 15) * 4, tj = (tid >> 4) * 4;
  float acc[4][4];
#pragma unroll
  for (int a=0;a<4;++a)
#pragma unroll
    for (int c=0;c<4;++c) acc[a][c]=0.f;
  for (int s = 0; s < SS; ++s) {
    const float* row = xs + s*FF;
    float4 av = *(const float4*)(row + ti);
    float4 bv = *(const float4*)(row + tj);
    float aa[4] = {av.x,av.y,av.z,av.w};
    float bb2[4] = {bv.x,bv.y,bv.z,bv.w};
#pragma unroll
    for (int a=0;a<4;++a)
#pragma unroll
      for (int c=0;c<4;++c) acc[a][c] += aa[a]*bb2[c];
  }
#pragma unroll
  for (int a=0;a<4;++a)
#pragma unroll
    for (int c=0;c<4;++c) img2[(ti+a+1)*66 + (tj+c+1)] = acc[a][c];
  __syncthreads();
  // conv1 + relu + maxpool2 -> half channel-last [b][p][ic]
  int oc = tid>>4, slot = tid&15;
  float wr[9];
#pragma unroll
  for (int t=0;t<9;++t) wr[t]=ws1[oc*9+t];
  float bo = bs1[oc];
  for (int p=slot;p<1024;p+=16){
    int py=p>>5, px=p&31;
    int y0=py*2, x0=px*2;
    float v[4][4];
#pragma unroll
    for (int wy=0;wy<4;++wy)
#pragma unroll
      for (int wxx=0;wxx<4;++wxx) v[wy][wxx]=img2[(y0+wy)*66 + x0+wxx];
    float s00=bo,s01=bo,s10=bo,s11=bo;
#pragma unroll
    for (int ky=0;ky<3;++ky)
#pragma unroll
      for (int kx=0;kx<3;++kx){
        float w=wr[ky*3+kx];
        s00 += v[ky][kx]*w;   s01 += v[ky][kx+1]*w;
        s10 += v[ky+1][kx]*w; s11 += v[ky+1][kx+1]*w;
      }
    float mx = fmaxf(fmaxf(s00,s01),fmaxf(s10,s11));
    pool1[(size_t)b*16384 + p*16 + oc] = __float2half(fmaxf(mx,0.f));
  }
}

// ================= conv2 as implicit-im2col MFMA GEMM =================
__global__ __launch_bounds__(512, 4) void k_conv2mfma(const __half* __restrict__ pool1,
    const float* __restrict__ c2w, const float* __restrict__ c2b, float* __restrict__ proc){
  __shared__ __align__(16) _Float16 img[(34*34+1)*24];   // +1 zero slot
  __shared__ float red[8][32];
  int b = blockIdx.x, tid = threadIdx.x;
  int wv = tid>>6, l = tid&63, lm = l&15, lq = l>>4;
  h8 bfr[2][5];
  float biasv[2];
#pragma unroll
  for (int nt=0; nt<2; ++nt){
    int oc = nt*16 + lm;
    biasv[nt] = c2b[oc];
#pragma unroll
    for (int c=0;c<5;++c){
      h8 f;
#pragma unroll
      for (int j=0;j<8;++j){
        int k = c*32 + lq*8 + j;
        int tap = k>>4, ic = k&15;
        f[j] = (_Float16)((tap<9) ? c2w[oc*144 + ic*9 + tap] : 0.f);
      }
      bfr[nt][c]=f;
    }
  }
  {
    h8 z = {0,0,0,0,0,0,0,0};
    for (int i=tid; i<(34*34+1)*3; i+=512) ((h8*)img)[i] = z;
  }
  __syncthreads();
  const __half* src = pool1 + (size_t)b*16384;
  for (int pp=tid; pp<1024; pp+=512){
    int y=pp>>5, x=pp&31;
    const h8* s = (const h8*)(src + pp*16);
    h8* d = (h8*)&img[((y+1)*34 + (x+1))*24];
    d[0]=s[0]; d[1]=s[1];
  }
  __syncthreads();
  f4v ssum0 = {0,0,0,0}, ssum1 = {0,0,0,0};
#pragma unroll 2
  for (int i=0;i<8;++i){
    int mt = wv + i*8;
    int y = mt>>1, x0 = (mt&1)*16;
    h8 afr[5];
#pragma unroll
    for (int c=0;c<5;++c){
      int tap = 2*c + (lq>>1);
      int addr;
      if (c==4 && lq>=2) addr = 34*34*24;
      else {
        int dy = tap/3 - 1, dx = tap - (tap/3)*3 - 1;
        addr = ((y+dy+1)*34 + (x0+lm+dx+1))*24 + (lq&1)*8;
      }
      afr[c] = *(const h8*)&img[addr];
    }
    f4v a0 = {biasv[0],biasv[0],biasv[0],biasv[0]};
    f4v a1 = {biasv[1],biasv[1],biasv[1],biasv[1]};
#pragma unroll
    for (int c=0;c<5;++c){
      a0 = __builtin_amdgcn_mfma_f32_16x16x32_f16(afr[c], bfr[0][c], a0, 0,0,0);
      a1 = __builtin_amdgcn_mfma_f32_16x16x32_f16(afr[c], bfr[1][c], a1, 0,0,0);
    }
#pragma unroll
    for (int r=0;r<4;++r){
      ssum0[r] += fmaxf(a0[r],0.f);
      ssum1[r] += fmaxf(a1[r],0.f);
    }
  }
  float s0 = ssum0[0]+ssum0[1]+ssum0[2]+ssum0[3];
  float s1 = ssum1[0]+ssum1[1]+ssum1[2]+ssum1[3];
  s0 += __shfl_xor(s0,16,64); s0 += __shfl_xor(s0,32,64);
  s1 += __shfl_xor(s1,16,64); s1 += __shfl_xor(s1,32,64);
  if (lq==0){ red[wv][lm]=s0; red[wv][16+lm]=s1; }
  __syncthreads();
  if (tid<32){
    float t=0.f;
#pragma unroll
    for (int w2=0;w2<8;++w2) t += red[w2][tid];
    proc[b*32+tid] = t*(1.f/1024.f);
  }
}

// ====== R8: fused feature pipeline (was k_fs + k_attnmlp), MFMA ======
// Per (b,s) row: fs = tanh(x@fW1^T+fb1)@fW2^T+fb2;
//   aw = tanh([fs,proc_b]@cW1^T+cb1)@cW2^T+cb2; fw = softmax_m(aw); wx = x*fw.
// All four layers as 16x16x32 f16 MFMA (enc's swapped-operand pattern:
// A = weight frags in registers, B = 16 rows as columns). Inter-layer
// redistribution via per-wave [16 rows][128 f16] LDS tiles with granule-XOR
// swizzle (bijective per row; ds_read_b128 2-way banks = free). Softmax over
// the m-axis = per-lane 16-max + 2 shfl_xor (lanes lm,lm+16,lm+32,lm+48 hold
// one column). Old kernels ran these GEMMs on VALU with ~800 scalar LDS
// reads per row-pass -> LDS-issue bound (~85us est); MFMA removes that and
// the 67MB fs round-trip.
// Block = 4 waves x 2 groups x 16 rows = 128 rows = one batch b.
#define TADDR(row,k) (((row)<<7) + (((((k)>>3) ^ (row)) & 15)<<3) + ((k)&7))
__global__ __launch_bounds__(256, 2) void k_feat(const float* __restrict__ x,
    const float* __restrict__ proc,
    const float* __restrict__ fW1, const float* __restrict__ fb1,
    const float* __restrict__ fW2, const float* __restrict__ fb2,
    const float* __restrict__ cW1, const float* __restrict__ cb1,
    const float* __restrict__ cW2, const float* __restrict__ cb2,
    float* __restrict__ fw_out, float* __restrict__ wx){
  __shared__ __align__(16) _Float16 tiles[4][3][2048];   // [wave][xt,tA,tB][16*128]
  __shared__ __align__(16) _Float16 proc_h[32];
  int tid = threadIdx.x, w = tid>>6, l = tid&63, lm = l&15, lq = l>>4;
  int b = blockIdx.x;
  // --- weight fragments (A-operands; M-tile = mt*16+lm, k = kc*32+lq*8+j) ---
  h8 wfr1[2][2], wfr2[4], wfr3[4][3], wfr4[4][2];
#pragma unroll
  for (int mt=0; mt<2; ++mt)
#pragma unroll
    for (int kc=0; kc<2; ++kc){
      h8 f;
#pragma unroll
      for (int j=0;j<8;++j) f[j] = (_Float16)(fW1[(mt*16+lm)*64 + kc*32 + lq*8 + j]*S_TANH);
      wfr1[mt][kc]=f;
    }
#pragma unroll
  for (int mt=0; mt<4; ++mt){
    h8 f;
#pragma unroll
    for (int j=0;j<8;++j) f[j] = (_Float16)(fW2[(mt*16+lm)*32 + lq*8 + j]);
    wfr2[mt]=f;
  }
#pragma unroll
  for (int mt=0; mt<4; ++mt)
#pragma unroll
    for (int kc=0; kc<3; ++kc){
      h8 f;
#pragma unroll
      for (int j=0;j<8;++j) f[j] = (_Float16)(cW1[(mt*16+lm)*96 + kc*32 + lq*8 + j]*S_TANH);
      wfr3[mt][kc]=f;
    }
#pragma unroll
  for (int mt=0; mt<4; ++mt)
#pragma unroll
    for (int kc=0; kc<2; ++kc){
      h8 f;
#pragma unroll
      for (int j=0;j<8;++j) f[j] = (_Float16)(cW2[(mt*16+lm)*64 + kc*32 + lq*8 + j]);
      wfr4[mt][kc]=f;
    }
  f4v b1v[2], b2v[4], b3v[4], b4v[4];
#pragma unroll
  for (int mt=0;mt<2;++mt){
    float4 t = *(const float4*)&fb1[mt*16 + lq*4];
    f4v v = {t.x*S_TANH, t.y*S_TANH, t.z*S_TANH, t.w*S_TANH}; b1v[mt]=v;
  }
#pragma unroll
  for (int mt=0;mt<4;++mt){
    float4 t = *(const float4*)&fb2[mt*16 + lq*4];
    f4v v = {t.x, t.y, t.z, t.w}; b2v[mt]=v;
  }
#pragma unroll
  for (int mt=0;mt<4;++mt){
    float4 t = *(const float4*)&cb1[mt*16 + lq*4];
    f4v v = {t.x*S_TANH, t.y*S_TANH, t.z*S_TANH, t.w*S_TANH}; b3v[mt]=v;
  }
#pragma unroll
  for (int mt=0;mt<4;++mt){
    float4 t = *(const float4*)&cb2[mt*16 + lq*4];
    f4v v = {t.x, t.y, t.z, t.w}; b4v[mt]=v;
  }
  if (tid<32) proc_h[tid] = (_Float16)proc[b*32+tid];
  __syncthreads();
  _Float16* xt = tiles[w][0];
  _Float16* tA = tiles[w][1];
  _Float16* tB = tiles[w][2];
  // cmb proc part (k=64..95), constant across both groups
  {
    h8 ph = *(const h8*)&proc_h[lq*8];
    *(h8*)&tB[TADDR(lm, 64+lq*8)] = ph;
  }
#pragma unroll 1
  for (int g2 = 0; g2 < 2; ++g2){
    int g = w*2 + g2;
    size_t R0 = (size_t)b*SS + g*16;
    // stage x rows (f16): lane covers row lm, feats lq*16..+15
    const float* xr = x + (R0+lm)*64 + lq*16;
    float4 x0 = *(const float4*)xr;
    float4 x1 = *(const float4*)(xr+4);
    float4 x2 = *(const float4*)(xr+8);
    float4 x3 = *(const float4*)(xr+12);
    h8 hx0 = {(_Float16)x0.x,(_Float16)x0.y,(_Float16)x0.z,(_Float16)x0.w,
              (_Float16)x1.x,(_Float16)x1.y,(_Float16)x1.z,(_Float16)x1.w};
    h8 hx1 = {(_Float16)x2.x,(_Float16)x2.y,(_Float16)x2.z,(_Float16)x2.w,
              (_Float16)x3.x,(_Float16)x3.y,(_Float16)x3.z,(_Float16)x3.w};
    *(h8*)&xt[TADDR(lm, lq*16)] = hx0;
    *(h8*)&xt[TADDR(lm, lq*16+8)] = hx1;
    __syncthreads();
    // L1: t1[32,16] = tanh2(W1s @ x + b1s)
    h8 bx0 = *(const h8*)&xt[TADDR(lm, lq*8)];
    h8 bx1 = *(const h8*)&xt[TADDR(lm, 32+lq*8)];
    f4v a1[2];
#pragma unroll
    for (int mt=0;mt<2;++mt){
      f4v a = __builtin_amdgcn_mfma_f32_16x16x32_f16(wfr1[mt][0], bx0, b1v[mt],0,0,0);
      a1[mt] = __builtin_amdgcn_mfma_f32_16x16x32_f16(wfr1[mt][1], bx1, a,0,0,0);
    }
#pragma unroll
    for (int mt=0;mt<2;++mt){
      h4 tv = {(_Float16)tanh2(a1[mt][0]),(_Float16)tanh2(a1[mt][1]),
               (_Float16)tanh2(a1[mt][2]),(_Float16)tanh2(a1[mt][3])};
      *(h4*)&tA[TADDR(lm, mt*16+lq*4)] = tv;
    }
    __syncthreads();
    // L2: fs[64,16] = W2 @ t1 + b2  -> cmb tile k=0..63
    h8 bt = *(const h8*)&tA[TADDR(lm, lq*8)];
    f4v a2[4];
#pragma unroll
    for (int mt=0;mt<4;++mt)
      a2[mt] = __builtin_amdgcn_mfma_f32_16x16x32_f16(wfr2[mt], bt, b2v[mt],0,0,0);
#pragma unroll
    for (int mt=0;mt<4;++mt){
      h4 fv = {(_Float16)a2[mt][0],(_Float16)a2[mt][1],
               (_Float16)a2[mt][2],(_Float16)a2[mt][3]};
      *(h4*)&tB[TADDR(lm, mt*16+lq*4)] = fv;
    }
    __syncthreads();
    // L3: h2[64,16] = tanh2(cW1s @ cmb + b3s)
    h8 bc0 = *(const h8*)&tB[TADDR(lm, lq*8)];
    h8 bc1 = *(const h8*)&tB[TADDR(lm, 32+lq*8)];
    h8 bc2 = *(const h8*)&tB[TADDR(lm, 64+lq*8)];
    f4v a3[4];
#pragma unroll
    for (int mt=0;mt<4;++mt){
      f4v z = {0.f,0.f,0.f,0.f};
      f4v a = __builtin_amdgcn_mfma_f32_16x16x32_f16(wfr3[mt][0], bc0, b3v[mt],0,0,0);
      f4v c = __builtin_amdgcn_mfma_f32_16x16x32_f16(wfr3[mt][1], bc1, z,0,0,0);
      a = __builtin_amdgcn_mfma_f32_16x16x32_f16(wfr3[mt][2], bc2, a,0,0,0);
      a3[mt] = a + c;
    }
#pragma unroll
    for (int mt=0;mt<4;++mt){
      h4 hv = {(_Float16)tanh2(a3[mt][0]),(_Float16)tanh2(a3[mt][1]),
               (_Float16)tanh2(a3[mt][2]),(_Float16)tanh2(a3[mt][3])};
      *(h4*)&tA[TADDR(lm, mt*16+lq*4)] = hv;
    }
    __syncthreads();
    // L4: aw[64,16] = cW2 @ h2 + b4
    h8 bh0 = *(const h8*)&tA[TADDR(lm, lq*8)];
    h8 bh1 = *(const h8*)&tA[TADDR(lm, 32+lq*8)];
    f4v a4[4];
#pragma unroll
    for (int mt=0;mt<4;++mt){
      f4v a = __builtin_amdgcn_mfma_f32_16x16x32_f16(wfr4[mt][0], bh0, b4v[mt],0,0,0);
      a4[mt] = __builtin_amdgcn_mfma_f32_16x16x32_f16(wfr4[mt][1], bh1, a,0,0,0);
    }
    // softmax over m (64 feats) per column n=lm: lanes {lm,+16,+32,+48}
    float mx = a4[0][0];
#pragma unroll
    for (int mt=0;mt<4;++mt)
#pragma unroll
      for (int r=0;r<4;++r) mx = fmaxf(mx, a4[mt][r]);
    mx = fmaxf(mx, __shfl_xor(mx,16,64));
    mx = fmaxf(mx, __shfl_xor(mx,32,64));
    f4v e4[4];
    float s = 0.f;
#pragma unroll
    for (int mt=0;mt<4;++mt)
#pragma unroll
      for (int r=0;r<4;++r){
        float e = fexp2((a4[mt][r]-mx)*LOG2E);
        e4[mt][r] = e; s += e;
      }
    s += __shfl_xor(s,16,64);
    s += __shfl_xor(s,32,64);
    float rs = frcp(s);
#pragma unroll
    for (int mt=0;mt<4;++mt){
      h4 xh = *(const h4*)&xt[TADDR(lm, mt*16+lq*4)];
      float4 fwv, wxv;
      fwv.x = e4[mt][0]*rs; fwv.y = e4[mt][1]*rs;
      fwv.z = e4[mt][2]*rs; fwv.w = e4[mt][3]*rs;
      wxv.x = (float)xh[0]*fwv.x; wxv.y = (float)xh[1]*fwv.y;
      wxv.z = (float)xh[2]*fwv.z; wxv.w = (float)xh[3]*fwv.w;
      size_t off = (R0+lm)*64 + mt*16 + lq*4;
      *(float4*)&fw_out[off] = fwv;
      *(float4*)&wx[off] = wxv;
    }
    __syncthreads();   // xt/tB safe to overwrite next group
  }
}

// ================= MFMA encoder LSTM (swapped operands) =================
// 7 waves, 16 batches/block, 64 blocks (N=16 MFMA batch cols pins grid at 64;
// 512-reg/SIMD file caps 2 waves/SIMD with weights in AGPRs). exp2-domain
// gates; split MFMA chains; sigtanh product fusion.
// ench: f16 copy of enc, row-padded to 112 (units 100..111 zeroed).
__global__ __launch_bounds__(448) void k_enc_mfma(const float* __restrict__ wx,
    const float* __restrict__ Wih, const float* __restrict__ Whh,
    const float* __restrict__ bih, const float* __restrict__ bhh,
    _Float16* __restrict__ ench){
  __shared__ __align__(16) _Float16 hbuf[2][16*128];
  __shared__ __align__(16) _Float16 xst[2][16*64];
  int tid = threadIdx.x;
  int w = tid >> 6, l = tid & 63;
  int lm = l & 15, lq = l >> 4;
  int b0 = blockIdx.x * 16;
  int au = w*16 + lm;
  bool avalid = au < 100;
  int u0 = w*16 + lq*4;
  bool uvalid = (u0 + 3) < 100;
  const float gsc[4] = {S_SIG, S_SIG, S_TANH, S_SIG};   // gate order i,f,g,o
  h8 wfr[4][6];
#pragma unroll
  for (int tt=0; tt<4; ++tt){
    int row = tt*100 + au;
#pragma unroll
    for (int cc=0; cc<6; ++cc){
      h8 f;
#pragma unroll
      for (int j=0;j<8;++j){
        int kg = cc*32 + lq*8 + j;
        float v = 0.f;
        if (avalid){
          if (kg < 64) v = Wih[(size_t)row*64 + kg];
          else { int kh = kg - 64; if (kh < 100) v = Whh[(size_t)row*100 + kh]; }
        }
        f[j] = (_Float16)(v*gsc[tt]);
      }
      wfr[tt][cc] = f;
    }
  }
  f4v biasv[4];
#pragma unroll
  for (int tt=0; tt<4; ++tt){
    if (uvalid){
      float4 bi = *(const float4*)&bih[tt*100 + u0];
      float4 bh = *(const float4*)&bhh[tt*100 + u0];
      float s = gsc[tt];
      f4v bv2 = {(bi.x+bh.x)*s, (bi.y+bh.y)*s, (bi.z+bh.z)*s, (bi.w+bh.w)*s};
      biasv[tt] = bv2;
    } else { f4v z = {0,0,0,0}; biasv[tt] = z; }
  }
  for (int i = tid; i < 2*16*128; i += 448) hbuf[0][i] = (_Float16)0.f;
  int sm = tid >> 4, skq = tid & 15;
  bool doPref = (tid < 256);
  float4 rA, rB;
  if (doPref){
    float4 xv0 = *(const float4*)(wx + ((size_t)(b0+sm)*SS + 0)*FF + skq*4);
    h4 p = {(_Float16)xv0.x,(_Float16)xv0.y,(_Float16)xv0.z,(_Float16)xv0.w};
    *(h4*)&xst[0][sm*64 + (((skq>>1) ^ (sm&7))<<3) + (skq&1)*4] = p;
    rA = *(const float4*)(wx + ((size_t)(b0+sm)*SS + 1)*FF + skq*4);   // x(1)
  }
  float cst[4] = {0.f,0.f,0.f,0.f};
  int hwaddr = lm*128 + (((2*w + (lq>>1)) ^ (lm&7))<<3) + (lq&1)*4;
  int xwaddr = sm*64 + (((skq>>1) ^ (sm&7))<<3) + (skq&1)*4;
  __syncthreads();

#define ENC_STEP(T, CUR, RCONS, RISSUE)                                          \
  {                                                                              \
    const int cur = (CUR), nxt = (CUR)^1;                                        \
    if (doPref && (T) < SS-2)                                                    \
      RISSUE = *(const float4*)(wx + ((size_t)(b0+sm)*SS + ((T)+2))*FF + skq*4); \
    h8 bact[6];                                                                  \
    _Pragma("unroll")                                                            \
    for (int cc=0; cc<2; ++cc)                                                   \
      bact[cc] = *(const h8*)&xst[cur][lm*64 + (((cc*4+lq) ^ (lm&7))<<3)];       \
    _Pragma("unroll")                                                            \
    for (int cc=0; cc<4; ++cc)                                                   \
      bact[2+cc] = *(const h8*)&hbuf[cur][lm*128 + (((cc*4+lq) ^ (lm&7))<<3)];   \
    f4v acc[4];                                                                  \
    __builtin_amdgcn_s_setprio(1);                                               \
    _Pragma("unroll")                                                            \
    for (int tt=0; tt<4; ++tt){                                                  \
      f4v a1 = biasv[tt];                                                        \
      f4v a2 = {0.f,0.f,0.f,0.f};                                                \
      a1 = __builtin_amdgcn_mfma_f32_16x16x32_f16(wfr[tt][0], bact[0], a1, 0,0,0); \
      a2 = __builtin_amdgcn_mfma_f32_16x16x32_f16(wfr[tt][1], bact[1], a2, 0,0,0); \
      a1 = __builtin_amdgcn_mfma_f32_16x16x32_f16(wfr[tt][2], bact[2], a1, 0,0,0); \
      a2 = __builtin_amdgcn_mfma_f32_16x16x32_f16(wfr[tt][3], bact[3], a2, 0,0,0); \
      a1 = __builtin_amdgcn_mfma_f32_16x16x32_f16(wfr[tt][4], bact[4], a1, 0,0,0); \
      a2 = __builtin_amdgcn_mfma_f32_16x16x32_f16(wfr[tt][5], bact[5], a2, 0,0,0); \
      acc[tt] = a1 + a2;                                                         \
    }                                                                            \
    __builtin_amdgcn_s_setprio(0);                                               \
    float hn[4];                                                                 \
    _Pragma("unroll")                                                            \
    for (int r=0;r<4;++r){                                                       \
      float Ei = fexp2(acc[0][r]), Ef = fexp2(acc[1][r]);                        \
      float Eg = fexp2(acc[2][r]), Eo = fexp2(acc[3][r]);                        \
      float cn = frcp(1.f+Ef)*cst[r] + sigtanh(Ei, Eg);                          \
      float Ec = fexp2(cn*S_TANH);                                               \
      hn[r] = sigtanh(Eo, Ec);                                                   \
      cst[r] = cn;                                                               \
    }                                                                            \
    if (uvalid){                                                                 \
      h4 hp = {(_Float16)hn[0],(_Float16)hn[1],(_Float16)hn[2],(_Float16)hn[3]}; \
      *(h4*)&hbuf[nxt][hwaddr] = hp;                                             \
      *(h4*)&ench[((size_t)(b0+lm)*SS + (T))*112 + u0] = hp;                     \
    } else {                                                                     \
      h4 z = {(_Float16)0.f,(_Float16)0.f,(_Float16)0.f,(_Float16)0.f};          \
      *(h4*)&ench[((size_t)(b0+lm)*SS + (T))*112 + u0] = z;                      \
    }                                                                            \
    if (doPref && (T) < SS-1){                                                   \
      h4 p = {(_Float16)RCONS.x,(_Float16)RCONS.y,(_Float16)RCONS.z,(_Float16)RCONS.w}; \
      *(h4*)&xst[nxt][xwaddr] = p;                                               \
    }                                                                            \
    LDS_BARRIER();                                                               \
  }

  for (int t = 0; t < SS; t += 2){
    ENC_STEP(t,   0, rA, rB)   // consumes x(t+1) from rA, issues x(t+2) into rB
    ENC_STEP(t+1, 1, rB, rA)   // consumes x(t+2) from rB, issues x(t+3) into rA
  }
#undef ENC_STEP
}

// ================= ts GEMM: ts[b,s] = aW2 @ tanh(aW1 @ enc_row + ab1) + ab2 ========
// M = B*S rows (ench f16, 112-padded), N = 64, K = 100->128 (chunk 3 half-zero).
// aW1/ab1 pre-scaled by 2/ln2 -> tanh2 on the MFMA output directly.
__global__ __launch_bounds__(256) void k_ts(const _Float16* __restrict__ ench,
    const float* __restrict__ aW1, const float* __restrict__ ab1,
    const float* __restrict__ aW2, const float* __restrict__ ab2,
    float* __restrict__ ts){
  int tid = threadIdx.x, wv = tid>>6, l = tid&63, lm = l&15, lq = l>>4;
  h8 bfr[4][4];
#pragma unroll
  for (int nt=0; nt<4; ++nt){
    int n = nt*16 + lm;
#pragma unroll
    for (int cc=0; cc<4; ++cc){
      h8 f;
#pragma unroll
      for (int j=0;j<8;++j){
        int k = cc*32 + lq*8 + j;
        f[j] = (_Float16)((k<100) ? aW1[n*100+k]*S_TANH : 0.f);
      }
      bfr[nt][cc]=f;
    }
  }
  float ab1v[4], aw2v[4];
#pragma unroll
  for (int nt=0; nt<4; ++nt){ ab1v[nt] = ab1[nt*16+lm]*S_TANH; aw2v[nt] = aW2[nt*16+lm]; }
  float ab2v = ab2[0];
  int tile0 = (blockIdx.x*4 + wv)*4;
#pragma unroll
  for (int i=0;i<4;++i){
    int M0 = (tile0+i)*16;
    const _Float16* rowp = ench + (size_t)(M0+lm)*112;
    h8 afr[4];
#pragma unroll
    for (int cc=0; cc<3; ++cc)
      afr[cc] = *(const h8*)(rowp + cc*32 + lq*8);
    if (lq < 2) afr[3] = *(const h8*)(rowp + 96 + lq*8);
    else { h8 z={0,0,0,0,0,0,0,0}; afr[3]=z; }
    f4v acc[4];
#pragma unroll
    for (int nt=0; nt<4; ++nt){
      f4v a = {ab1v[nt],ab1v[nt],ab1v[nt],ab1v[nt]};
#pragma unroll
      for (int cc=0; cc<4; ++cc)
        a = __builtin_amdgcn_mfma_f32_16x16x32_f16(afr[cc], bfr[nt][cc], a, 0,0,0);
      acc[nt]=a;
    }
    float p[4];
#pragma unroll
    for (int r=0;r<4;++r){
      p[r] = aw2v[0]*tanh2(acc[0][r]) + aw2v[1]*tanh2(acc[1][r])
           + aw2v[2]*tanh2(acc[2][r]) + aw2v[3]*tanh2(acc[3][r]);
#pragma unroll
      for (int m=1;m<16;m<<=1) p[r] += __shfl_xor(p[r], m, 64);
    }
    if (lm==0){
      float4 st; st.x=p[0]+ab2v; st.y=p[1]+ab2v; st.z=p[2]+ab2v; st.w=p[3]+ab2v;
      *(float4*)&ts[M0 + lq*4] = st;
    }
  }
}

// ------- per-b: softmax(ts) over S, ctx, bott, dh0, dc0, decpre -------
// ctx accumulated from ench (f16); GEMV split over 200 threads (2 s-halves).
__global__ __launch_bounds__(256) void k_attn2(const _Float16* __restrict__ ench,
    const float* __restrict__ ts,
    const float* __restrict__ bW, const float* __restrict__ bb_,
    const float* __restrict__ h0W, const float* __restrict__ h0b,
    const float* __restrict__ c0W, const float* __restrict__ c0b,
    const float* __restrict__ dWih, const float* __restrict__ dbih, const float* __restrict__ dbhh,
    float* __restrict__ tw_out, float* __restrict__ dh0, float* __restrict__ dc0,
    float* __restrict__ decpre){
  __shared__ float tsb[SS];
  __shared__ float ctxb[HH];
  __shared__ float ctx2[200];
  __shared__ float bottb[32];
  __shared__ float red[8];
  int tid = threadIdx.x, wv = tid>>6, lane = tid&63;
  int b = blockIdx.x;
  const _Float16* encb = ench + (size_t)b*SS*112;
  float tv = (tid < SS) ? ts[(size_t)b*SS + tid] : -1e30f;
  float m = wmax(tv);
  if (lane==0) red[wv]=m;
  __syncthreads();
  m = fmaxf(fmaxf(red[0],red[1]), fmaxf(red[2],red[3]));
  float e = (tid < SS) ? __expf(tv - m) : 0.f;
  float sm = wsum(e);
  if (lane==0) red[4+wv]=sm;
  __syncthreads();
  float denom = red[4]+red[5]+red[6]+red[7];
  float rden = frcp(denom);
  if (tid < SS){
    float twv = e*rden;
    tw_out[(size_t)b*SS + tid] = twv;
    tsb[tid] = twv;
  }
  __syncthreads();
  if (tid < 200){
    int u = (tid < 100) ? tid : (tid - 100);
    int sb = (tid < 100) ? 0 : 64;
    const _Float16* ep = encb + (size_t)sb*112 + u;
    const float* tp = tsb + sb;
    float a = 0.f;
#pragma unroll 4
    for (int s=0;s<64;++s) a += tp[s]*(float)ep[s*112];
    ctx2[tid] = a;
  }
  __syncthreads();
  if (tid < HH) ctxb[tid] = ctx2[tid] + ctx2[tid+100];
  __syncthreads();
  if (tid < 32){
    float a = bb_[tid];
    const float* wr = bW + tid*HH;
    for (int k=0;k<HH;++k) a += wr[k]*ctxb[k];
    bottb[tid]=a;
  }
  __syncthreads();
  if (tid < HH){
    float a = h0b[tid];
    const float* wr = h0W + tid*32;
#pragma unroll
    for (int k=0;k<32;++k) a += wr[k]*bottb[k];
    dh0[(size_t)b*HH + tid] = a;
  } else if (tid < 200){
    int jj = tid-100;
    float a = c0b[jj];
    const float* wr = c0W + jj*32;
#pragma unroll
    for (int k=0;k<32;++k) a += wr[k]*bottb[k];
    dc0[(size_t)b*HH + jj] = a;
  }
  {
    int jj = tid;
    float a = dbih[jj]+dbhh[jj];
    const float* wr = dWih + jj*32;
#pragma unroll
    for (int k=0;k<32;++k) a += wr[k]*bottb[k];
    decpre[(size_t)b*400 + jj] = a;
    jj = tid + 256;
    if (jj < 400){
      float a2v = dbih[jj]+dbhh[jj];
      const float* wr2 = dWih + jj*32;
#pragma unroll
      for (int k=0;k<32;++k) a2v += wr2[k]*bottb[k];
      decpre[(size_t)b*400 + jj] = a2v;
    }
  }
}

// ================= MFMA decoder LSTM (swapped operands) =================
// f16 dech output; exp2-domain gates; split chains; sigtanh fusion.
__global__ __launch_bounds__(448) void k_dec_mfma(const float* __restrict__ decpre,
    const float* __restrict__ Whh,
    const float* __restrict__ dh0, const float* __restrict__ dc0,
    _Float16* __restrict__ dech){
  __shared__ __align__(16) _Float16 hbuf[2][16*128];
  int tid = threadIdx.x;
  int w = tid >> 6, l = tid & 63;
  int lm = l & 15, lq = l >> 4;
  int b0 = blockIdx.x * 16;
  int au = w*16 + lm;
  bool avalid = au < 100;
  int u0 = w*16 + lq*4;
  bool uvalid = (u0 + 3) < 100;
  const float gsc[4] = {S_SIG, S_SIG, S_TANH, S_SIG};
  h8 wfr[4][4];
#pragma unroll
  for (int tt = 0; tt < 4; ++tt){
    int row = tt*100 + au;
#pragma unroll
    for (int cc = 0; cc < 4; ++cc){
      h8 f;
#pragma unroll
      for (int j = 0; j < 8; ++j){
        int kh = cc*32 + lq*8 + j;
        float v = (avalid && kh < 100) ? Whh[(size_t)row*100 + kh] : 0.f;
        f[j] = (_Float16)(v*gsc[tt]);
      }
      wfr[tt][cc] = f;
    }
  }
  f4v pre[4];
  float cst[4] = {0.f,0.f,0.f,0.f};
  if (uvalid){
#pragma unroll
    for (int tt = 0; tt < 4; ++tt){
      float4 p = *(const float4*)&decpre[(size_t)(b0+lm)*400 + tt*100 + u0];
      float s = gsc[tt];
      f4v pv = {p.x*s, p.y*s, p.z*s, p.w*s};
      pre[tt] = pv;
    }
    float4 c4 = *(const float4*)&dc0[(size_t)(b0+lm)*100 + u0];
    cst[0]=c4.x; cst[1]=c4.y; cst[2]=c4.z; cst[3]=c4.w;
  } else {
    f4v z = {0,0,0,0};
#pragma unroll
    for (int tt = 0; tt < 4; ++tt) pre[tt] = z;
  }
  for (int i = tid; i < 16*128; i += 448) hbuf[1][i] = (_Float16)0.f;
  for (int idx = tid; idx < 16*128; idx += 448){
    int m = idx >> 7, u2 = idx & 127;
    float v = (u2 < 100) ? dh0[(size_t)(b0+m)*HH + u2] : 0.f;
    hbuf[0][m*128 + (((u2>>3) ^ (m&7))<<3) + (u2&7)] = (_Float16)v;
  }
  int hwaddr = lm*128 + (((2*w + (lq>>1)) ^ (lm&7))<<3) + (lq&1)*4;
  __syncthreads();

#define DEC_STEP(T, CUR)                                                         \
  {                                                                              \
    const int cur = (CUR), nxt = (CUR)^1;                                        \
    h8 bact[4];                                                                  \
    _Pragma("unroll")                                                            \
    for (int cc = 0; cc < 4; ++cc)                                               \
      bact[cc] = *(const h8*)&hbuf[cur][lm*128 + (((cc*4+lq) ^ (lm&7))<<3)];     \
    f4v acc[4];                                                                  \
    __builtin_amdgcn_s_setprio(1);                                               \
    _Pragma("unroll")                                                            \
    for (int tt = 0; tt < 4; ++tt){                                              \
      f4v a1 = pre[tt];                                                          \
      f4v a2 = {0.f,0.f,0.f,0.f};                                                \
      a1 = __builtin_amdgcn_mfma_f32_16x16x32_f16(wfr[tt][0], bact[0], a1, 0,0,0); \
      a2 = __builtin_amdgcn_mfma_f32_16x16x32_f16(wfr[tt][1], bact[1], a2, 0,0,0); \
      a1 = __builtin_amdgcn_mfma_f32_16x16x32_f16(wfr[tt][2], bact[2], a1, 0,0,0); \
      a2 = __builtin_amdgcn_mfma_f32_16x16x32_f16(wfr[tt][3], bact[3], a2, 0,0,0); \
      acc[tt] = a1 + a2;                                                         \
    }                                                                            \
    __builtin_amdgcn_s_setprio(0);                                               \
    float hn[4];                                                                 \
    _Pragma("unroll")                                                            \
    for (int r=0;r<4;++r){                                                       \
      float Ei = fexp2(acc[0][r]), Ef = fexp2(acc[1][r]);                        \
      float Eg = fexp2(acc[2][r]), Eo = fexp2(acc[3][r]);                        \
      float cn = frcp(1.f+Ef)*cst[r] + sigtanh(Ei, Eg);                          \
      float Ec = fexp2(cn*S_TANH);                                               \
      hn[r] = sigtanh(Eo, Ec);                                                   \
      cst[r] = cn;                                                               \
    }                                                                            \
    if (uvalid){                                                                 \
      h4 hp = {(_Float16)hn[0],(_Float16)hn[1],(_Float16)hn[2],(_Float16)hn[3]}; \
      *(h4*)&hbuf[nxt][hwaddr] = hp;                                             \
      *(h4*)&dech[((size_t)(b0+lm)*SS + (T))*112 + u0] = hp;                     \
    }                                                                            \
    LDS_BARRIER();                                                               \
  }

  for (int t = 0; t < SS; t += 2){
    DEC_STEP(t,   0)
    DEC_STEP(t+1, 1)
  }
#undef DEC_STEP
}

// ------------- out = dec @ oW^T + ob (dec consumed as f16 dech) -------------
// 512 blocks x 4 row-tiles; oWt staged once per block.
__global__ __launch_bounds__(256) void k_out(const _Float16* __restrict__ dech,
    const float* __restrict__ oW, const float* __restrict__ ob, float* __restrict__ out0){
  __shared__ float oWt[100*64];
  __shared__ float dsr[64*112];
  int tid=threadIdx.x;
  for (int i=tid;i<6400;i+=256){ int j=i/100,k=i%100; oWt[k*64+j]=oW[i]; }
  int j = tid&63, rbt = tid>>6;
  float obv = ob[j];
  for (int rb = 0; rb < 4; ++rb){
    size_t R0 = (size_t)blockIdx.x*256 + rb*64;
    __syncthreads();   // oWt ready (rb=0) / dsr readers done (rb>0)
    {
      const h8* db = (const h8*)(dech + R0*112);
      for (int i=tid;i<896;i+=256){
        h8 v = db[i];
        float* d = dsr + i*8;
#pragma unroll
        for (int jj=0;jj<8;++jj) d[jj] = (float)v[jj];
      }
    }
    __syncthreads();
    float acc[16];
#pragma unroll
    for (int i=0;i<16;++i) acc[i]=0.f;
    for (int k=0;k<100;++k){
      float w = oWt[k*64+j];
#pragma unroll
      for (int i=0;i<16;++i) acc[i] += w*dsr[(rbt + i*4)*112 + k];
    }
#pragma unroll
    for (int i=0;i<16;++i) out0[(R0 + rbt + i*4)*64 + j] = acc[i] + obv;
  }
}

extern "C" void kernel_launch(void* const* d_in, const int* in_sizes, int n_in,
                              void* d_out, int out_size, void* d_ws, size_t ws_size,
                              hipStream_t stream) {
  const float* x    = (const float*)d_in[0];
  const float* c1w  = (const float*)d_in[1];
  const float* c1b  = (const float*)d_in[2];
  const float* c2w  = (const float*)d_in[3];
  const float* c2b  = (const float*)d_in[4];
  const float* fW1  = (const float*)d_in[5];
  const float* fb1  = (const float*)d_in[6];
  const float* fW2  = (const float*)d_in[7];
  const float* fb2  = (const float*)d_in[8];
  const float* cW1  = (const float*)d_in[9];
  const float* cb1  = (const float*)d_in[10];
  const float* cW2  = (const float*)d_in[11];
  const float* cb2  = (const float*)d_in[12];
  const float* eWih = (const float*)d_in[13];
  const float* eWhh = (const float*)d_in[14];
  const float* ebih = (const float*)d_in[15];
  const float* ebhh = (const float*)d_in[16];
  const float* aW1  = (const float*)d_in[17];
  const float* ab1  = (const float*)d_in[18];
  const float* aW2  = (const float*)d_in[19];
  const float* ab2  = (const float*)d_in[20];
  const float* bW   = (const float*)d_in[21];
  const float* bb   = (const float*)d_in[22];
  const float* h0W  = (const float*)d_in[23];
  const float* h0b  = (const float*)d_in[24];
  const float* c0W  = (const float*)d_in[25];
  const float* c0b  = (const float*)d_in[26];
  const float* dWih = (const float*)d_in[27];
  const float* dWhh = (const float*)d_in[28];
  const float* dbih = (const float*)d_in[29];
  const float* dbhh = (const float*)d_in[30];
  const float* oW   = (const float*)d_in[31];
  const float* ob   = (const float*)d_in[32];

  float* out0   = (float*)d_out;
  float* out_tw = out0 + (size_t)BB*SS*FF;
  float* out_fw = out_tw + (size_t)BB*SS;

  char* ws = (char*)d_ws;
  // gram + fs buffers eliminated (R8 fusions)
  __half* pool1  = (__half*)(ws + 16777216);    // 33.55 MB (channel-last [b][p][ic])
  float*  proc   = (float*) (ws + 50331648);    // 0.13 MB
  float*  wx     = (float*) (ws + 84017152);    // 33.55 MB
  float*  dh0    = (float*) (ws + 170000384);   // 0.41 MB
  float*  dc0    = (float*) (ws + 170409984);   // 0.41 MB
  float*  decpre = (float*) (ws + 170819584);   // 1.64 MB
  _Float16* dech = (_Float16*)(ws + 172457984); // 29.36 MB (f16, [row][112])
  float*     tsbuf = (float*)(ws + 0);          // 0.52 MB
  _Float16*  ench  = (_Float16*)(ws + 50462720);// 29.36 MB

  k_gc1<<<BB, 256, 0, stream>>>(x, c1w, c1b, pool1);
  k_conv2mfma<<<BB, 512, 0, stream>>>(pool1, c2w, c2b, proc);
  k_feat<<<BB, 256, 0, stream>>>(x, proc, fW1, fb1, fW2, fb2,
                                 cW1, cb1, cW2, cb2, out_fw, wx);
  k_enc_mfma<<<64, 448, 0, stream>>>(wx, eWih, eWhh, ebih, ebhh, ench);
  k_ts<<<512, 256, 0, stream>>>(ench, aW1, ab1, aW2, ab2, tsbuf);
  k_attn2<<<BB, 256, 0, stream>>>(ench, tsbuf, bW, bb, h0W, h0b, c0W, c0b,
                                  dWih, dbih, dbhh, out_tw, dh0, dc0, decpre);
  k_dec_mfma<<<64, 448, 0, stream>>>(decpre, dWhh, dh0, dc0, dech);
  k_out<<<512, 256, 0, stream>>>(dech, oW, ob, out0);
}

// Round 9
// 625.820 us; speedup vs baseline: 1.5953x; 1.0823x over previous
//
#include <hip/hip_runtime.h>
#include <hip/hip_fp16.h>

#define BB 1024
#define SS 128
#define FF 64
#define HH 100

typedef _Float16 h8 __attribute__((ext_vector_type(8)));
typedef _Float16 h4 __attribute__((ext_vector_type(4)));
typedef float f4v __attribute__((ext_vector_type(4)));

// --- fast transcendentals ---------------------------------------------------
// v_rcp_f32 (~1 ulp); fp32 '/' without fast-math is ~11 VALU ops (R5: -32%).
// exp2-domain gates (R6): fold 1/ln2 (and tanh's 2x) into weights/biases so
// sigma/tanh start at v_exp_f32 directly.
// R7: product fusion sigma(zi)*tanh(zt) = (Et-1)*rcp((1+Ei)(1+Et)).
#define S_SIG  (-1.4426950408889634f)   // i,f,o rows: acc = -z/ln2
#define S_TANH ( 2.8853900817779268f)   // g rows:     acc = 2z/ln2
#define LOG2E  ( 1.4426950408889634f)
__device__ __forceinline__ float frcp(float x){ return __builtin_amdgcn_rcpf(x); }
__device__ __forceinline__ float fexp2(float x){ return __builtin_amdgcn_exp2f(x); }
__device__ __forceinline__ float sigm2(float a){ return frcp(1.f + fexp2(a)); }        // a = -z/ln2
__device__ __forceinline__ float tanh2(float a){ return 1.f - 2.f*frcp(fexp2(a)+1.f);} // a = 2z/ln2
__device__ __forceinline__ float ftanh(float x){ return tanh2(x*S_TANH); }             // unscaled arg
__device__ __forceinline__ float sigtanh(float Ei, float Et){
  float D = __builtin_fmaf(Ei, Et, Ei) + (Et + 1.f);   // (1+Ei)(1+Et)
  return (Et - 1.f) * frcp(D);
}

// LDS-only barrier: waits own LDS ops, does NOT drain vmcnt (global stores
// stay in flight across steps).
#define LDS_BARRIER() __asm__ __volatile__("s_waitcnt lgkmcnt(0)\ns_barrier" ::: "memory")

__device__ __forceinline__ float wsum(float v){
#pragma unroll
  for (int m = 32; m >= 1; m >>= 1) v += __shfl_xor(v, m, 64);
  return v;
}
__device__ __forceinline__ float wmax(float v){
#pragma unroll
  for (int m = 32; m >= 1; m >>= 1) v = fmaxf(v, __shfl_xor(v, m, 64));
  return v;
}

// ====== gram + conv1(3x3,1->16)+relu+maxpool2 FUSED ======
// gram[b] (64x64) is computed in LDS and consumed in-place by conv1pool.
__global__ __launch_bounds__(256) void k_gc1(const float* __restrict__ x,
    const float* __restrict__ c1w, const float* __restrict__ c1b, __half* __restrict__ pool1){
  __shared__ __align__(16) float xs[SS*FF];
  __shared__ float img2[66*66];
  __shared__ float ws1[144];
  __shared__ float bs1[16];
  int tid=threadIdx.x, b=blockIdx.x;
  const float* xb = x + (size_t)b*SS*FF;
  for (int i = tid; i < SS*FF/4; i += 256)
    ((float4*)xs)[i] = ((const float4*)xb)[i];
  for (int i=tid;i<66*66;i+=256) img2[i]=0.f;
  if (tid<144) ws1[tid]=c1w[tid];
  if (tid<16) bs1[tid]=c1b[tid];
  __syncthreads();
  int ti = (tid & 15) * 4, tj = (tid >> 4) * 4;
  float acc[4][4];
#pragma unroll
  for (int a=0;a<4;++a)
#pragma unroll
    for (int c=0;c<4;++c) acc[a][c]=0.f;
  for (int s = 0; s < SS; ++s) {
    const float* row = xs + s*FF;
    float4 av = *(const float4*)(row + ti);
    float4 bv = *(const float4*)(row + tj);
    float aa[4] = {av.x,av.y,av.z,av.w};
    float bb2[4] = {bv.x,bv.y,bv.z,bv.w};
#pragma unroll
    for (int a=0;a<4;++a)
#pragma unroll
      for (int c=0;c<4;++c) acc[a][c] += aa[a]*bb2[c];
  }
#pragma unroll
  for (int a=0;a<4;++a)
#pragma unroll
    for (int c=0;c<4;++c) img2[(ti+a+1)*66 + (tj+c+1)] = acc[a][c];
  __syncthreads();
  int oc = tid>>4, slot = tid&15;
  float wr[9];
#pragma unroll
  for (int t=0;t<9;++t) wr[t]=ws1[oc*9+t];
  float bo = bs1[oc];
  for (int p=slot;p<1024;p+=16){
    int py=p>>5, px=p&31;
    int y0=py*2, x0=px*2;
    float v[4][4];
#pragma unroll
    for (int wy=0;wy<4;++wy)
#pragma unroll
      for (int wxx=0;wxx<4;++wxx) v[wy][wxx]=img2[(y0+wy)*66 + x0+wxx];
    float s00=bo,s01=bo,s10=bo,s11=bo;
#pragma unroll
    for (int ky=0;ky<3;++ky)
#pragma unroll
      for (int kx=0;kx<3;++kx){
        float w=wr[ky*3+kx];
        s00 += v[ky][kx]*w;   s01 += v[ky][kx+1]*w;
        s10 += v[ky+1][kx]*w; s11 += v[ky+1][kx+1]*w;
      }
    float mx = fmaxf(fmaxf(s00,s01),fmaxf(s10,s11));
    pool1[(size_t)b*16384 + p*16 + oc] = __float2half(fmaxf(mx,0.f));
  }
}

// ================= conv2 as implicit-im2col MFMA GEMM =================
__global__ __launch_bounds__(512, 4) void k_conv2mfma(const __half* __restrict__ pool1,
    const float* __restrict__ c2w, const float* __restrict__ c2b, float* __restrict__ proc){
  __shared__ __align__(16) _Float16 img[(34*34+1)*24];   // +1 zero slot
  __shared__ float red[8][32];
  int b = blockIdx.x, tid = threadIdx.x;
  int wv = tid>>6, l = tid&63, lm = l&15, lq = l>>4;
  h8 bfr[2][5];
  float biasv[2];
#pragma unroll
  for (int nt=0; nt<2; ++nt){
    int oc = nt*16 + lm;
    biasv[nt] = c2b[oc];
#pragma unroll
    for (int c=0;c<5;++c){
      h8 f;
#pragma unroll
      for (int j=0;j<8;++j){
        int k = c*32 + lq*8 + j;
        int tap = k>>4, ic = k&15;
        f[j] = (_Float16)((tap<9) ? c2w[oc*144 + ic*9 + tap] : 0.f);
      }
      bfr[nt][c]=f;
    }
  }
  {
    h8 z = {0,0,0,0,0,0,0,0};
    for (int i=tid; i<(34*34+1)*3; i+=512) ((h8*)img)[i] = z;
  }
  __syncthreads();
  const __half* src = pool1 + (size_t)b*16384;
  for (int pp=tid; pp<1024; pp+=512){
    int y=pp>>5, x=pp&31;
    const h8* s = (const h8*)(src + pp*16);
    h8* d = (h8*)&img[((y+1)*34 + (x+1))*24];
    d[0]=s[0]; d[1]=s[1];
  }
  __syncthreads();
  f4v ssum0 = {0,0,0,0}, ssum1 = {0,0,0,0};
#pragma unroll 2
  for (int i=0;i<8;++i){
    int mt = wv + i*8;
    int y = mt>>1, x0 = (mt&1)*16;
    h8 afr[5];
#pragma unroll
    for (int c=0;c<5;++c){
      int tap = 2*c + (lq>>1);
      int addr;
      if (c==4 && lq>=2) addr = 34*34*24;
      else {
        int dy = tap/3 - 1, dx = tap - (tap/3)*3 - 1;
        addr = ((y+dy+1)*34 + (x0+lm+dx+1))*24 + (lq&1)*8;
      }
      afr[c] = *(const h8*)&img[addr];
    }
    f4v a0 = {biasv[0],biasv[0],biasv[0],biasv[0]};
    f4v a1 = {biasv[1],biasv[1],biasv[1],biasv[1]};
#pragma unroll
    for (int c=0;c<5;++c){
      a0 = __builtin_amdgcn_mfma_f32_16x16x32_f16(afr[c], bfr[0][c], a0, 0,0,0);
      a1 = __builtin_amdgcn_mfma_f32_16x16x32_f16(afr[c], bfr[1][c], a1, 0,0,0);
    }
#pragma unroll
    for (int r=0;r<4;++r){
      ssum0[r] += fmaxf(a0[r],0.f);
      ssum1[r] += fmaxf(a1[r],0.f);
    }
  }
  float s0 = ssum0[0]+ssum0[1]+ssum0[2]+ssum0[3];
  float s1 = ssum1[0]+ssum1[1]+ssum1[2]+ssum1[3];
  s0 += __shfl_xor(s0,16,64); s0 += __shfl_xor(s0,32,64);
  s1 += __shfl_xor(s1,16,64); s1 += __shfl_xor(s1,32,64);
  if (lq==0){ red[wv][lm]=s0; red[wv][16+lm]=s1; }
  __syncthreads();
  if (tid<32){
    float t=0.f;
#pragma unroll
    for (int w2=0;w2<8;++w2) t += red[w2][tid];
    proc[b*32+tid] = t*(1.f/1024.f);
  }
}

// ====== fused feature pipeline (fs + attnmlp), MFMA ======
// R9: wx emitted as f16 (wxh) -- enc is the only consumer; halves its stream
// bytes and removes 4 cvt/step/thread from the recurrence staging.
#define TADDR(row,k) (((row)<<7) + (((((k)>>3) ^ (row)) & 15)<<3) + ((k)&7))
__global__ __launch_bounds__(256, 2) void k_feat(const float* __restrict__ x,
    const float* __restrict__ proc,
    const float* __restrict__ fW1, const float* __restrict__ fb1,
    const float* __restrict__ fW2, const float* __restrict__ fb2,
    const float* __restrict__ cW1, const float* __restrict__ cb1,
    const float* __restrict__ cW2, const float* __restrict__ cb2,
    float* __restrict__ fw_out, _Float16* __restrict__ wxh){
  __shared__ __align__(16) _Float16 tiles[4][3][2048];   // [wave][xt,tA,tB][16*128]
  __shared__ __align__(16) _Float16 proc_h[32];
  int tid = threadIdx.x, w = tid>>6, l = tid&63, lm = l&15, lq = l>>4;
  int b = blockIdx.x;
  h8 wfr1[2][2], wfr2[4], wfr3[4][3], wfr4[4][2];
#pragma unroll
  for (int mt=0; mt<2; ++mt)
#pragma unroll
    for (int kc=0; kc<2; ++kc){
      h8 f;
#pragma unroll
      for (int j=0;j<8;++j) f[j] = (_Float16)(fW1[(mt*16+lm)*64 + kc*32 + lq*8 + j]*S_TANH);
      wfr1[mt][kc]=f;
    }
#pragma unroll
  for (int mt=0; mt<4; ++mt){
    h8 f;
#pragma unroll
    for (int j=0;j<8;++j) f[j] = (_Float16)(fW2[(mt*16+lm)*32 + lq*8 + j]);
    wfr2[mt]=f;
  }
#pragma unroll
  for (int mt=0; mt<4; ++mt)
#pragma unroll
    for (int kc=0; kc<3; ++kc){
      h8 f;
#pragma unroll
      for (int j=0;j<8;++j) f[j] = (_Float16)(cW1[(mt*16+lm)*96 + kc*32 + lq*8 + j]*S_TANH);
      wfr3[mt][kc]=f;
    }
#pragma unroll
  for (int mt=0; mt<4; ++mt)
#pragma unroll
    for (int kc=0; kc<2; ++kc){
      h8 f;
#pragma unroll
      for (int j=0;j<8;++j) f[j] = (_Float16)(cW2[(mt*16+lm)*64 + kc*32 + lq*8 + j]);
      wfr4[mt][kc]=f;
    }
  f4v b1v[2], b2v[4], b3v[4], b4v[4];
#pragma unroll
  for (int mt=0;mt<2;++mt){
    float4 t = *(const float4*)&fb1[mt*16 + lq*4];
    f4v v = {t.x*S_TANH, t.y*S_TANH, t.z*S_TANH, t.w*S_TANH}; b1v[mt]=v;
  }
#pragma unroll
  for (int mt=0;mt<4;++mt){
    float4 t = *(const float4*)&fb2[mt*16 + lq*4];
    f4v v = {t.x, t.y, t.z, t.w}; b2v[mt]=v;
  }
#pragma unroll
  for (int mt=0;mt<4;++mt){
    float4 t = *(const float4*)&cb1[mt*16 + lq*4];
    f4v v = {t.x*S_TANH, t.y*S_TANH, t.z*S_TANH, t.w*S_TANH}; b3v[mt]=v;
  }
#pragma unroll
  for (int mt=0;mt<4;++mt){
    float4 t = *(const float4*)&cb2[mt*16 + lq*4];
    f4v v = {t.x, t.y, t.z, t.w}; b4v[mt]=v;
  }
  if (tid<32) proc_h[tid] = (_Float16)proc[b*32+tid];
  __syncthreads();
  _Float16* xt = tiles[w][0];
  _Float16* tA = tiles[w][1];
  _Float16* tB = tiles[w][2];
  {
    h8 ph = *(const h8*)&proc_h[lq*8];
    *(h8*)&tB[TADDR(lm, 64+lq*8)] = ph;
  }
#pragma unroll 1
  for (int g2 = 0; g2 < 2; ++g2){
    int g = w*2 + g2;
    size_t R0 = (size_t)b*SS + g*16;
    const float* xr = x + (R0+lm)*64 + lq*16;
    float4 x0 = *(const float4*)xr;
    float4 x1 = *(const float4*)(xr+4);
    float4 x2 = *(const float4*)(xr+8);
    float4 x3 = *(const float4*)(xr+12);
    h8 hx0 = {(_Float16)x0.x,(_Float16)x0.y,(_Float16)x0.z,(_Float16)x0.w,
              (_Float16)x1.x,(_Float16)x1.y,(_Float16)x1.z,(_Float16)x1.w};
    h8 hx1 = {(_Float16)x2.x,(_Float16)x2.y,(_Float16)x2.z,(_Float16)x2.w,
              (_Float16)x3.x,(_Float16)x3.y,(_Float16)x3.z,(_Float16)x3.w};
    *(h8*)&xt[TADDR(lm, lq*16)] = hx0;
    *(h8*)&xt[TADDR(lm, lq*16+8)] = hx1;
    __syncthreads();
    h8 bx0 = *(const h8*)&xt[TADDR(lm, lq*8)];
    h8 bx1 = *(const h8*)&xt[TADDR(lm, 32+lq*8)];
    f4v a1[2];
#pragma unroll
    for (int mt=0;mt<2;++mt){
      f4v a = __builtin_amdgcn_mfma_f32_16x16x32_f16(wfr1[mt][0], bx0, b1v[mt],0,0,0);
      a1[mt] = __builtin_amdgcn_mfma_f32_16x16x32_f16(wfr1[mt][1], bx1, a,0,0,0);
    }
#pragma unroll
    for (int mt=0;mt<2;++mt){
      h4 tv = {(_Float16)tanh2(a1[mt][0]),(_Float16)tanh2(a1[mt][1]),
               (_Float16)tanh2(a1[mt][2]),(_Float16)tanh2(a1[mt][3])};
      *(h4*)&tA[TADDR(lm, mt*16+lq*4)] = tv;
    }
    __syncthreads();
    h8 bt = *(const h8*)&tA[TADDR(lm, lq*8)];
    f4v a2[4];
#pragma unroll
    for (int mt=0;mt<4;++mt)
      a2[mt] = __builtin_amdgcn_mfma_f32_16x16x32_f16(wfr2[mt], bt, b2v[mt],0,0,0);
#pragma unroll
    for (int mt=0;mt<4;++mt){
      h4 fv = {(_Float16)a2[mt][0],(_Float16)a2[mt][1],
               (_Float16)a2[mt][2],(_Float16)a2[mt][3]};
      *(h4*)&tB[TADDR(lm, mt*16+lq*4)] = fv;
    }
    __syncthreads();
    h8 bc0 = *(const h8*)&tB[TADDR(lm, lq*8)];
    h8 bc1 = *(const h8*)&tB[TADDR(lm, 32+lq*8)];
    h8 bc2 = *(const h8*)&tB[TADDR(lm, 64+lq*8)];
    f4v a3[4];
#pragma unroll
    for (int mt=0;mt<4;++mt){
      f4v z = {0.f,0.f,0.f,0.f};
      f4v a = __builtin_amdgcn_mfma_f32_16x16x32_f16(wfr3[mt][0], bc0, b3v[mt],0,0,0);
      f4v c = __builtin_amdgcn_mfma_f32_16x16x32_f16(wfr3[mt][1], bc1, z,0,0,0);
      a = __builtin_amdgcn_mfma_f32_16x16x32_f16(wfr3[mt][2], bc2, a,0,0,0);
      a3[mt] = a + c;
    }
#pragma unroll
    for (int mt=0;mt<4;++mt){
      h4 hv = {(_Float16)tanh2(a3[mt][0]),(_Float16)tanh2(a3[mt][1]),
               (_Float16)tanh2(a3[mt][2]),(_Float16)tanh2(a3[mt][3])};
      *(h4*)&tA[TADDR(lm, mt*16+lq*4)] = hv;
    }
    __syncthreads();
    h8 bh0 = *(const h8*)&tA[TADDR(lm, lq*8)];
    h8 bh1 = *(const h8*)&tA[TADDR(lm, 32+lq*8)];
    f4v a4[4];
#pragma unroll
    for (int mt=0;mt<4;++mt){
      f4v a = __builtin_amdgcn_mfma_f32_16x16x32_f16(wfr4[mt][0], bh0, b4v[mt],0,0,0);
      a4[mt] = __builtin_amdgcn_mfma_f32_16x16x32_f16(wfr4[mt][1], bh1, a,0,0,0);
    }
    float mx = a4[0][0];
#pragma unroll
    for (int mt=0;mt<4;++mt)
#pragma unroll
      for (int r=0;r<4;++r) mx = fmaxf(mx, a4[mt][r]);
    mx = fmaxf(mx, __shfl_xor(mx,16,64));
    mx = fmaxf(mx, __shfl_xor(mx,32,64));
    f4v e4[4];
    float s = 0.f;
#pragma unroll
    for (int mt=0;mt<4;++mt)
#pragma unroll
      for (int r=0;r<4;++r){
        float e = fexp2((a4[mt][r]-mx)*LOG2E);
        e4[mt][r] = e; s += e;
      }
    s += __shfl_xor(s,16,64);
    s += __shfl_xor(s,32,64);
    float rs = frcp(s);
#pragma unroll
    for (int mt=0;mt<4;++mt){
      h4 xh = *(const h4*)&xt[TADDR(lm, mt*16+lq*4)];
      float4 fwv;
      fwv.x = e4[mt][0]*rs; fwv.y = e4[mt][1]*rs;
      fwv.z = e4[mt][2]*rs; fwv.w = e4[mt][3]*rs;
      h4 wh = {(_Float16)((float)xh[0]*fwv.x), (_Float16)((float)xh[1]*fwv.y),
               (_Float16)((float)xh[2]*fwv.z), (_Float16)((float)xh[3]*fwv.w)};
      size_t off = (R0+lm)*64 + mt*16 + lq*4;
      *(float4*)&fw_out[off] = fwv;
      *(h4*)&wxh[off] = wh;
    }
    __syncthreads();
  }
}

// ================= MFMA encoder LSTM (swapped operands) =================
// 7 waves, 16 batches/block, 64 blocks. exp2-domain gates; split MFMA chains;
// sigtanh fusion. R9: consumes wxh (f16) -- staging is a raw h4 copy, no cvt.
// ench: f16 copy of enc, row-padded to 112 (units 100..111 zeroed).
__global__ __launch_bounds__(448) void k_enc_mfma(const _Float16* __restrict__ wxh,
    const float* __restrict__ Wih, const float* __restrict__ Whh,
    const float* __restrict__ bih, const float* __restrict__ bhh,
    _Float16* __restrict__ ench){
  __shared__ __align__(16) _Float16 hbuf[2][16*128];
  __shared__ __align__(16) _Float16 xst[2][16*64];
  int tid = threadIdx.x;
  int w = tid >> 6, l = tid & 63;
  int lm = l & 15, lq = l >> 4;
  int b0 = blockIdx.x * 16;
  int au = w*16 + lm;
  bool avalid = au < 100;
  int u0 = w*16 + lq*4;
  bool uvalid = (u0 + 3) < 100;
  const float gsc[4] = {S_SIG, S_SIG, S_TANH, S_SIG};   // gate order i,f,g,o
  h8 wfr[4][6];
#pragma unroll
  for (int tt=0; tt<4; ++tt){
    int row = tt*100 + au;
#pragma unroll
    for (int cc=0; cc<6; ++cc){
      h8 f;
#pragma unroll
      for (int j=0;j<8;++j){
        int kg = cc*32 + lq*8 + j;
        float v = 0.f;
        if (avalid){
          if (kg < 64) v = Wih[(size_t)row*64 + kg];
          else { int kh = kg - 64; if (kh < 100) v = Whh[(size_t)row*100 + kh]; }
        }
        f[j] = (_Float16)(v*gsc[tt]);
      }
      wfr[tt][cc] = f;
    }
  }
  f4v biasv[4];
#pragma unroll
  for (int tt=0; tt<4; ++tt){
    if (uvalid){
      float4 bi = *(const float4*)&bih[tt*100 + u0];
      float4 bh = *(const float4*)&bhh[tt*100 + u0];
      float s = gsc[tt];
      f4v bv2 = {(bi.x+bh.x)*s, (bi.y+bh.y)*s, (bi.z+bh.z)*s, (bi.w+bh.w)*s};
      biasv[tt] = bv2;
    } else { f4v z = {0,0,0,0}; biasv[tt] = z; }
  }
  for (int i = tid; i < 2*16*128; i += 448) hbuf[0][i] = (_Float16)0.f;
  int sm = tid >> 4, skq = tid & 15;
  bool doPref = (tid < 256);
  int xwaddr = sm*64 + (((skq>>1) ^ (sm&7))<<3) + (skq&1)*4;
  h4 rA, rB;
  if (doPref){
    *(h4*)&xst[0][xwaddr] = *(const h4*)(wxh + ((size_t)(b0+sm)*SS + 0)*FF + skq*4);
    rA = *(const h4*)(wxh + ((size_t)(b0+sm)*SS + 1)*FF + skq*4);   // x(1)
  }
  float cst[4] = {0.f,0.f,0.f,0.f};
  int hwaddr = lm*128 + (((2*w + (lq>>1)) ^ (lm&7))<<3) + (lq&1)*4;
  __syncthreads();

#define ENC_STEP(T, CUR, RCONS, RISSUE)                                          \
  {                                                                              \
    const int cur = (CUR), nxt = (CUR)^1;                                        \
    if (doPref && (T) < SS-2)                                                    \
      RISSUE = *(const h4*)(wxh + ((size_t)(b0+sm)*SS + ((T)+2))*FF + skq*4);    \
    h8 bact[6];                                                                  \
    _Pragma("unroll")                                                            \
    for (int cc=0; cc<2; ++cc)                                                   \
      bact[cc] = *(const h8*)&xst[cur][lm*64 + (((cc*4+lq) ^ (lm&7))<<3)];       \
    _Pragma("unroll")                                                            \
    for (int cc=0; cc<4; ++cc)                                                   \
      bact[2+cc] = *(const h8*)&hbuf[cur][lm*128 + (((cc*4+lq) ^ (lm&7))<<3)];   \
    f4v acc[4];                                                                  \
    __builtin_amdgcn_s_setprio(1);                                               \
    _Pragma("unroll")                                                            \
    for (int tt=0; tt<4; ++tt){                                                  \
      f4v a1 = biasv[tt];                                                        \
      f4v a2 = {0.f,0.f,0.f,0.f};                                                \
      a1 = __builtin_amdgcn_mfma_f32_16x16x32_f16(wfr[tt][0], bact[0], a1, 0,0,0); \
      a2 = __builtin_amdgcn_mfma_f32_16x16x32_f16(wfr[tt][1], bact[1], a2, 0,0,0); \
      a1 = __builtin_amdgcn_mfma_f32_16x16x32_f16(wfr[tt][2], bact[2], a1, 0,0,0); \
      a2 = __builtin_amdgcn_mfma_f32_16x16x32_f16(wfr[tt][3], bact[3], a2, 0,0,0); \
      a1 = __builtin_amdgcn_mfma_f32_16x16x32_f16(wfr[tt][4], bact[4], a1, 0,0,0); \
      a2 = __builtin_amdgcn_mfma_f32_16x16x32_f16(wfr[tt][5], bact[5], a2, 0,0,0); \
      acc[tt] = a1 + a2;                                                         \
    }                                                                            \
    __builtin_amdgcn_s_setprio(0);                                               \
    float hn[4];                                                                 \
    _Pragma("unroll")                                                            \
    for (int r=0;r<4;++r){                                                       \
      float Ei = fexp2(acc[0][r]), Ef = fexp2(acc[1][r]);                        \
      float Eg = fexp2(acc[2][r]), Eo = fexp2(acc[3][r]);                        \
      float cn = frcp(1.f+Ef)*cst[r] + sigtanh(Ei, Eg);                          \
      float Ec = fexp2(cn*S_TANH);                                               \
      hn[r] = sigtanh(Eo, Ec);                                                   \
      cst[r] = cn;                                                               \
    }                                                                            \
    if (uvalid){                                                                 \
      h4 hp = {(_Float16)hn[0],(_Float16)hn[1],(_Float16)hn[2],(_Float16)hn[3]}; \
      *(h4*)&hbuf[nxt][hwaddr] = hp;                                             \
      *(h4*)&ench[((size_t)(b0+lm)*SS + (T))*112 + u0] = hp;                     \
    } else {                                                                     \
      h4 z = {(_Float16)0.f,(_Float16)0.f,(_Float16)0.f,(_Float16)0.f};          \
      *(h4*)&ench[((size_t)(b0+lm)*SS + (T))*112 + u0] = z;                      \
    }                                                                            \
    if (doPref && (T) < SS-1){                                                   \
      *(h4*)&xst[nxt][xwaddr] = RCONS;                                           \
    }                                                                            \
    LDS_BARRIER();                                                               \
  }

  for (int t = 0; t < SS; t += 2){
    ENC_STEP(t,   0, rA, rB)   // consumes x(t+1) from rA, issues x(t+2) into rB
    ENC_STEP(t+1, 1, rB, rA)   // consumes x(t+2) from rB, issues x(t+3) into rA
  }
#undef ENC_STEP
}

// ====== R9: ts GEMM + attn2 FUSED (one block per batch) ======
// Phase 1: ts[s] for the batch's 128 rows via MFMA (k_ts pattern: A = ench
// rows direct-h8, B = aW1 frags) -> LDS. Phase 2: softmax/ctx/bott/heads
// (old k_attn2). Saves the ts round-trip, a launch, and keeps ench L2-hot.
__global__ __launch_bounds__(256) void k_tsattn2(const _Float16* __restrict__ ench,
    const float* __restrict__ aW1, const float* __restrict__ ab1,
    const float* __restrict__ aW2, const float* __restrict__ ab2,
    const float* __restrict__ bW, const float* __restrict__ bb_,
    const float* __restrict__ h0W, const float* __restrict__ h0b,
    const float* __restrict__ c0W, const float* __restrict__ c0b,
    const float* __restrict__ dWih, const float* __restrict__ dbih, const float* __restrict__ dbhh,
    float* __restrict__ tw_out, float* __restrict__ dh0, float* __restrict__ dc0,
    float* __restrict__ decpre){
  __shared__ float tsb[SS];
  __shared__ float ctxb[HH];
  __shared__ float ctx2[200];
  __shared__ float bottb[32];
  __shared__ float red[8];
  int tid = threadIdx.x, wv = tid>>6, lane = tid&63, lm = lane&15, lq = lane>>4;
  int b = blockIdx.x;
  // ---- phase 1: ts rows (per wave: 2 M-tiles of 16 rows) ----
  {
    h8 bfr[4][4];
#pragma unroll
    for (int nt=0; nt<4; ++nt){
      int n = nt*16 + lm;
#pragma unroll
      for (int cc=0; cc<4; ++cc){
        h8 f;
#pragma unroll
        for (int j=0;j<8;++j){
          int k = cc*32 + lq*8 + j;
          f[j] = (_Float16)((k<100) ? aW1[n*100+k]*S_TANH : 0.f);
        }
        bfr[nt][cc]=f;
      }
    }
    float ab1v[4], aw2v[4];
#pragma unroll
    for (int nt=0; nt<4; ++nt){ ab1v[nt] = ab1[nt*16+lm]*S_TANH; aw2v[nt] = aW2[nt*16+lm]; }
    float ab2v = ab2[0];
#pragma unroll
    for (int i=0;i<2;++i){
      int M0 = b*SS + wv*32 + i*16;
      const _Float16* rowp = ench + (size_t)(M0+lm)*112;
      h8 afr[4];
#pragma unroll
      for (int cc=0; cc<3; ++cc)
        afr[cc] = *(const h8*)(rowp + cc*32 + lq*8);
      if (lq < 2) afr[3] = *(const h8*)(rowp + 96 + lq*8);
      else { h8 z={0,0,0,0,0,0,0,0}; afr[3]=z; }
      f4v acc[4];
#pragma unroll
      for (int nt=0; nt<4; ++nt){
        f4v a = {ab1v[nt],ab1v[nt],ab1v[nt],ab1v[nt]};
#pragma unroll
        for (int cc=0; cc<4; ++cc)
          a = __builtin_amdgcn_mfma_f32_16x16x32_f16(afr[cc], bfr[nt][cc], a, 0,0,0);
        acc[nt]=a;
      }
      float p[4];
#pragma unroll
      for (int r=0;r<4;++r){
        p[r] = aw2v[0]*tanh2(acc[0][r]) + aw2v[1]*tanh2(acc[1][r])
             + aw2v[2]*tanh2(acc[2][r]) + aw2v[3]*tanh2(acc[3][r]);
#pragma unroll
        for (int m=1;m<16;m<<=1) p[r] += __shfl_xor(p[r], m, 64);
      }
      if (lm==0){
        float4 st; st.x=p[0]+ab2v; st.y=p[1]+ab2v; st.z=p[2]+ab2v; st.w=p[3]+ab2v;
        *(float4*)&tsb[wv*32 + i*16 + lq*4] = st;
      }
    }
  }
  __syncthreads();
  // ---- phase 2: softmax over S, ctx, bott, heads ----
  const _Float16* encb = ench + (size_t)b*SS*112;
  float tv = (tid < SS) ? tsb[tid] : -1e30f;
  float m = wmax(tv);
  if (lane==0) red[wv]=m;
  __syncthreads();
  m = fmaxf(fmaxf(red[0],red[1]), fmaxf(red[2],red[3]));
  float e = (tid < SS) ? __expf(tv - m) : 0.f;
  float sm = wsum(e);
  if (lane==0) red[4+wv]=sm;
  __syncthreads();
  float denom = red[4]+red[5]+red[6]+red[7];
  float rden = frcp(denom);
  if (tid < SS){
    float twv = e*rden;
    tw_out[(size_t)b*SS + tid] = twv;
    tsb[tid] = twv;
  }
  __syncthreads();
  if (tid < 200){
    int u = (tid < 100) ? tid : (tid - 100);
    int sb = (tid < 100) ? 0 : 64;
    const _Float16* ep = encb + (size_t)sb*112 + u;
    const float* tp = tsb + sb;
    float a = 0.f;
#pragma unroll 4
    for (int s=0;s<64;++s) a += tp[s]*(float)ep[s*112];
    ctx2[tid] = a;
  }
  __syncthreads();
  if (tid < HH) ctxb[tid] = ctx2[tid] + ctx2[tid+100];
  __syncthreads();
  if (tid < 32){
    float a = bb_[tid];
    const float* wr = bW + tid*HH;
    for (int k=0;k<HH;++k) a += wr[k]*ctxb[k];
    bottb[tid]=a;
  }
  __syncthreads();
  if (tid < HH){
    float a = h0b[tid];
    const float* wr = h0W + tid*32;
#pragma unroll
    for (int k=0;k<32;++k) a += wr[k]*bottb[k];
    dh0[(size_t)b*HH + tid] = a;
  } else if (tid < 200){
    int jj = tid-100;
    float a = c0b[jj];
    const float* wr = c0W + jj*32;
#pragma unroll
    for (int k=0;k<32;++k) a += wr[k]*bottb[k];
    dc0[(size_t)b*HH + jj] = a;
  }
  {
    int jj = tid;
    float a = dbih[jj]+dbhh[jj];
    const float* wr = dWih + jj*32;
#pragma unroll
    for (int k=0;k<32;++k) a += wr[k]*bottb[k];
    decpre[(size_t)b*400 + jj] = a;
    jj = tid + 256;
    if (jj < 400){
      float a2v = dbih[jj]+dbhh[jj];
      const float* wr2 = dWih + jj*32;
#pragma unroll
      for (int k=0;k<32;++k) a2v += wr2[k]*bottb[k];
      decpre[(size_t)b*400 + jj] = a2v;
    }
  }
}

// ================= MFMA decoder LSTM (swapped operands) =================
// f16 dech output; exp2-domain gates; split chains; sigtanh fusion.
// R9: zero the 112-pad (units 100..111) so the MFMA k_out never reads garbage.
__global__ __launch_bounds__(448) void k_dec_mfma(const float* __restrict__ decpre,
    const float* __restrict__ Whh,
    const float* __restrict__ dh0, const float* __restrict__ dc0,
    _Float16* __restrict__ dech){
  __shared__ __align__(16) _Float16 hbuf[2][16*128];
  int tid = threadIdx.x;
  int w = tid >> 6, l = tid & 63;
  int lm = l & 15, lq = l >> 4;
  int b0 = blockIdx.x * 16;
  int au = w*16 + lm;
  bool avalid = au < 100;
  int u0 = w*16 + lq*4;
  bool uvalid = (u0 + 3) < 100;
  const float gsc[4] = {S_SIG, S_SIG, S_TANH, S_SIG};
  h8 wfr[4][4];
#pragma unroll
  for (int tt = 0; tt < 4; ++tt){
    int row = tt*100 + au;
#pragma unroll
    for (int cc = 0; cc < 4; ++cc){
      h8 f;
#pragma unroll
      for (int j = 0; j < 8; ++j){
        int kh = cc*32 + lq*8 + j;
        float v = (avalid && kh < 100) ? Whh[(size_t)row*100 + kh] : 0.f;
        f[j] = (_Float16)(v*gsc[tt]);
      }
      wfr[tt][cc] = f;
    }
  }
  f4v pre[4];
  float cst[4] = {0.f,0.f,0.f,0.f};
  if (uvalid){
#pragma unroll
    for (int tt = 0; tt < 4; ++tt){
      float4 p = *(const float4*)&decpre[(size_t)(b0+lm)*400 + tt*100 + u0];
      float s = gsc[tt];
      f4v pv = {p.x*s, p.y*s, p.z*s, p.w*s};
      pre[tt] = pv;
    }
    float4 c4 = *(const float4*)&dc0[(size_t)(b0+lm)*100 + u0];
    cst[0]=c4.x; cst[1]=c4.y; cst[2]=c4.z; cst[3]=c4.w;
  } else {
    f4v z = {0,0,0,0};
#pragma unroll
    for (int tt = 0; tt < 4; ++tt) pre[tt] = z;
  }
  for (int i = tid; i < 16*128; i += 448) hbuf[1][i] = (_Float16)0.f;
  for (int idx = tid; idx < 16*128; idx += 448){
    int m = idx >> 7, u2 = idx & 127;
    float v = (u2 < 100) ? dh0[(size_t)(b0+m)*HH + u2] : 0.f;
    hbuf[0][m*128 + (((u2>>3) ^ (m&7))<<3) + (u2&7)] = (_Float16)v;
  }
  int hwaddr = lm*128 + (((2*w + (lq>>1)) ^ (lm&7))<<3) + (lq&1)*4;
  __syncthreads();

#define DEC_STEP(T, CUR)                                                         \
  {                                                                              \
    const int cur = (CUR), nxt = (CUR)^1;                                        \
    h8 bact[4];                                                                  \
    _Pragma("unroll")                                                            \
    for (int cc = 0; cc < 4; ++cc)                                               \
      bact[cc] = *(const h8*)&hbuf[cur][lm*128 + (((cc*4+lq) ^ (lm&7))<<3)];     \
    f4v acc[4];                                                                  \
    __builtin_amdgcn_s_setprio(1);                                               \
    _Pragma("unroll")                                                            \
    for (int tt = 0; tt < 4; ++tt){                                              \
      f4v a1 = pre[tt];                                                          \
      f4v a2 = {0.f,0.f,0.f,0.f};                                                \
      a1 = __builtin_amdgcn_mfma_f32_16x16x32_f16(wfr[tt][0], bact[0], a1, 0,0,0); \
      a2 = __builtin_amdgcn_mfma_f32_16x16x32_f16(wfr[tt][1], bact[1], a2, 0,0,0); \
      a1 = __builtin_amdgcn_mfma_f32_16x16x32_f16(wfr[tt][2], bact[2], a1, 0,0,0); \
      a2 = __builtin_amdgcn_mfma_f32_16x16x32_f16(wfr[tt][3], bact[3], a2, 0,0,0); \
      acc[tt] = a1 + a2;                                                         \
    }                                                                            \
    __builtin_amdgcn_s_setprio(0);                                               \
    float hn[4];                                                                 \
    _Pragma("unroll")                                                            \
    for (int r=0;r<4;++r){                                                       \
      float Ei = fexp2(acc[0][r]), Ef = fexp2(acc[1][r]);                        \
      float Eg = fexp2(acc[2][r]), Eo = fexp2(acc[3][r]);                        \
      float cn = frcp(1.f+Ef)*cst[r] + sigtanh(Ei, Eg);                          \
      float Ec = fexp2(cn*S_TANH);                                               \
      hn[r] = sigtanh(Eo, Ec);                                                   \
      cst[r] = cn;                                                               \
    }                                                                            \
    if (uvalid){                                                                 \
      h4 hp = {(_Float16)hn[0],(_Float16)hn[1],(_Float16)hn[2],(_Float16)hn[3]}; \
      *(h4*)&hbuf[nxt][hwaddr] = hp;                                             \
      *(h4*)&dech[((size_t)(b0+lm)*SS + (T))*112 + u0] = hp;                     \
    } else {                                                                     \
      h4 z = {(_Float16)0.f,(_Float16)0.f,(_Float16)0.f,(_Float16)0.f};          \
      *(h4*)&dech[((size_t)(b0+lm)*SS + (T))*112 + u0] = z;                      \
    }                                                                            \
    LDS_BARRIER();                                                               \
  }

  for (int t = 0; t < SS; t += 2){
    DEC_STEP(t,   0)
    DEC_STEP(t+1, 1)
  }
#undef DEC_STEP
}

// ------------- out = dech @ oW^T + ob, MFMA (R9) -------------
// Was a VALU GEMV with ~6800 scalar LDS reads/thread; now the k_ts pattern:
// A = dech rows (direct h8 global loads, 112-padded, pad zeroed by k_dec),
// B = oW frags in registers, bias as C-init. D layout: row m = lq*4+r,
// col n = nt*16+lm (same orientation verified in k_ts).
__global__ __launch_bounds__(256) void k_out(const _Float16* __restrict__ dech,
    const float* __restrict__ oW, const float* __restrict__ ob, float* __restrict__ out0){
  int tid = threadIdx.x, wv = tid>>6, l = tid&63, lm = l&15, lq = l>>4;
  h8 bfr[4][4];
#pragma unroll
  for (int nt=0; nt<4; ++nt){
    int n = nt*16 + lm;
#pragma unroll
    for (int cc=0; cc<4; ++cc){
      h8 f;
#pragma unroll
      for (int j=0;j<8;++j){
        int k = cc*32 + lq*8 + j;
        f[j] = (_Float16)((k<100) ? oW[n*100+k] : 0.f);
      }
      bfr[nt][cc]=f;
    }
  }
  float obv[4];
#pragma unroll
  for (int nt=0; nt<4; ++nt) obv[nt] = ob[nt*16+lm];
  int tile0 = (blockIdx.x*4 + wv)*4;
#pragma unroll
  for (int i=0;i<4;++i){
    int M0 = (tile0+i)*16;
    const _Float16* rowp = dech + (size_t)(M0+lm)*112;
    h8 afr[4];
#pragma unroll
    for (int cc=0; cc<3; ++cc)
      afr[cc] = *(const h8*)(rowp + cc*32 + lq*8);
    if (lq < 2) afr[3] = *(const h8*)(rowp + 96 + lq*8);
    else { h8 z={0,0,0,0,0,0,0,0}; afr[3]=z; }
#pragma unroll
    for (int nt=0; nt<4; ++nt){
      f4v a = {obv[nt],obv[nt],obv[nt],obv[nt]};
#pragma unroll
      for (int cc=0; cc<4; ++cc)
        a = __builtin_amdgcn_mfma_f32_16x16x32_f16(afr[cc], bfr[nt][cc], a, 0,0,0);
#pragma unroll
      for (int r=0;r<4;++r)
        out0[(size_t)(M0 + lq*4 + r)*64 + nt*16 + lm] = a[r];
    }
  }
}

extern "C" void kernel_launch(void* const* d_in, const int* in_sizes, int n_in,
                              void* d_out, int out_size, void* d_ws, size_t ws_size,
                              hipStream_t stream) {
  const float* x    = (const float*)d_in[0];
  const float* c1w  = (const float*)d_in[1];
  const float* c1b  = (const float*)d_in[2];
  const float* c2w  = (const float*)d_in[3];
  const float* c2b  = (const float*)d_in[4];
  const float* fW1  = (const float*)d_in[5];
  const float* fb1  = (const float*)d_in[6];
  const float* fW2  = (const float*)d_in[7];
  const float* fb2  = (const float*)d_in[8];
  const float* cW1  = (const float*)d_in[9];
  const float* cb1  = (const float*)d_in[10];
  const float* cW2  = (const float*)d_in[11];
  const float* cb2  = (const float*)d_in[12];
  const float* eWih = (const float*)d_in[13];
  const float* eWhh = (const float*)d_in[14];
  const float* ebih = (const float*)d_in[15];
  const float* ebhh = (const float*)d_in[16];
  const float* aW1  = (const float*)d_in[17];
  const float* ab1  = (const float*)d_in[18];
  const float* aW2  = (const float*)d_in[19];
  const float* ab2  = (const float*)d_in[20];
  const float* bW   = (const float*)d_in[21];
  const float* bb   = (const float*)d_in[22];
  const float* h0W  = (const float*)d_in[23];
  const float* h0b  = (const float*)d_in[24];
  const float* c0W  = (const float*)d_in[25];
  const float* c0b  = (const float*)d_in[26];
  const float* dWih = (const float*)d_in[27];
  const float* dWhh = (const float*)d_in[28];
  const float* dbih = (const float*)d_in[29];
  const float* dbhh = (const float*)d_in[30];
  const float* oW   = (const float*)d_in[31];
  const float* ob   = (const float*)d_in[32];

  float* out0   = (float*)d_out;
  float* out_tw = out0 + (size_t)BB*SS*FF;
  float* out_fw = out_tw + (size_t)BB*SS;

  char* ws = (char*)d_ws;
  __half* pool1  = (__half*)(ws + 16777216);    // 33.55 MB (channel-last [b][p][ic])
  float*  proc   = (float*) (ws + 50331648);    // 0.13 MB
  _Float16* wxh  = (_Float16*)(ws + 84017152);  // 16.78 MB (f16, [b*S+s][64])
  float*  dh0    = (float*) (ws + 170000384);   // 0.41 MB
  float*  dc0    = (float*) (ws + 170409984);   // 0.41 MB
  float*  decpre = (float*) (ws + 170819584);   // 1.64 MB
  _Float16* dech = (_Float16*)(ws + 172457984); // 29.36 MB (f16, [row][112])
  _Float16* ench = (_Float16*)(ws + 50462720);  // 29.36 MB

  k_gc1<<<BB, 256, 0, stream>>>(x, c1w, c1b, pool1);
  k_conv2mfma<<<BB, 512, 0, stream>>>(pool1, c2w, c2b, proc);
  k_feat<<<BB, 256, 0, stream>>>(x, proc, fW1, fb1, fW2, fb2,
                                 cW1, cb1, cW2, cb2, out_fw, wxh);
  k_enc_mfma<<<64, 448, 0, stream>>>(wxh, eWih, eWhh, ebih, ebhh, ench);
  k_tsattn2<<<BB, 256, 0, stream>>>(ench, aW1, ab1, aW2, ab2, bW, bb,
                                    h0W, h0b, c0W, c0b,
                                    dWih, dbih, dbhh, out_tw, dh0, dc0, decpre);
  k_dec_mfma<<<64, 448, 0, stream>>>(decpre, dWhh, dh0, dc0, dech);
  k_out<<<512, 256, 0, stream>>>(dech, oW, ob, out0);
}

// Round 10
// 622.092 us; speedup vs baseline: 1.6049x; 1.0060x over previous
//
#include <hip/hip_runtime.h>
#include <hip/hip_fp16.h>

#define BB 1024
#define SS 128
#define FF 64
#define HH 100

typedef _Float16 h8 __attribute__((ext_vector_type(8)));
typedef _Float16 h4 __attribute__((ext_vector_type(4)));
typedef float f4v __attribute__((ext_vector_type(4)));

// --- fast transcendentals ---------------------------------------------------
// v_rcp_f32 (~1 ulp); fp32 '/' without fast-math is ~11 VALU ops (R5: -32%).
// exp2-domain gates (R6): fold 1/ln2 (and tanh's 2x) into weights/biases.
// R7: product fusion sigma(zi)*tanh(zt) = (Et-1)*rcp((1+Ei)(1+Et)).
// R10: cell state kept pre-scaled (cst2 = c*2/ln2) -- removes the serial
// cn*S_TANH mul before the Ec exp2; the scale folds into sigtanhT's fma.
#define S_SIG  (-1.4426950408889634f)   // i,f,o rows: acc = -z/ln2
#define S_TANH ( 2.8853900817779268f)   // g rows:     acc = 2z/ln2
#define LOG2E  ( 1.4426950408889634f)
__device__ __forceinline__ float frcp(float x){ return __builtin_amdgcn_rcpf(x); }
__device__ __forceinline__ float fexp2(float x){ return __builtin_amdgcn_exp2f(x); }
__device__ __forceinline__ float sigm2(float a){ return frcp(1.f + fexp2(a)); }        // a = -z/ln2
__device__ __forceinline__ float tanh2(float a){ return 1.f - 2.f*frcp(fexp2(a)+1.f);} // a = 2z/ln2
__device__ __forceinline__ float ftanh(float x){ return tanh2(x*S_TANH); }             // unscaled arg
__device__ __forceinline__ float sigtanh(float Ei, float Et){
  float D = __builtin_fmaf(Ei, Et, Ei) + (Et + 1.f);   // (1+Ei)(1+Et)
  return (Et - 1.f) * frcp(D);
}
// S_TANH * sigma * tanh (for the pre-scaled cell state):
__device__ __forceinline__ float sigtanhT(float Ei, float Et){
  float D = __builtin_fmaf(Ei, Et, Ei) + (Et + 1.f);
  return __builtin_fmaf(S_TANH, Et, -S_TANH) * frcp(D);
}

// LDS-only barrier: waits own LDS ops, does NOT drain vmcnt (global stores
// stay in flight across steps).
#define LDS_BARRIER() __asm__ __volatile__("s_waitcnt lgkmcnt(0)\ns_barrier" ::: "memory")

__device__ __forceinline__ float wsum(float v){
#pragma unroll
  for (int m = 32; m >= 1; m >>= 1) v += __shfl_xor(v, m, 64);
  return v;
}
__device__ __forceinline__ float wmax(float v){
#pragma unroll
  for (int m = 32; m >= 1; m >>= 1) v = fmaxf(v, __shfl_xor(v, m, 64));
  return v;
}

// ====== R10: gram + conv1pool + conv2 + mean FUSED (one block per batch) ======
// The whole conv pipeline is per-batch independent. conv1pool writes straight
// into conv2's padded im2col LDS image -- pool1 (33.5MB x2 HBM traffic) and
// conv2's zero+restage phase are eliminated, plus one launch.
// LDS overlay (64256 B total, 2 blocks/CU):
//   [0,8712)      img2 f16 66x66 (gram output; reused as red[8][32] at end)
//   [8720,64256)  img f16 (34*34+1)*24 (aliases xs f32 128x64 during gram)
__global__ __launch_bounds__(512) void k_conv(const float* __restrict__ x,
    const float* __restrict__ c1w, const float* __restrict__ c1b,
    const float* __restrict__ c2w, const float* __restrict__ c2b,
    float* __restrict__ proc){
  __shared__ __align__(16) char smem[64256];
  _Float16* img2 = (_Float16*)smem;              // 8712 B
  float*    xs   = (float*)(smem + 8720);        // 32768 B (dies at img zero)
  _Float16* img  = (_Float16*)(smem + 8720);     // 55536 B
  float*    red  = (float*)smem;                 // 1024 B (alias img2, late)
  int tid = threadIdx.x, b = blockIdx.x;
  int wv = tid>>6, l = tid&63, lm = l&15, lq = l>>4;
  // conv2 weight frags (registers, same as old k_conv2mfma)
  h8 bfr[2][5];
  float biasv[2];
#pragma unroll
  for (int nt=0; nt<2; ++nt){
    int oc = nt*16 + lm;
    biasv[nt] = c2b[oc];
#pragma unroll
    for (int c=0;c<5;++c){
      h8 f;
#pragma unroll
      for (int j=0;j<8;++j){
        int k = c*32 + lq*8 + j;
        int tap = k>>4, ic = k&15;
        f[j] = (_Float16)((tap<9) ? c2w[oc*144 + ic*9 + tap] : 0.f);
      }
      bfr[nt][c]=f;
    }
  }
  // stage x rows (f32) + zero img2
  {
    const float* xb = x + (size_t)b*SS*FF;
    for (int i = tid; i < SS*FF/4; i += 512)
      ((float4*)xs)[i] = ((const float4*)xb)[i];
    for (int i = tid; i < 66*66; i += 512) img2[i] = (_Float16)0.f;
  }
  __syncthreads();
  // gram: 512 threads x (2x4) cells
  {
    int ti = (tid & 31)*2, tj = (tid >> 5)*4;
    float acc[2][4];
#pragma unroll
    for (int a=0;a<2;++a)
#pragma unroll
      for (int c=0;c<4;++c) acc[a][c]=0.f;
    for (int s = 0; s < SS; ++s){
      const float* row = xs + s*FF;
      float a0 = row[ti], a1 = row[ti+1];
      float4 bv = *(const float4*)(row + tj);
      float bb2[4] = {bv.x,bv.y,bv.z,bv.w};
#pragma unroll
      for (int c=0;c<4;++c){ acc[0][c] += a0*bb2[c]; acc[1][c] += a1*bb2[c]; }
    }
    __syncthreads();   // xs reads done before img zero (next phase) overwrites
#pragma unroll
    for (int a=0;a<2;++a)
#pragma unroll
      for (int c=0;c<4;++c) img2[(ti+a+1)*66 + (tj+c+1)] = (_Float16)acc[a][c];
  }
  // zero img (kills xs)
  {
    h8 z = {0,0,0,0,0,0,0,0};
    for (int i=tid; i<(34*34+1)*3; i+=512) ((h8*)img)[i] = z;
  }
  __syncthreads();
  // conv1 + relu + maxpool2 -> f16 straight into the padded im2col image
  {
    int oc = tid>>5, slot = tid&31;
    float wr[9];
#pragma unroll
    for (int t=0;t<9;++t) wr[t]=c1w[oc*9+t];
    float bo = c1b[oc];
    for (int p=slot;p<1024;p+=32){
      int py=p>>5, px=p&31;
      int y0=py*2, x0=px*2;
      float v[4][4];
#pragma unroll
      for (int wy=0;wy<4;++wy)
#pragma unroll
        for (int wxx=0;wxx<4;++wxx) v[wy][wxx]=(float)img2[(y0+wy)*66 + x0+wxx];
      float s00=bo,s01=bo,s10=bo,s11=bo;
#pragma unroll
      for (int ky=0;ky<3;++ky)
#pragma unroll
        for (int kx=0;kx<3;++kx){
          float w=wr[ky*3+kx];
          s00 += v[ky][kx]*w;   s01 += v[ky][kx+1]*w;
          s10 += v[ky+1][kx]*w; s11 += v[ky+1][kx+1]*w;
        }
      float mx = fmaxf(fmaxf(s00,s01),fmaxf(s10,s11));
      img[((py+1)*34 + (px+1))*24 + oc] = (_Float16)fmaxf(mx,0.f);
    }
  }
  __syncthreads();
  // conv2 implicit-im2col MFMA + relu + mean
  f4v ssum0 = {0,0,0,0}, ssum1 = {0,0,0,0};
#pragma unroll 2
  for (int i=0;i<8;++i){
    int mt = wv + i*8;
    int y = mt>>1, x0 = (mt&1)*16;
    h8 afr[5];
#pragma unroll
    for (int c=0;c<5;++c){
      int tap = 2*c + (lq>>1);
      int addr;
      if (c==4 && lq>=2) addr = 34*34*24;
      else {
        int dy = tap/3 - 1, dx = tap - (tap/3)*3 - 1;
        addr = ((y+dy+1)*34 + (x0+lm+dx+1))*24 + (lq&1)*8;
      }
      afr[c] = *(const h8*)&img[addr];
    }
    f4v a0 = {biasv[0],biasv[0],biasv[0],biasv[0]};
    f4v a1 = {biasv[1],biasv[1],biasv[1],biasv[1]};
#pragma unroll
    for (int c=0;c<5;++c){
      a0 = __builtin_amdgcn_mfma_f32_16x16x32_f16(afr[c], bfr[0][c], a0, 0,0,0);
      a1 = __builtin_amdgcn_mfma_f32_16x16x32_f16(afr[c], bfr[1][c], a1, 0,0,0);
    }
#pragma unroll
    for (int r=0;r<4;++r){
      ssum0[r] += fmaxf(a0[r],0.f);
      ssum1[r] += fmaxf(a1[r],0.f);
    }
  }
  float s0 = ssum0[0]+ssum0[1]+ssum0[2]+ssum0[3];
  float s1 = ssum1[0]+ssum1[1]+ssum1[2]+ssum1[3];
  s0 += __shfl_xor(s0,16,64); s0 += __shfl_xor(s0,32,64);
  s1 += __shfl_xor(s1,16,64); s1 += __shfl_xor(s1,32,64);
  __syncthreads();   // img2 region dead -> red可用
  if (lq==0){ red[wv*32+lm]=s0; red[wv*32+16+lm]=s1; }
  __syncthreads();
  if (tid<32){
    float t=0.f;
#pragma unroll
    for (int w2=0;w2<8;++w2) t += red[w2*32+tid];
    proc[b*32+tid] = t*(1.f/1024.f);
  }
}

// ====== fused feature pipeline (fs + attnmlp), MFMA ======
#define TADDR(row,k) (((row)<<7) + (((((k)>>3) ^ (row)) & 15)<<3) + ((k)&7))
__global__ __launch_bounds__(256, 2) void k_feat(const float* __restrict__ x,
    const float* __restrict__ proc,
    const float* __restrict__ fW1, const float* __restrict__ fb1,
    const float* __restrict__ fW2, const float* __restrict__ fb2,
    const float* __restrict__ cW1, const float* __restrict__ cb1,
    const float* __restrict__ cW2, const float* __restrict__ cb2,
    float* __restrict__ fw_out, _Float16* __restrict__ wxh){
  __shared__ __align__(16) _Float16 tiles[4][3][2048];   // [wave][xt,tA,tB][16*128]
  __shared__ __align__(16) _Float16 proc_h[32];
  int tid = threadIdx.x, w = tid>>6, l = tid&63, lm = l&15, lq = l>>4;
  int b = blockIdx.x;
  h8 wfr1[2][2], wfr2[4], wfr3[4][3], wfr4[4][2];
#pragma unroll
  for (int mt=0; mt<2; ++mt)
#pragma unroll
    for (int kc=0; kc<2; ++kc){
      h8 f;
#pragma unroll
      for (int j=0;j<8;++j) f[j] = (_Float16)(fW1[(mt*16+lm)*64 + kc*32 + lq*8 + j]*S_TANH);
      wfr1[mt][kc]=f;
    }
#pragma unroll
  for (int mt=0; mt<4; ++mt){
    h8 f;
#pragma unroll
    for (int j=0;j<8;++j) f[j] = (_Float16)(fW2[(mt*16+lm)*32 + lq*8 + j]);
    wfr2[mt]=f;
  }
#pragma unroll
  for (int mt=0; mt<4; ++mt)
#pragma unroll
    for (int kc=0; kc<3; ++kc){
      h8 f;
#pragma unroll
      for (int j=0;j<8;++j) f[j] = (_Float16)(cW1[(mt*16+lm)*96 + kc*32 + lq*8 + j]*S_TANH);
      wfr3[mt][kc]=f;
    }
#pragma unroll
  for (int mt=0; mt<4; ++mt)
#pragma unroll
    for (int kc=0; kc<2; ++kc){
      h8 f;
#pragma unroll
      for (int j=0;j<8;++j) f[j] = (_Float16)(cW2[(mt*16+lm)*64 + kc*32 + lq*8 + j]);
      wfr4[mt][kc]=f;
    }
  f4v b1v[2], b2v[4], b3v[4], b4v[4];
#pragma unroll
  for (int mt=0;mt<2;++mt){
    float4 t = *(const float4*)&fb1[mt*16 + lq*4];
    f4v v = {t.x*S_TANH, t.y*S_TANH, t.z*S_TANH, t.w*S_TANH}; b1v[mt]=v;
  }
#pragma unroll
  for (int mt=0;mt<4;++mt){
    float4 t = *(const float4*)&fb2[mt*16 + lq*4];
    f4v v = {t.x, t.y, t.z, t.w}; b2v[mt]=v;
  }
#pragma unroll
  for (int mt=0;mt<4;++mt){
    float4 t = *(const float4*)&cb1[mt*16 + lq*4];
    f4v v = {t.x*S_TANH, t.y*S_TANH, t.z*S_TANH, t.w*S_TANH}; b3v[mt]=v;
  }
#pragma unroll
  for (int mt=0;mt<4;++mt){
    float4 t = *(const float4*)&cb2[mt*16 + lq*4];
    f4v v = {t.x, t.y, t.z, t.w}; b4v[mt]=v;
  }
  if (tid<32) proc_h[tid] = (_Float16)proc[b*32+tid];
  __syncthreads();
  _Float16* xt = tiles[w][0];
  _Float16* tA = tiles[w][1];
  _Float16* tB = tiles[w][2];
  {
    h8 ph = *(const h8*)&proc_h[lq*8];
    *(h8*)&tB[TADDR(lm, 64+lq*8)] = ph;
  }
#pragma unroll 1
  for (int g2 = 0; g2 < 2; ++g2){
    int g = w*2 + g2;
    size_t R0 = (size_t)b*SS + g*16;
    const float* xr = x + (R0+lm)*64 + lq*16;
    float4 x0 = *(const float4*)xr;
    float4 x1 = *(const float4*)(xr+4);
    float4 x2 = *(const float4*)(xr+8);
    float4 x3 = *(const float4*)(xr+12);
    h8 hx0 = {(_Float16)x0.x,(_Float16)x0.y,(_Float16)x0.z,(_Float16)x0.w,
              (_Float16)x1.x,(_Float16)x1.y,(_Float16)x1.z,(_Float16)x1.w};
    h8 hx1 = {(_Float16)x2.x,(_Float16)x2.y,(_Float16)x2.z,(_Float16)x2.w,
              (_Float16)x3.x,(_Float16)x3.y,(_Float16)x3.z,(_Float16)x3.w};
    *(h8*)&xt[TADDR(lm, lq*16)] = hx0;
    *(h8*)&xt[TADDR(lm, lq*16+8)] = hx1;
    __syncthreads();
    h8 bx0 = *(const h8*)&xt[TADDR(lm, lq*8)];
    h8 bx1 = *(const h8*)&xt[TADDR(lm, 32+lq*8)];
    f4v a1[2];
#pragma unroll
    for (int mt=0;mt<2;++mt){
      f4v a = __builtin_amdgcn_mfma_f32_16x16x32_f16(wfr1[mt][0], bx0, b1v[mt],0,0,0);
      a1[mt] = __builtin_amdgcn_mfma_f32_16x16x32_f16(wfr1[mt][1], bx1, a,0,0,0);
    }
#pragma unroll
    for (int mt=0;mt<2;++mt){
      h4 tv = {(_Float16)tanh2(a1[mt][0]),(_Float16)tanh2(a1[mt][1]),
               (_Float16)tanh2(a1[mt][2]),(_Float16)tanh2(a1[mt][3])};
      *(h4*)&tA[TADDR(lm, mt*16+lq*4)] = tv;
    }
    __syncthreads();
    h8 bt = *(const h8*)&tA[TADDR(lm, lq*8)];
    f4v a2[4];
#pragma unroll
    for (int mt=0;mt<4;++mt)
      a2[mt] = __builtin_amdgcn_mfma_f32_16x16x32_f16(wfr2[mt], bt, b2v[mt],0,0,0);
#pragma unroll
    for (int mt=0;mt<4;++mt){
      h4 fv = {(_Float16)a2[mt][0],(_Float16)a2[mt][1],
               (_Float16)a2[mt][2],(_Float16)a2[mt][3]};
      *(h4*)&tB[TADDR(lm, mt*16+lq*4)] = fv;
    }
    __syncthreads();
    h8 bc0 = *(const h8*)&tB[TADDR(lm, lq*8)];
    h8 bc1 = *(const h8*)&tB[TADDR(lm, 32+lq*8)];
    h8 bc2 = *(const h8*)&tB[TADDR(lm, 64+lq*8)];
    f4v a3[4];
#pragma unroll
    for (int mt=0;mt<4;++mt){
      f4v z = {0.f,0.f,0.f,0.f};
      f4v a = __builtin_amdgcn_mfma_f32_16x16x32_f16(wfr3[mt][0], bc0, b3v[mt],0,0,0);
      f4v c = __builtin_amdgcn_mfma_f32_16x16x32_f16(wfr3[mt][1], bc1, z,0,0,0);
      a = __builtin_amdgcn_mfma_f32_16x16x32_f16(wfr3[mt][2], bc2, a,0,0,0);
      a3[mt] = a + c;
    }
#pragma unroll
    for (int mt=0;mt<4;++mt){
      h4 hv = {(_Float16)tanh2(a3[mt][0]),(_Float16)tanh2(a3[mt][1]),
               (_Float16)tanh2(a3[mt][2]),(_Float16)tanh2(a3[mt][3])};
      *(h4*)&tA[TADDR(lm, mt*16+lq*4)] = hv;
    }
    __syncthreads();
    h8 bh0 = *(const h8*)&tA[TADDR(lm, lq*8)];
    h8 bh1 = *(const h8*)&tA[TADDR(lm, 32+lq*8)];
    f4v a4[4];
#pragma unroll
    for (int mt=0;mt<4;++mt){
      f4v a = __builtin_amdgcn_mfma_f32_16x16x32_f16(wfr4[mt][0], bh0, b4v[mt],0,0,0);
      a4[mt] = __builtin_amdgcn_mfma_f32_16x16x32_f16(wfr4[mt][1], bh1, a,0,0,0);
    }
    float mx = a4[0][0];
#pragma unroll
    for (int mt=0;mt<4;++mt)
#pragma unroll
      for (int r=0;r<4;++r) mx = fmaxf(mx, a4[mt][r]);
    mx = fmaxf(mx, __shfl_xor(mx,16,64));
    mx = fmaxf(mx, __shfl_xor(mx,32,64));
    f4v e4[4];
    float s = 0.f;
#pragma unroll
    for (int mt=0;mt<4;++mt)
#pragma unroll
      for (int r=0;r<4;++r){
        float e = fexp2((a4[mt][r]-mx)*LOG2E);
        e4[mt][r] = e; s += e;
      }
    s += __shfl_xor(s,16,64);
    s += __shfl_xor(s,32,64);
    float rs = frcp(s);
#pragma unroll
    for (int mt=0;mt<4;++mt){
      h4 xh = *(const h4*)&xt[TADDR(lm, mt*16+lq*4)];
      float4 fwv;
      fwv.x = e4[mt][0]*rs; fwv.y = e4[mt][1]*rs;
      fwv.z = e4[mt][2]*rs; fwv.w = e4[mt][3]*rs;
      h4 wh = {(_Float16)((float)xh[0]*fwv.x), (_Float16)((float)xh[1]*fwv.y),
               (_Float16)((float)xh[2]*fwv.z), (_Float16)((float)xh[3]*fwv.w)};
      size_t off = (R0+lm)*64 + mt*16 + lq*4;
      *(float4*)&fw_out[off] = fwv;
      *(h4*)&wxh[off] = wh;
    }
    __syncthreads();
  }
}

// ================= MFMA encoder LSTM (swapped operands) =================
// ench: f16 copy of enc, row-padded to 112 (units 100..111 zeroed).
__global__ __launch_bounds__(448) void k_enc_mfma(const _Float16* __restrict__ wxh,
    const float* __restrict__ Wih, const float* __restrict__ Whh,
    const float* __restrict__ bih, const float* __restrict__ bhh,
    _Float16* __restrict__ ench){
  __shared__ __align__(16) _Float16 hbuf[2][16*128];
  __shared__ __align__(16) _Float16 xst[2][16*64];
  int tid = threadIdx.x;
  int w = tid >> 6, l = tid & 63;
  int lm = l & 15, lq = l >> 4;
  int b0 = blockIdx.x * 16;
  int au = w*16 + lm;
  bool avalid = au < 100;
  int u0 = w*16 + lq*4;
  bool uvalid = (u0 + 3) < 100;
  const float gsc[4] = {S_SIG, S_SIG, S_TANH, S_SIG};   // gate order i,f,g,o
  h8 wfr[4][6];
#pragma unroll
  for (int tt=0; tt<4; ++tt){
    int row = tt*100 + au;
#pragma unroll
    for (int cc=0; cc<6; ++cc){
      h8 f;
#pragma unroll
      for (int j=0;j<8;++j){
        int kg = cc*32 + lq*8 + j;
        float v = 0.f;
        if (avalid){
          if (kg < 64) v = Wih[(size_t)row*64 + kg];
          else { int kh = kg - 64; if (kh < 100) v = Whh[(size_t)row*100 + kh]; }
        }
        f[j] = (_Float16)(v*gsc[tt]);
      }
      wfr[tt][cc] = f;
    }
  }
  f4v biasv[4];
#pragma unroll
  for (int tt=0; tt<4; ++tt){
    if (uvalid){
      float4 bi = *(const float4*)&bih[tt*100 + u0];
      float4 bh = *(const float4*)&bhh[tt*100 + u0];
      float s = gsc[tt];
      f4v bv2 = {(bi.x+bh.x)*s, (bi.y+bh.y)*s, (bi.z+bh.z)*s, (bi.w+bh.w)*s};
      biasv[tt] = bv2;
    } else { f4v z = {0,0,0,0}; biasv[tt] = z; }
  }
  for (int i = tid; i < 2*16*128; i += 448) hbuf[0][i] = (_Float16)0.f;
  int sm = tid >> 4, skq = tid & 15;
  bool doPref = (tid < 256);
  int xwaddr = sm*64 + (((skq>>1) ^ (sm&7))<<3) + (skq&1)*4;
  h4 rA, rB;
  if (doPref){
    *(h4*)&xst[0][xwaddr] = *(const h4*)(wxh + ((size_t)(b0+sm)*SS + 0)*FF + skq*4);
    rA = *(const h4*)(wxh + ((size_t)(b0+sm)*SS + 1)*FF + skq*4);   // x(1)
  }
  float cst[4] = {0.f,0.f,0.f,0.f};   // pre-scaled cell state (c * 2/ln2)
  int hwaddr = lm*128 + (((2*w + (lq>>1)) ^ (lm&7))<<3) + (lq&1)*4;
  __syncthreads();

#define ENC_STEP(T, CUR, RCONS, RISSUE)                                          \
  {                                                                              \
    const int cur = (CUR), nxt = (CUR)^1;                                        \
    if (doPref && (T) < SS-2)                                                    \
      RISSUE = *(const h4*)(wxh + ((size_t)(b0+sm)*SS + ((T)+2))*FF + skq*4);    \
    h8 bact[6];                                                                  \
    _Pragma("unroll")                                                            \
    for (int cc=0; cc<2; ++cc)                                                   \
      bact[cc] = *(const h8*)&xst[cur][lm*64 + (((cc*4+lq) ^ (lm&7))<<3)];       \
    _Pragma("unroll")                                                            \
    for (int cc=0; cc<4; ++cc)                                                   \
      bact[2+cc] = *(const h8*)&hbuf[cur][lm*128 + (((cc*4+lq) ^ (lm&7))<<3)];   \
    f4v acc[4];                                                                  \
    __builtin_amdgcn_s_setprio(1);                                               \
    _Pragma("unroll")                                                            \
    for (int tt=0; tt<4; ++tt){                                                  \
      f4v a1 = biasv[tt];                                                        \
      f4v a2 = {0.f,0.f,0.f,0.f};                                                \
      a1 = __builtin_amdgcn_mfma_f32_16x16x32_f16(wfr[tt][0], bact[0], a1, 0,0,0); \
      a2 = __builtin_amdgcn_mfma_f32_16x16x32_f16(wfr[tt][1], bact[1], a2, 0,0,0); \
      a1 = __builtin_amdgcn_mfma_f32_16x16x32_f16(wfr[tt][2], bact[2], a1, 0,0,0); \
      a2 = __builtin_amdgcn_mfma_f32_16x16x32_f16(wfr[tt][3], bact[3], a2, 0,0,0); \
      a1 = __builtin_amdgcn_mfma_f32_16x16x32_f16(wfr[tt][4], bact[4], a1, 0,0,0); \
      a2 = __builtin_amdgcn_mfma_f32_16x16x32_f16(wfr[tt][5], bact[5], a2, 0,0,0); \
      acc[tt] = a1 + a2;                                                         \
    }                                                                            \
    __builtin_amdgcn_s_setprio(0);                                               \
    float hn[4];                                                                 \
    _Pragma("unroll")                                                            \
    for (int r=0;r<4;++r){                                                       \
      float Ei = fexp2(acc[0][r]), Ef = fexp2(acc[1][r]);                        \
      float Eg = fexp2(acc[2][r]), Eo = fexp2(acc[3][r]);                        \
      float cn2 = frcp(1.f+Ef)*cst[r] + sigtanhT(Ei, Eg);                        \
      float Ec = fexp2(cn2);                                                     \
      hn[r] = sigtanh(Eo, Ec);                                                   \
      cst[r] = cn2;                                                              \
    }                                                                            \
    if (uvalid){                                                                 \
      h4 hp = {(_Float16)hn[0],(_Float16)hn[1],(_Float16)hn[2],(_Float16)hn[3]}; \
      *(h4*)&hbuf[nxt][hwaddr] = hp;                                             \
      *(h4*)&ench[((size_t)(b0+lm)*SS + (T))*112 + u0] = hp;                     \
    } else {                                                                     \
      h4 z = {(_Float16)0.f,(_Float16)0.f,(_Float16)0.f,(_Float16)0.f};          \
      *(h4*)&ench[((size_t)(b0+lm)*SS + (T))*112 + u0] = z;                      \
    }                                                                            \
    if (doPref && (T) < SS-1){                                                   \
      *(h4*)&xst[nxt][xwaddr] = RCONS;                                           \
    }                                                                            \
    LDS_BARRIER();                                                               \
  }

  for (int t = 0; t < SS; t += 2){
    ENC_STEP(t,   0, rA, rB)
    ENC_STEP(t+1, 1, rB, rA)
  }
#undef ENC_STEP
}

// ====== ts GEMM + attn2 FUSED (one block per batch) ======
__global__ __launch_bounds__(256) void k_tsattn2(const _Float16* __restrict__ ench,
    const float* __restrict__ aW1, const float* __restrict__ ab1,
    const float* __restrict__ aW2, const float* __restrict__ ab2,
    const float* __restrict__ bW, const float* __restrict__ bb_,
    const float* __restrict__ h0W, const float* __restrict__ h0b,
    const float* __restrict__ c0W, const float* __restrict__ c0b,
    const float* __restrict__ dWih, const float* __restrict__ dbih, const float* __restrict__ dbhh,
    float* __restrict__ tw_out, float* __restrict__ dh0, float* __restrict__ dc0,
    float* __restrict__ decpre){
  __shared__ float tsb[SS];
  __shared__ float ctxb[HH];
  __shared__ float ctx2[200];
  __shared__ float bottb[32];
  __shared__ float red[8];
  int tid = threadIdx.x, wv = tid>>6, lane = tid&63, lm = lane&15, lq = lane>>4;
  int b = blockIdx.x;
  {
    h8 bfr[4][4];
#pragma unroll
    for (int nt=0; nt<4; ++nt){
      int n = nt*16 + lm;
#pragma unroll
      for (int cc=0; cc<4; ++cc){
        h8 f;
#pragma unroll
        for (int j=0;j<8;++j){
          int k = cc*32 + lq*8 + j;
          f[j] = (_Float16)((k<100) ? aW1[n*100+k]*S_TANH : 0.f);
        }
        bfr[nt][cc]=f;
      }
    }
    float ab1v[4], aw2v[4];
#pragma unroll
    for (int nt=0; nt<4; ++nt){ ab1v[nt] = ab1[nt*16+lm]*S_TANH; aw2v[nt] = aW2[nt*16+lm]; }
    float ab2v = ab2[0];
#pragma unroll
    for (int i=0;i<2;++i){
      int M0 = b*SS + wv*32 + i*16;
      const _Float16* rowp = ench + (size_t)(M0+lm)*112;
      h8 afr[4];
#pragma unroll
      for (int cc=0; cc<3; ++cc)
        afr[cc] = *(const h8*)(rowp + cc*32 + lq*8);
      if (lq < 2) afr[3] = *(const h8*)(rowp + 96 + lq*8);
      else { h8 z={0,0,0,0,0,0,0,0}; afr[3]=z; }
      f4v acc[4];
#pragma unroll
      for (int nt=0; nt<4; ++nt){
        f4v a = {ab1v[nt],ab1v[nt],ab1v[nt],ab1v[nt]};
#pragma unroll
        for (int cc=0; cc<4; ++cc)
          a = __builtin_amdgcn_mfma_f32_16x16x32_f16(afr[cc], bfr[nt][cc], a, 0,0,0);
        acc[nt]=a;
      }
      float p[4];
#pragma unroll
      for (int r=0;r<4;++r){
        p[r] = aw2v[0]*tanh2(acc[0][r]) + aw2v[1]*tanh2(acc[1][r])
             + aw2v[2]*tanh2(acc[2][r]) + aw2v[3]*tanh2(acc[3][r]);
#pragma unroll
        for (int m=1;m<16;m<<=1) p[r] += __shfl_xor(p[r], m, 64);
      }
      if (lm==0){
        float4 st; st.x=p[0]+ab2v; st.y=p[1]+ab2v; st.z=p[2]+ab2v; st.w=p[3]+ab2v;
        *(float4*)&tsb[wv*32 + i*16 + lq*4] = st;
      }
    }
  }
  __syncthreads();
  const _Float16* encb = ench + (size_t)b*SS*112;
  float tv = (tid < SS) ? tsb[tid] : -1e30f;
  float m = wmax(tv);
  if (lane==0) red[wv]=m;
  __syncthreads();
  m = fmaxf(fmaxf(red[0],red[1]), fmaxf(red[2],red[3]));
  float e = (tid < SS) ? __expf(tv - m) : 0.f;
  float sm = wsum(e);
  if (lane==0) red[4+wv]=sm;
  __syncthreads();
  float denom = red[4]+red[5]+red[6]+red[7];
  float rden = frcp(denom);
  if (tid < SS){
    float twv = e*rden;
    tw_out[(size_t)b*SS + tid] = twv;
    tsb[tid] = twv;
  }
  __syncthreads();
  if (tid < 200){
    int u = (tid < 100) ? tid : (tid - 100);
    int sb = (tid < 100) ? 0 : 64;
    const _Float16* ep = encb + (size_t)sb*112 + u;
    const float* tp = tsb + sb;
    float a = 0.f;
#pragma unroll 4
    for (int s=0;s<64;++s) a += tp[s]*(float)ep[s*112];
    ctx2[tid] = a;
  }
  __syncthreads();
  if (tid < HH) ctxb[tid] = ctx2[tid] + ctx2[tid+100];
  __syncthreads();
  if (tid < 32){
    float a = bb_[tid];
    const float* wr = bW + tid*HH;
    for (int k=0;k<HH;++k) a += wr[k]*ctxb[k];
    bottb[tid]=a;
  }
  __syncthreads();
  if (tid < HH){
    float a = h0b[tid];
    const float* wr = h0W + tid*32;
#pragma unroll
    for (int k=0;k<32;++k) a += wr[k]*bottb[k];
    dh0[(size_t)b*HH + tid] = a;
  } else if (tid < 200){
    int jj = tid-100;
    float a = c0b[jj];
    const float* wr = c0W + jj*32;
#pragma unroll
    for (int k=0;k<32;++k) a += wr[k]*bottb[k];
    dc0[(size_t)b*HH + jj] = a;
  }
  {
    int jj = tid;
    float a = dbih[jj]+dbhh[jj];
    const float* wr = dWih + jj*32;
#pragma unroll
    for (int k=0;k<32;++k) a += wr[k]*bottb[k];
    decpre[(size_t)b*400 + jj] = a;
    jj = tid + 256;
    if (jj < 400){
      float a2v = dbih[jj]+dbhh[jj];
      const float* wr2 = dWih + jj*32;
#pragma unroll
      for (int k=0;k<32;++k) a2v += wr2[k]*bottb[k];
      decpre[(size_t)b*400 + jj] = a2v;
    }
  }
}

// ================= MFMA decoder LSTM (swapped operands) =================
// f16 dech output (112-pad zeroed for the MFMA k_out); pre-scaled cell state.
__global__ __launch_bounds__(448) void k_dec_mfma(const float* __restrict__ decpre,
    const float* __restrict__ Whh,
    const float* __restrict__ dh0, const float* __restrict__ dc0,
    _Float16* __restrict__ dech){
  __shared__ __align__(16) _Float16 hbuf[2][16*128];
  int tid = threadIdx.x;
  int w = tid >> 6, l = tid & 63;
  int lm = l & 15, lq = l >> 4;
  int b0 = blockIdx.x * 16;
  int au = w*16 + lm;
  bool avalid = au < 100;
  int u0 = w*16 + lq*4;
  bool uvalid = (u0 + 3) < 100;
  const float gsc[4] = {S_SIG, S_SIG, S_TANH, S_SIG};
  h8 wfr[4][4];
#pragma unroll
  for (int tt = 0; tt < 4; ++tt){
    int row = tt*100 + au;
#pragma unroll
    for (int cc = 0; cc < 4; ++cc){
      h8 f;
#pragma unroll
      for (int j = 0; j < 8; ++j){
        int kh = cc*32 + lq*8 + j;
        float v = (avalid && kh < 100) ? Whh[(size_t)row*100 + kh] : 0.f;
        f[j] = (_Float16)(v*gsc[tt]);
      }
      wfr[tt][cc] = f;
    }
  }
  f4v pre[4];
  float cst[4] = {0.f,0.f,0.f,0.f};
  if (uvalid){
#pragma unroll
    for (int tt = 0; tt < 4; ++tt){
      float4 p = *(const float4*)&decpre[(size_t)(b0+lm)*400 + tt*100 + u0];
      float s = gsc[tt];
      f4v pv = {p.x*s, p.y*s, p.z*s, p.w*s};
      pre[tt] = pv;
    }
    float4 c4 = *(const float4*)&dc0[(size_t)(b0+lm)*100 + u0];
    cst[0]=c4.x*S_TANH; cst[1]=c4.y*S_TANH; cst[2]=c4.z*S_TANH; cst[3]=c4.w*S_TANH;
  } else {
    f4v z = {0,0,0,0};
#pragma unroll
    for (int tt = 0; tt < 4; ++tt) pre[tt] = z;
  }
  for (int i = tid; i < 16*128; i += 448) hbuf[1][i] = (_Float16)0.f;
  for (int idx = tid; idx < 16*128; idx += 448){
    int m = idx >> 7, u2 = idx & 127;
    float v = (u2 < 100) ? dh0[(size_t)(b0+m)*HH + u2] : 0.f;
    hbuf[0][m*128 + (((u2>>3) ^ (m&7))<<3) + (u2&7)] = (_Float16)v;
  }
  int hwaddr = lm*128 + (((2*w + (lq>>1)) ^ (lm&7))<<3) + (lq&1)*4;
  __syncthreads();

#define DEC_STEP(T, CUR)                                                         \
  {                                                                              \
    const int cur = (CUR), nxt = (CUR)^1;                                        \
    h8 bact[4];                                                                  \
    _Pragma("unroll")                                                            \
    for (int cc = 0; cc < 4; ++cc)                                               \
      bact[cc] = *(const h8*)&hbuf[cur][lm*128 + (((cc*4+lq) ^ (lm&7))<<3)];     \
    f4v acc[4];                                                                  \
    __builtin_amdgcn_s_setprio(1);                                               \
    _Pragma("unroll")                                                            \
    for (int tt = 0; tt < 4; ++tt){                                              \
      f4v a1 = pre[tt];                                                          \
      f4v a2 = {0.f,0.f,0.f,0.f};                                                \
      a1 = __builtin_amdgcn_mfma_f32_16x16x32_f16(wfr[tt][0], bact[0], a1, 0,0,0); \
      a2 = __builtin_amdgcn_mfma_f32_16x16x32_f16(wfr[tt][1], bact[1], a2, 0,0,0); \
      a1 = __builtin_amdgcn_mfma_f32_16x16x32_f16(wfr[tt][2], bact[2], a1, 0,0,0); \
      a2 = __builtin_amdgcn_mfma_f32_16x16x32_f16(wfr[tt][3], bact[3], a2, 0,0,0); \
      acc[tt] = a1 + a2;                                                         \
    }                                                                            \
    __builtin_amdgcn_s_setprio(0);                                               \
    float hn[4];                                                                 \
    _Pragma("unroll")                                                            \
    for (int r=0;r<4;++r){                                                       \
      float Ei = fexp2(acc[0][r]), Ef = fexp2(acc[1][r]);                        \
      float Eg = fexp2(acc[2][r]), Eo = fexp2(acc[3][r]);                        \
      float cn2 = frcp(1.f+Ef)*cst[r] + sigtanhT(Ei, Eg);                        \
      float Ec = fexp2(cn2);                                                     \
      hn[r] = sigtanh(Eo, Ec);                                                   \
      cst[r] = cn2;                                                              \
    }                                                                            \
    if (uvalid){                                                                 \
      h4 hp = {(_Float16)hn[0],(_Float16)hn[1],(_Float16)hn[2],(_Float16)hn[3]}; \
      *(h4*)&hbuf[nxt][hwaddr] = hp;                                             \
      *(h4*)&dech[((size_t)(b0+lm)*SS + (T))*112 + u0] = hp;                     \
    } else {                                                                     \
      h4 z = {(_Float16)0.f,(_Float16)0.f,(_Float16)0.f,(_Float16)0.f};          \
      *(h4*)&dech[((size_t)(b0+lm)*SS + (T))*112 + u0] = z;                      \
    }                                                                            \
    LDS_BARRIER();                                                               \
  }

  for (int t = 0; t < SS; t += 2){
    DEC_STEP(t,   0)
    DEC_STEP(t+1, 1)
  }
#undef DEC_STEP
}

// ------------- out = dech @ oW^T + ob, MFMA -------------
__global__ __launch_bounds__(256) void k_out(const _Float16* __restrict__ dech,
    const float* __restrict__ oW, const float* __restrict__ ob, float* __restrict__ out0){
  int tid = threadIdx.x, wv = tid>>6, l = tid&63, lm = l&15, lq = l>>4;
  h8 bfr[4][4];
#pragma unroll
  for (int nt=0; nt<4; ++nt){
    int n = nt*16 + lm;
#pragma unroll
    for (int cc=0; cc<4; ++cc){
      h8 f;
#pragma unroll
      for (int j=0;j<8;++j){
        int k = cc*32 + lq*8 + j;
        f[j] = (_Float16)((k<100) ? oW[n*100+k] : 0.f);
      }
      bfr[nt][cc]=f;
    }
  }
  float obv[4];
#pragma unroll
  for (int nt=0; nt<4; ++nt) obv[nt] = ob[nt*16+lm];
  int tile0 = (blockIdx.x*4 + wv)*4;
#pragma unroll
  for (int i=0;i<4;++i){
    int M0 = (tile0+i)*16;
    const _Float16* rowp = dech + (size_t)(M0+lm)*112;
    h8 afr[4];
#pragma unroll
    for (int cc=0; cc<3; ++cc)
      afr[cc] = *(const h8*)(rowp + cc*32 + lq*8);
    if (lq < 2) afr[3] = *(const h8*)(rowp + 96 + lq*8);
    else { h8 z={0,0,0,0,0,0,0,0}; afr[3]=z; }
#pragma unroll
    for (int nt=0; nt<4; ++nt){
      f4v a = {obv[nt],obv[nt],obv[nt],obv[nt]};
#pragma unroll
      for (int cc=0; cc<4; ++cc)
        a = __builtin_amdgcn_mfma_f32_16x16x32_f16(afr[cc], bfr[nt][cc], a, 0,0,0);
#pragma unroll
      for (int r=0;r<4;++r)
        out0[(size_t)(M0 + lq*4 + r)*64 + nt*16 + lm] = a[r];
    }
  }
}

extern "C" void kernel_launch(void* const* d_in, const int* in_sizes, int n_in,
                              void* d_out, int out_size, void* d_ws, size_t ws_size,
                              hipStream_t stream) {
  const float* x    = (const float*)d_in[0];
  const float* c1w  = (const float*)d_in[1];
  const float* c1b  = (const float*)d_in[2];
  const float* c2w  = (const float*)d_in[3];
  const float* c2b  = (const float*)d_in[4];
  const float* fW1  = (const float*)d_in[5];
  const float* fb1  = (const float*)d_in[6];
  const float* fW2  = (const float*)d_in[7];
  const float* fb2  = (const float*)d_in[8];
  const float* cW1  = (const float*)d_in[9];
  const float* cb1  = (const float*)d_in[10];
  const float* cW2  = (const float*)d_in[11];
  const float* cb2  = (const float*)d_in[12];
  const float* eWih = (const float*)d_in[13];
  const float* eWhh = (const float*)d_in[14];
  const float* ebih = (const float*)d_in[15];
  const float* ebhh = (const float*)d_in[16];
  const float* aW1  = (const float*)d_in[17];
  const float* ab1  = (const float*)d_in[18];
  const float* aW2  = (const float*)d_in[19];
  const float* ab2  = (const float*)d_in[20];
  const float* bW   = (const float*)d_in[21];
  const float* bb   = (const float*)d_in[22];
  const float* h0W  = (const float*)d_in[23];
  const float* h0b  = (const float*)d_in[24];
  const float* c0W  = (const float*)d_in[25];
  const float* c0b  = (const float*)d_in[26];
  const float* dWih = (const float*)d_in[27];
  const float* dWhh = (const float*)d_in[28];
  const float* dbih = (const float*)d_in[29];
  const float* dbhh = (const float*)d_in[30];
  const float* oW   = (const float*)d_in[31];
  const float* ob   = (const float*)d_in[32];

  float* out0   = (float*)d_out;
  float* out_tw = out0 + (size_t)BB*SS*FF;
  float* out_fw = out_tw + (size_t)BB*SS;

  char* ws = (char*)d_ws;
  float*  proc   = (float*) (ws + 50331648);    // 0.13 MB
  _Float16* wxh  = (_Float16*)(ws + 84017152);  // 16.78 MB (f16, [b*S+s][64])
  float*  dh0    = (float*) (ws + 170000384);   // 0.41 MB
  float*  dc0    = (float*) (ws + 170409984);   // 0.41 MB
  float*  decpre = (float*) (ws + 170819584);   // 1.64 MB
  _Float16* dech = (_Float16*)(ws + 172457984); // 29.36 MB (f16, [row][112])
  _Float16* ench = (_Float16*)(ws + 50462720);  // 29.36 MB

  k_conv<<<BB, 512, 0, stream>>>(x, c1w, c1b, c2w, c2b, proc);
  k_feat<<<BB, 256, 0, stream>>>(x, proc, fW1, fb1, fW2, fb2,
                                 cW1, cb1, cW2, cb2, out_fw, wxh);
  k_enc_mfma<<<64, 448, 0, stream>>>(wxh, eWih, eWhh, ebih, ebhh, ench);
  k_tsattn2<<<BB, 256, 0, stream>>>(ench, aW1, ab1, aW2, ab2, bW, bb,
                                    h0W, h0b, c0W, c0b,
                                    dWih, dbih, dbhh, out_tw, dh0, dc0, decpre);
  k_dec_mfma<<<64, 448, 0, stream>>>(decpre, dWhh, dh0, dc0, dech);
  k_out<<<512, 256, 0, stream>>>(dech, oW, ob, out0);
}